// Round 1
// baseline (4001.853 us; speedup 1.0000x reference)
//
#include <hip/hip_runtime.h>
#include <hip/hip_bf16.h>

#define N_LAYERS 4
#define D_MODEL  1024
#define D_INNER  2048
#define D_STATE  16
#define D_CONV   4
#define DT_RANK  64
#define BB       2
#define TT       1024
#define BT       (BB*TT)   // 2048 rows (b*T)

__device__ __forceinline__ float sigmoidf_(float x){ return 1.f/(1.f+__expf(-x)); }
__device__ __forceinline__ float siluf_(float x){ return x*sigmoidf_(x); }
__device__ __forceinline__ float softplusf_(float x){ return fmaxf(x,0.f) + log1pf(__expf(-fabsf(x))); }

// C[M][N] = A[M][K] @ W[N][K]^T  (both row-major), 64x64 tile, BK=16, 4x4/thread.
// EPI: 0 = plain store, 1 = softplus(c + bias[n]), 2 = c + res[m*ldc+n]
template<int EPI>
__global__ __launch_bounds__(256) void gemm_tn(
    const float* __restrict__ A, int lda,
    const float* __restrict__ W, int ldw,
    float* __restrict__ C, int ldc,
    int M, int N, int K,
    const float* __restrict__ bias,
    const float* __restrict__ res)
{
    // [k][m] layout, row padded to 68 floats (272B, multiple of 16B) so
    // float4 LDS reads stay aligned; 68%32=4 spreads rows across banks.
    __shared__ float As[16][68];
    __shared__ float Ws[16][68];
    const int tid = threadIdx.x;
    const int tx = tid & 15, ty = tid >> 4;
    const int m0 = blockIdx.y * 64, n0 = blockIdx.x * 64;
    const int lr = tid >> 2;          // 0..63 tile row for staging
    const int lk = (tid & 3) << 2;    // 0,4,8,12 k-offset for staging
    float acc[4][4] = {{0.f}};

    for (int k0 = 0; k0 < K; k0 += 16) {
        float4 av = *(const float4*)(A + (size_t)(m0+lr)*lda + k0 + lk);
        float4 wv = make_float4(0.f,0.f,0.f,0.f);
        if (n0 + lr < N) wv = *(const float4*)(W + (size_t)(n0+lr)*ldw + k0 + lk);
        __syncthreads();
        As[lk+0][lr]=av.x; As[lk+1][lr]=av.y; As[lk+2][lr]=av.z; As[lk+3][lr]=av.w;
        Ws[lk+0][lr]=wv.x; Ws[lk+1][lr]=wv.y; Ws[lk+2][lr]=wv.z; Ws[lk+3][lr]=wv.w;
        __syncthreads();
        #pragma unroll
        for (int k = 0; k < 16; ++k) {
            float4 a = *(const float4*)&As[k][ty<<2];
            float4 b = *(const float4*)&Ws[k][tx<<2];
            float a4[4] = {a.x,a.y,a.z,a.w};
            float b4[4] = {b.x,b.y,b.z,b.w};
            #pragma unroll
            for (int i=0;i<4;++i)
                #pragma unroll
                for (int j=0;j<4;++j)
                    acc[i][j] = fmaf(a4[i], b4[j], acc[i][j]);
        }
    }

    #pragma unroll
    for (int i=0;i<4;++i){
        int m = m0 + (ty<<2) + i;
        #pragma unroll
        for (int j=0;j<4;++j){
            int n = n0 + (tx<<2) + j;
            if (n < N){
                float v = acc[i][j];
                if (EPI==1) v = softplusf_(v + bias[n]);
                if (EPI==2) v = v + res[(size_t)m*ldc + n];
                C[(size_t)m*ldc + n] = v;
            }
        }
    }
}

// Depthwise causal conv (K=4) + bias + SiLU. u = xz[..., :2048].
__global__ __launch_bounds__(256) void conv_silu_k(
    const float* __restrict__ xz, const float* __restrict__ cw,
    const float* __restrict__ cb, float* __restrict__ uc)
{
    int idx = blockIdx.x*256 + threadIdx.x;   // over BT*D_INNER
    int d  = idx & (D_INNER-1);
    int bt = idx >> 11;
    int t  = bt & (TT-1);
    float4 w4 = *(const float4*)(cw + d*4);
    float wv[4] = {w4.x, w4.y, w4.z, w4.w};
    float acc = cb[d];
    #pragma unroll
    for (int k=0;k<4;++k){
        int tt = t - 3 + k;
        if (tt >= 0) acc = fmaf(xz[(size_t)(bt-3+k)*4096 + d], wv[k], acc);
    }
    uc[idx] = siluf_(acc);
}

// Selective scan: thread per (b,d), 16 states in registers, sequential over T.
__global__ __launch_bounds__(256) void scan_k(
    const float* __restrict__ uc, const float* __restrict__ dt,
    const float* __restrict__ xdbl, const float* __restrict__ A_log,
    float* __restrict__ ys)
{
    int gid = blockIdx.x*256 + threadIdx.x;   // 0..4095
    int b = gid >> 11, d = gid & (D_INNER-1);
    float A[16];
    const float4* al = (const float4*)(A_log + (size_t)d*16);
    #pragma unroll
    for (int q=0;q<4;++q){
        float4 v = al[q];
        A[q*4+0] = -__expf(v.x); A[q*4+1] = -__expf(v.y);
        A[q*4+2] = -__expf(v.z); A[q*4+3] = -__expf(v.w);
    }
    float h[16];
    #pragma unroll
    for (int s=0;s<16;++s) h[s]=0.f;
    const float* ucp = uc   + (size_t)b*TT*D_INNER + d;
    const float* dtp = dt   + (size_t)b*TT*D_INNER + d;
    const float* xp  = xdbl + (size_t)b*TT*96;
    float* yp = ys + (size_t)b*TT*D_INNER + d;
    #pragma unroll 2
    for (int t=0; t<TT; ++t){
        float dtv = dtp[(size_t)t*D_INNER];
        float uv  = ucp[(size_t)t*D_INNER];
        const float4* bc = (const float4*)(xp + (size_t)t*96 + 64);
        float4 B0=bc[0], B1=bc[1], B2=bc[2], B3=bc[3];
        float4 C0=bc[4], C1=bc[5], C2=bc[6], C3=bc[7];
        float Bv[16] = {B0.x,B0.y,B0.z,B0.w, B1.x,B1.y,B1.z,B1.w,
                        B2.x,B2.y,B2.z,B2.w, B3.x,B3.y,B3.z,B3.w};
        float Cv[16] = {C0.x,C0.y,C0.z,C0.w, C1.x,C1.y,C1.z,C1.w,
                        C2.x,C2.y,C2.z,C2.w, C3.x,C3.y,C3.z,C3.w};
        float du = dtv*uv;
        float y = 0.f;
        #pragma unroll
        for (int s=0;s<16;++s){
            h[s] = fmaf(__expf(dtv*A[s]), h[s], du*Bv[s]);
            y = fmaf(h[s], Cv[s], y);
        }
        yp[(size_t)t*D_INNER] = y;
    }
}

// y = (ys + uc*Dd[d]) * silu(z), in-place into ys. z = xz[..., 2048:].
__global__ __launch_bounds__(256) void fin_y_k(
    float* __restrict__ ys, const float* __restrict__ uc,
    const float* __restrict__ xz, const float* __restrict__ Dd)
{
    int idx = blockIdx.x*256 + threadIdx.x;
    int d  = idx & (D_INNER-1);
    int bt = idx >> 11;
    float z = xz[(size_t)bt*4096 + 2048 + d];
    ys[idx] = (ys[idx] + uc[idx]*Dd[d]) * siluf_(z);
}

__global__ __launch_bounds__(256) void layernorm_k(
    const float* __restrict__ X, const float* __restrict__ w,
    const float* __restrict__ b, float* __restrict__ out)
{
    int row = blockIdx.x;
    int tid = threadIdx.x;
    const float* xr = X + (size_t)row*D_MODEL;
    float4 v = *(const float4*)(xr + tid*4);
    float s  = v.x+v.y+v.z+v.w;
    float ss = fmaf(v.x,v.x, fmaf(v.y,v.y, fmaf(v.z,v.z, v.w*v.w)));
    #pragma unroll
    for (int off=32; off>0; off>>=1){
        s  += __shfl_down(s, off, 64);
        ss += __shfl_down(ss, off, 64);
    }
    __shared__ float red[8];
    int wid = tid>>6, lane = tid&63;
    if (lane==0){ red[wid]=s; red[4+wid]=ss; }
    __syncthreads();
    if (tid==0){
        float S  = red[0]+red[1]+red[2]+red[3];
        float SS = red[4]+red[5]+red[6]+red[7];
        float mu = S*(1.f/D_MODEL);
        float var = SS*(1.f/D_MODEL) - mu*mu;
        red[0]=mu; red[1]=rsqrtf(var + 1e-5f);
    }
    __syncthreads();
    float mu=red[0], rs=red[1];
    float4 wv = *(const float4*)(w + tid*4);
    float4 bv = *(const float4*)(b + tid*4);
    float4 o;
    o.x = fmaf((v.x-mu)*rs, wv.x, bv.x);
    o.y = fmaf((v.y-mu)*rs, wv.y, bv.y);
    o.z = fmaf((v.z-mu)*rs, wv.z, bv.z);
    o.w = fmaf((v.w-mu)*rs, wv.w, bv.w);
    *(float4*)(out + (size_t)row*D_MODEL + tid*4) = o;
}

extern "C" void kernel_launch(void* const* d_in, const int* in_sizes, int n_in,
                              void* d_out, int out_size, void* d_ws, size_t ws_size,
                              hipStream_t stream) {
    (void)in_sizes; (void)n_in; (void)out_size; (void)ws_size;
    const float* x      = (const float*)d_in[0];
    const float* in_w   = (const float*)d_in[1];
    const float* conv_w = (const float*)d_in[2];
    const float* conv_b = (const float*)d_in[3];
    const float* xp_w   = (const float*)d_in[4];
    const float* dtp_w  = (const float*)d_in[5];
    const float* dtp_b  = (const float*)d_in[6];
    const float* A_log  = (const float*)d_in[7];
    const float* Dd     = (const float*)d_in[8];
    const float* out_w  = (const float*)d_in[9];
    const float* nw     = (const float*)d_in[10];
    const float* nb     = (const float*)d_in[11];
    float* out = (float*)d_out;

    float* ws   = (float*)d_ws;
    float* xz   = ws;                              // BT*4096
    float* uc   = xz   + (size_t)BT*4096;          // BT*2048
    float* xdbl = uc   + (size_t)BT*2048;          // BT*96
    float* dtb  = xdbl + (size_t)BT*96;            // BT*2048
    float* ys   = dtb  + (size_t)BT*2048;          // BT*2048
    float* xcur = ys   + (size_t)BT*2048;          // BT*1024

    for (int i = 0; i < N_LAYERS; ++i){
        const float* xin = (i==0) ? x : xcur;
        // xz = xin @ in_w^T   (2048 x 4096 x K=1024)
        gemm_tn<0><<<dim3(64,32),256,0,stream>>>(
            xin, D_MODEL, in_w + (size_t)i*4096*D_MODEL, D_MODEL,
            xz, 4096, BT, 4096, D_MODEL, nullptr, nullptr);
        // uc = silu(causal_conv(u) + cb)
        conv_silu_k<<<(BT*D_INNER)/256,256,0,stream>>>(
            xz, conv_w + (size_t)i*D_INNER*D_CONV, conv_b + (size_t)i*D_INNER, uc);
        // x_dbl = uc @ xp_w^T  (2048 x 96 x K=2048)
        gemm_tn<0><<<dim3(2,32),256,0,stream>>>(
            uc, D_INNER, xp_w + (size_t)i*96*D_INNER, D_INNER,
            xdbl, 96, BT, 96, D_INNER, nullptr, nullptr);
        // dt = softplus(dt_r @ dtp_w^T + dtp_b)  (2048 x 2048 x K=64)
        gemm_tn<1><<<dim3(32,32),256,0,stream>>>(
            xdbl, 96, dtp_w + (size_t)i*D_INNER*DT_RANK, DT_RANK,
            dtb, D_INNER, BT, D_INNER, DT_RANK, dtp_b + (size_t)i*D_INNER, nullptr);
        // selective scan
        scan_k<<<(BB*D_INNER)/256,256,0,stream>>>(
            uc, dtb, xdbl, A_log + (size_t)i*D_INNER*D_STATE, ys);
        // y = (ys + uc*Dd) * silu(z)
        fin_y_k<<<(BT*D_INNER)/256,256,0,stream>>>(ys, uc, xz, Dd + (size_t)i*D_INNER);
        // xcur = y @ out_w^T + xin   (2048 x 1024 x K=2048)
        gemm_tn<2><<<dim3(16,32),256,0,stream>>>(
            ys, D_INNER, out_w + (size_t)i*D_MODEL*D_INNER, D_INNER,
            xcur, D_MODEL, BT, D_MODEL, D_INNER, nullptr, xin);
    }
    layernorm_k<<<BT,256,0,stream>>>(xcur, nw, nb, out);
}

// Round 2
// 2920.276 us; speedup vs baseline: 1.3704x; 1.3704x over previous
//
#include <hip/hip_runtime.h>
#include <hip/hip_bf16.h>

#define N_LAYERS 4
#define D_MODEL  1024
#define D_INNER  2048
#define D_STATE  16
#define D_CONV   4
#define DT_RANK  64
#define BB       2
#define TT       1024
#define BT       (BB*TT)   // 2048 rows (b*T)

__device__ __forceinline__ float sigmoidf_(float x){ return 1.f/(1.f+__expf(-x)); }
__device__ __forceinline__ float siluf_(float x){ return x*sigmoidf_(x); }
__device__ __forceinline__ float softplusf_(float x){ return fmaxf(x,0.f) + log1pf(__expf(-fabsf(x))); }

// C[M][N] = A[M][K] @ W[N][K]^T  (both row-major), 64x64 tile, BK=16, 4x4/thread.
// EPI: 0 = plain store, 1 = softplus(c + bias[n]), 2 = c + res[m*ldc+n]
template<int EPI>
__global__ __launch_bounds__(256) void gemm_tn(
    const float* __restrict__ A, int lda,
    const float* __restrict__ W, int ldw,
    float* __restrict__ C, int ldc,
    int M, int N, int K,
    const float* __restrict__ bias,
    const float* __restrict__ res)
{
    __shared__ float As[16][68];
    __shared__ float Ws[16][68];
    const int tid = threadIdx.x;
    const int tx = tid & 15, ty = tid >> 4;
    const int m0 = blockIdx.y * 64, n0 = blockIdx.x * 64;
    const int lr = tid >> 2;          // 0..63 tile row for staging
    const int lk = (tid & 3) << 2;    // 0,4,8,12 k-offset for staging
    float acc[4][4] = {{0.f}};

    for (int k0 = 0; k0 < K; k0 += 16) {
        float4 av = *(const float4*)(A + (size_t)(m0+lr)*lda + k0 + lk);
        float4 wv = make_float4(0.f,0.f,0.f,0.f);
        if (n0 + lr < N) wv = *(const float4*)(W + (size_t)(n0+lr)*ldw + k0 + lk);
        __syncthreads();
        As[lk+0][lr]=av.x; As[lk+1][lr]=av.y; As[lk+2][lr]=av.z; As[lk+3][lr]=av.w;
        Ws[lk+0][lr]=wv.x; Ws[lk+1][lr]=wv.y; Ws[lk+2][lr]=wv.z; Ws[lk+3][lr]=wv.w;
        __syncthreads();
        #pragma unroll
        for (int k = 0; k < 16; ++k) {
            float4 a = *(const float4*)&As[k][ty<<2];
            float4 b = *(const float4*)&Ws[k][tx<<2];
            float a4[4] = {a.x,a.y,a.z,a.w};
            float b4[4] = {b.x,b.y,b.z,b.w};
            #pragma unroll
            for (int i=0;i<4;++i)
                #pragma unroll
                for (int j=0;j<4;++j)
                    acc[i][j] = fmaf(a4[i], b4[j], acc[i][j]);
        }
    }

    #pragma unroll
    for (int i=0;i<4;++i){
        int m = m0 + (ty<<2) + i;
        #pragma unroll
        for (int j=0;j<4;++j){
            int n = n0 + (tx<<2) + j;
            if (n < N){
                float v = acc[i][j];
                if (EPI==1) v = softplusf_(v + bias[n]);
                if (EPI==2) v = v + res[(size_t)m*ldc + n];
                C[(size_t)m*ldc + n] = v;
            }
        }
    }
}

// Depthwise causal conv (K=4) + bias + SiLU. u = xz[..., :2048].
__global__ __launch_bounds__(256) void conv_silu_k(
    const float* __restrict__ xz, const float* __restrict__ cw,
    const float* __restrict__ cb, float* __restrict__ uc)
{
    int idx = blockIdx.x*256 + threadIdx.x;   // over BT*D_INNER
    int d  = idx & (D_INNER-1);
    int bt = idx >> 11;
    int t  = bt & (TT-1);
    float4 w4 = *(const float4*)(cw + d*4);
    float wv[4] = {w4.x, w4.y, w4.z, w4.w};
    float acc = cb[d];
    #pragma unroll
    for (int k=0;k<4;++k){
        int tt = t - 3 + k;
        if (tt >= 0) acc = fmaf(xz[(size_t)(bt-3+k)*4096 + d], wv[k], acc);
    }
    uc[idx] = siluf_(acc);
}

// Selective scan v2: 4 lanes per channel (4 states each), 64 channels/block,
// LDS-staged dt/u/B/C in 64-timestep chunks. Grid (D_INNER/64, B).
#define SC_TC  64
#define SC_NCH 64
__global__ __launch_bounds__(256) void scan2_k(
    const float* __restrict__ uc, const float* __restrict__ dt,
    const float* __restrict__ xdbl, const float* __restrict__ A_log,
    float* __restrict__ ys)
{
    __shared__ float sdt[SC_TC][SC_NCH];
    __shared__ float su [SC_TC][SC_NCH];
    __shared__ float sBC[SC_TC][32];
    const int tid = threadIdx.x;
    const int b  = blockIdx.y;            // 0..BB-1
    const int d0 = blockIdx.x * SC_NCH;   // channel base
    const int c  = tid >> 2;              // channel within block
    const int l  = tid & 3;               // state quad (states 4l..4l+3)
    const int d  = d0 + c;

    float A4[4];
    {
        float4 v = *(const float4*)(A_log + (size_t)d*D_STATE + l*4);
        A4[0]=-__expf(v.x); A4[1]=-__expf(v.y); A4[2]=-__expf(v.z); A4[3]=-__expf(v.w);
    }
    float h0=0.f,h1=0.f,h2=0.f,h3=0.f;
    const size_t rowbase = (size_t)b*TT;

    for (int t0 = 0; t0 < TT; t0 += SC_TC){
        __syncthreads();
        #pragma unroll
        for (int i = 0; i < 4; ++i){
            int idx = tid + i*256;               // 0..1023
            int r = idx >> 4, c4 = (idx & 15) << 2;
            size_t g = (rowbase + t0 + r)*D_INNER + d0 + c4;
            *(float4*)&sdt[r][c4] = *(const float4*)(dt + g);
            *(float4*)&su [r][c4] = *(const float4*)(uc + g);
        }
        #pragma unroll
        for (int i = 0; i < 2; ++i){
            int idx = tid + i*256;               // 0..511
            int r = idx >> 3, c4 = (idx & 7) << 2;
            *(float4*)&sBC[r][c4] = *(const float4*)(xdbl + (rowbase + t0 + r)*96 + 64 + c4);
        }
        __syncthreads();
        #pragma unroll 4
        for (int t = 0; t < SC_TC; ++t){
            float dtv = sdt[t][c];
            float uv  = su [t][c];
            float4 Bv = *(const float4*)&sBC[t][l*4];
            float4 Cv = *(const float4*)&sBC[t][16 + l*4];
            float du = dtv*uv;
            h0 = fmaf(__expf(dtv*A4[0]), h0, du*Bv.x);
            h1 = fmaf(__expf(dtv*A4[1]), h1, du*Bv.y);
            h2 = fmaf(__expf(dtv*A4[2]), h2, du*Bv.z);
            h3 = fmaf(__expf(dtv*A4[3]), h3, du*Bv.w);
            float yp = fmaf(h0,Cv.x, fmaf(h1,Cv.y, fmaf(h2,Cv.z, h3*Cv.w)));
            yp += __shfl_xor(yp, 1);
            yp += __shfl_xor(yp, 2);
            if (l == 0) ys[(rowbase + t0 + t)*D_INNER + d] = yp;
        }
    }
}

// y = (ys + uc*Dd[d]) * silu(z), in-place into ys. z = xz[..., 2048:].
__global__ __launch_bounds__(256) void fin_y_k(
    float* __restrict__ ys, const float* __restrict__ uc,
    const float* __restrict__ xz, const float* __restrict__ Dd)
{
    int idx = blockIdx.x*256 + threadIdx.x;
    int d  = idx & (D_INNER-1);
    int bt = idx >> 11;
    float z = xz[(size_t)bt*4096 + 2048 + d];
    ys[idx] = (ys[idx] + uc[idx]*Dd[d]) * siluf_(z);
}

__global__ __launch_bounds__(256) void layernorm_k(
    const float* __restrict__ X, const float* __restrict__ w,
    const float* __restrict__ b, float* __restrict__ out)
{
    int row = blockIdx.x;
    int tid = threadIdx.x;
    const float* xr = X + (size_t)row*D_MODEL;
    float4 v = *(const float4*)(xr + tid*4);
    float s  = v.x+v.y+v.z+v.w;
    float ss = fmaf(v.x,v.x, fmaf(v.y,v.y, fmaf(v.z,v.z, v.w*v.w)));
    #pragma unroll
    for (int off=32; off>0; off>>=1){
        s  += __shfl_down(s, off, 64);
        ss += __shfl_down(ss, off, 64);
    }
    __shared__ float red[8];
    int wid = tid>>6, lane = tid&63;
    if (lane==0){ red[wid]=s; red[4+wid]=ss; }
    __syncthreads();
    if (tid==0){
        float S  = red[0]+red[1]+red[2]+red[3];
        float SS = red[4]+red[5]+red[6]+red[7];
        float mu = S*(1.f/D_MODEL);
        float var = SS*(1.f/D_MODEL) - mu*mu;
        red[0]=mu; red[1]=rsqrtf(var + 1e-5f);
    }
    __syncthreads();
    float mu=red[0], rs=red[1];
    float4 wv = *(const float4*)(w + tid*4);
    float4 bv = *(const float4*)(b + tid*4);
    float4 o;
    o.x = fmaf((v.x-mu)*rs, wv.x, bv.x);
    o.y = fmaf((v.y-mu)*rs, wv.y, bv.y);
    o.z = fmaf((v.z-mu)*rs, wv.z, bv.z);
    o.w = fmaf((v.w-mu)*rs, wv.w, bv.w);
    *(float4*)(out + (size_t)row*D_MODEL + tid*4) = o;
}

extern "C" void kernel_launch(void* const* d_in, const int* in_sizes, int n_in,
                              void* d_out, int out_size, void* d_ws, size_t ws_size,
                              hipStream_t stream) {
    (void)in_sizes; (void)n_in; (void)out_size; (void)ws_size;
    const float* x      = (const float*)d_in[0];
    const float* in_w   = (const float*)d_in[1];
    const float* conv_w = (const float*)d_in[2];
    const float* conv_b = (const float*)d_in[3];
    const float* xp_w   = (const float*)d_in[4];
    const float* dtp_w  = (const float*)d_in[5];
    const float* dtp_b  = (const float*)d_in[6];
    const float* A_log  = (const float*)d_in[7];
    const float* Dd     = (const float*)d_in[8];
    const float* out_w  = (const float*)d_in[9];
    const float* nw     = (const float*)d_in[10];
    const float* nb     = (const float*)d_in[11];
    float* out = (float*)d_out;

    float* ws   = (float*)d_ws;
    float* xz   = ws;                              // BT*4096
    float* uc   = xz   + (size_t)BT*4096;          // BT*2048
    float* xdbl = uc   + (size_t)BT*2048;          // BT*96
    float* dtb  = xdbl + (size_t)BT*96;            // BT*2048
    float* ys   = dtb  + (size_t)BT*2048;          // BT*2048
    float* xcur = ys   + (size_t)BT*2048;          // BT*1024

    for (int i = 0; i < N_LAYERS; ++i){
        const float* xin = (i==0) ? x : xcur;
        // xz = xin @ in_w^T   (2048 x 4096 x K=1024)
        gemm_tn<0><<<dim3(64,32),256,0,stream>>>(
            xin, D_MODEL, in_w + (size_t)i*4096*D_MODEL, D_MODEL,
            xz, 4096, BT, 4096, D_MODEL, nullptr, nullptr);
        // uc = silu(causal_conv(u) + cb)
        conv_silu_k<<<(BT*D_INNER)/256,256,0,stream>>>(
            xz, conv_w + (size_t)i*D_INNER*D_CONV, conv_b + (size_t)i*D_INNER, uc);
        // x_dbl = uc @ xp_w^T  (2048 x 96 x K=2048)
        gemm_tn<0><<<dim3(2,32),256,0,stream>>>(
            uc, D_INNER, xp_w + (size_t)i*96*D_INNER, D_INNER,
            xdbl, 96, BT, 96, D_INNER, nullptr, nullptr);
        // dt = softplus(dt_r @ dtp_w^T + dtp_b)  (2048 x 2048 x K=64)
        gemm_tn<1><<<dim3(32,32),256,0,stream>>>(
            xdbl, 96, dtp_w + (size_t)i*D_INNER*DT_RANK, DT_RANK,
            dtb, D_INNER, BT, D_INNER, DT_RANK, dtp_b + (size_t)i*D_INNER, nullptr);
        // selective scan (state-parallel + LDS-chunked)
        scan2_k<<<dim3(D_INNER/SC_NCH, BB),256,0,stream>>>(
            uc, dtb, xdbl, A_log + (size_t)i*D_INNER*D_STATE, ys);
        // y = (ys + uc*Dd) * silu(z)
        fin_y_k<<<(BT*D_INNER)/256,256,0,stream>>>(ys, uc, xz, Dd + (size_t)i*D_INNER);
        // xcur = y @ out_w^T + xin   (2048 x 1024 x K=2048)
        gemm_tn<2><<<dim3(16,32),256,0,stream>>>(
            ys, D_INNER, out_w + (size_t)i*D_MODEL*D_INNER, D_INNER,
            xcur, D_MODEL, BT, D_MODEL, D_INNER, nullptr, xin);
    }
    layernorm_k<<<BT,256,0,stream>>>(xcur, nw, nb, out);
}

// Round 3
// 1966.621 us; speedup vs baseline: 2.0349x; 1.4849x over previous
//
#include <hip/hip_runtime.h>
#include <hip/hip_bf16.h>

#define N_LAYERS 4
#define D_MODEL  1024
#define D_INNER  2048
#define D_STATE  16
#define D_CONV   4
#define DT_RANK  64
#define BB       2
#define TT       1024
#define BT       (BB*TT)   // 2048 rows (b*T)

typedef unsigned short ushort_t;
typedef __attribute__((ext_vector_type(8))) short short8;
typedef __attribute__((ext_vector_type(4))) float f32x4;

__device__ __forceinline__ float sigmoidf_(float x){ return 1.f/(1.f+__expf(-x)); }
__device__ __forceinline__ float siluf_(float x){ return x*sigmoidf_(x); }
__device__ __forceinline__ float softplusf_(float x){ return fmaxf(x,0.f) + log1pf(__expf(-fabsf(x))); }
__device__ __forceinline__ ushort_t f2b(float f){
    unsigned int x = __builtin_bit_cast(unsigned int, f);
    unsigned int r = (x + 0x7fffu + ((x>>16)&1u)) >> 16;   // RNE
    return (ushort_t)r;
}

#define GLOAD(g, l) __builtin_amdgcn_global_load_lds( \
    (const __attribute__((address_space(1))) void*)(g), \
    (__attribute__((address_space(3))) void*)(l), 16, 0, 0)

// fp32 -> bf16 conversion, 4 elems/thread. n must be multiple of 1024.
__global__ __launch_bounds__(256) void f2b_k(const float* __restrict__ in,
                                             ushort_t* __restrict__ out, int n){
    int i = blockIdx.x*256 + threadIdx.x;
    float4 v = ((const float4*)in)[i];
    ushort4 o;
    o.x = f2b(v.x); o.y = f2b(v.y); o.z = f2b(v.z); o.w = f2b(v.w);
    ((ushort4*)out)[i] = o;
}

// bf16 MFMA GEMM: C[M][N] = A[M][K] @ W[N][K]^T, fp32 out.
// 128x128 tile, BK=32, 256 thr = 4 waves (2x2), wave = 64x64 via 4x4 16x16x32 frags.
// M,N multiples of 128; K multiple of 32. EPI: 0 plain, 2 = +res.
template<int EPI>
__global__ __launch_bounds__(256) void gemm_mfma(
    const ushort_t* __restrict__ A, const ushort_t* __restrict__ W,
    float* __restrict__ C, int M, int N, int K,
    const float* __restrict__ res)
{
    __shared__ ushort_t As[128*32];
    __shared__ ushort_t Ws[128*32];
    const int tid  = threadIdx.x;
    const int lane = tid & 63;
    const int wv   = tid >> 6;
    const int wm0  = (wv>>1)*64, wn0 = (wv&1)*64;
    const int m0 = blockIdx.y*128, n0 = blockIdx.x*128;
    const int r0 = tid>>2, ch = tid&3;          // staging: row, 16B-chunk

    f32x4 acc[4][4];
    #pragma unroll
    for (int i=0;i<4;++i)
        #pragma unroll
        for (int j=0;j<4;++j) acc[i][j] = (f32x4){0.f,0.f,0.f,0.f};

    const int row_a = lane & 15, kc = (lane>>4)*8;

    for (int k0 = 0; k0 < K; k0 += 32){
        const ushort_t* gA = A + (size_t)(m0+r0)*K + k0 + ch*8;
        const ushort_t* gW = W + (size_t)(n0+r0)*K + k0 + ch*8;
        GLOAD(gA,            (char*)As + tid*16);
        GLOAD(gA + 64*(size_t)K, (char*)As + tid*16 + 4096);
        GLOAD(gW,            (char*)Ws + tid*16);
        GLOAD(gW + 64*(size_t)K, (char*)Ws + tid*16 + 4096);
        __syncthreads();
        short8 af[4], bf[4];
        #pragma unroll
        for (int i=0;i<4;++i){
            af[i] = *(const short8*)&As[(wm0 + i*16 + row_a)*32 + kc];
            bf[i] = *(const short8*)&Ws[(wn0 + i*16 + row_a)*32 + kc];
        }
        #pragma unroll
        for (int i=0;i<4;++i)
            #pragma unroll
            for (int j=0;j<4;++j)
                acc[i][j] = __builtin_amdgcn_mfma_f32_16x16x32_bf16(af[i], bf[j], acc[i][j], 0,0,0);
        __syncthreads();
    }

    const int crow = (lane>>4)*4, ccol = lane & 15;
    #pragma unroll
    for (int i=0;i<4;++i){
        #pragma unroll
        for (int j=0;j<4;++j){
            #pragma unroll
            for (int r=0;r<4;++r){
                int m = m0 + wm0 + i*16 + crow + r;
                int n = n0 + wn0 + j*16 + ccol;
                float v = acc[i][j][r];
                if (EPI==2) v += res[(size_t)m*N + n];
                C[(size_t)m*N + n] = v;
            }
        }
    }
}

// fp32 GEMM (small ops): C[M][N] = A[M][K] @ W[N][K]^T, 64x64 tile, BK=16.
// EPI: 0 plain, 1 = softplus(c + bias[n])
template<int EPI>
__global__ __launch_bounds__(256) void gemm_tn(
    const float* __restrict__ A, int lda,
    const float* __restrict__ W, int ldw,
    float* __restrict__ C, int ldc,
    int M, int N, int K,
    const float* __restrict__ bias)
{
    __shared__ float As[16][68];
    __shared__ float Ws[16][68];
    const int tid = threadIdx.x;
    const int tx = tid & 15, ty = tid >> 4;
    const int m0 = blockIdx.y * 64, n0 = blockIdx.x * 64;
    const int lr = tid >> 2;
    const int lk = (tid & 3) << 2;
    float acc[4][4] = {{0.f}};

    for (int k0 = 0; k0 < K; k0 += 16) {
        float4 av = *(const float4*)(A + (size_t)(m0+lr)*lda + k0 + lk);
        float4 wv = make_float4(0.f,0.f,0.f,0.f);
        if (n0 + lr < N) wv = *(const float4*)(W + (size_t)(n0+lr)*ldw + k0 + lk);
        __syncthreads();
        As[lk+0][lr]=av.x; As[lk+1][lr]=av.y; As[lk+2][lr]=av.z; As[lk+3][lr]=av.w;
        Ws[lk+0][lr]=wv.x; Ws[lk+1][lr]=wv.y; Ws[lk+2][lr]=wv.z; Ws[lk+3][lr]=wv.w;
        __syncthreads();
        #pragma unroll
        for (int k = 0; k < 16; ++k) {
            float4 a = *(const float4*)&As[k][ty<<2];
            float4 b = *(const float4*)&Ws[k][tx<<2];
            float a4[4] = {a.x,a.y,a.z,a.w};
            float b4[4] = {b.x,b.y,b.z,b.w};
            #pragma unroll
            for (int i=0;i<4;++i)
                #pragma unroll
                for (int j=0;j<4;++j)
                    acc[i][j] = fmaf(a4[i], b4[j], acc[i][j]);
        }
    }

    #pragma unroll
    for (int i=0;i<4;++i){
        int m = m0 + (ty<<2) + i;
        #pragma unroll
        for (int j=0;j<4;++j){
            int n = n0 + (tx<<2) + j;
            if (n < N){
                float v = acc[i][j];
                if (EPI==1) v = softplusf_(v + bias[n]);
                C[(size_t)m*ldc + n] = v;
            }
        }
    }
}

// Depthwise causal conv (K=4) + bias + SiLU. u = xz[..., :2048].
__global__ __launch_bounds__(256) void conv_silu_k(
    const float* __restrict__ xz, const float* __restrict__ cw,
    const float* __restrict__ cb, float* __restrict__ uc)
{
    int idx = blockIdx.x*256 + threadIdx.x;
    int d  = idx & (D_INNER-1);
    int bt = idx >> 11;
    int t  = bt & (TT-1);
    float4 w4 = *(const float4*)(cw + d*4);
    float wv[4] = {w4.x, w4.y, w4.z, w4.w};
    float acc = cb[d];
    #pragma unroll
    for (int k=0;k<4;++k){
        int tt = t - 3 + k;
        if (tt >= 0) acc = fmaf(xz[(size_t)(bt-3+k)*4096 + d], wv[k], acc);
    }
    uc[idx] = siluf_(acc);
}

// Selective scan + fused finalize: 4 lanes/channel (4 states each), 64 ch/block.
// LDS-staged dt/u/z/B/C in 64-step chunks. Writes ys as bf16:
// ysb = (scan_y + u*Dd) * silu(z). Grid (D_INNER/64, B).
#define SC_TC  64
#define SC_NCH 64
__global__ __launch_bounds__(256) void scan2_k(
    const float* __restrict__ uc, const float* __restrict__ dt,
    const float* __restrict__ xdbl, const float* __restrict__ A_log,
    const float* __restrict__ xz, const float* __restrict__ Dd,
    ushort_t* __restrict__ ysb)
{
    __shared__ float sdt[SC_TC][SC_NCH];
    __shared__ float su [SC_TC][SC_NCH];
    __shared__ float sz [SC_TC][SC_NCH];
    __shared__ float sBC[SC_TC][32];
    const int tid = threadIdx.x;
    const int b  = blockIdx.y;
    const int d0 = blockIdx.x * SC_NCH;
    const int c  = tid >> 2;
    const int l  = tid & 3;
    const int d  = d0 + c;

    float A4[4];
    {
        float4 v = *(const float4*)(A_log + (size_t)d*D_STATE + l*4);
        A4[0]=-__expf(v.x); A4[1]=-__expf(v.y); A4[2]=-__expf(v.z); A4[3]=-__expf(v.w);
    }
    const float Ddc = Dd[d];
    float h0=0.f,h1=0.f,h2=0.f,h3=0.f;
    const size_t rowbase = (size_t)b*TT;

    for (int t0 = 0; t0 < TT; t0 += SC_TC){
        __syncthreads();
        #pragma unroll
        for (int i = 0; i < 4; ++i){
            int idx = tid + i*256;
            int r = idx >> 4, c4 = (idx & 15) << 2;
            size_t g = (rowbase + t0 + r)*D_INNER + d0 + c4;
            *(float4*)&sdt[r][c4] = *(const float4*)(dt + g);
            *(float4*)&su [r][c4] = *(const float4*)(uc + g);
            *(float4*)&sz [r][c4] = *(const float4*)(xz + (rowbase + t0 + r)*4096 + 2048 + d0 + c4);
        }
        #pragma unroll
        for (int i = 0; i < 2; ++i){
            int idx = tid + i*256;
            int r = idx >> 3, c4 = (idx & 7) << 2;
            *(float4*)&sBC[r][c4] = *(const float4*)(xdbl + (rowbase + t0 + r)*96 + 64 + c4);
        }
        __syncthreads();
        #pragma unroll 4
        for (int t = 0; t < SC_TC; ++t){
            float dtv = sdt[t][c];
            float uv  = su [t][c];
            float4 Bv = *(const float4*)&sBC[t][l*4];
            float4 Cv = *(const float4*)&sBC[t][16 + l*4];
            float du = dtv*uv;
            h0 = fmaf(__expf(dtv*A4[0]), h0, du*Bv.x);
            h1 = fmaf(__expf(dtv*A4[1]), h1, du*Bv.y);
            h2 = fmaf(__expf(dtv*A4[2]), h2, du*Bv.z);
            h3 = fmaf(__expf(dtv*A4[3]), h3, du*Bv.w);
            float yp = fmaf(h0,Cv.x, fmaf(h1,Cv.y, fmaf(h2,Cv.z, h3*Cv.w)));
            yp += __shfl_xor(yp, 1);
            yp += __shfl_xor(yp, 2);
            if (l == 0){
                float yv = (yp + uv*Ddc) * siluf_(sz[t][c]);
                ysb[(rowbase + t0 + t)*D_INNER + d] = f2b(yv);
            }
        }
    }
}

__global__ __launch_bounds__(256) void layernorm_k(
    const float* __restrict__ X, const float* __restrict__ w,
    const float* __restrict__ b, float* __restrict__ out)
{
    int row = blockIdx.x;
    int tid = threadIdx.x;
    const float* xr = X + (size_t)row*D_MODEL;
    float4 v = *(const float4*)(xr + tid*4);
    float s  = v.x+v.y+v.z+v.w;
    float ss = fmaf(v.x,v.x, fmaf(v.y,v.y, fmaf(v.z,v.z, v.w*v.w)));
    #pragma unroll
    for (int off=32; off>0; off>>=1){
        s  += __shfl_down(s, off, 64);
        ss += __shfl_down(ss, off, 64);
    }
    __shared__ float red[8];
    int wid = tid>>6, lane = tid&63;
    if (lane==0){ red[wid]=s; red[4+wid]=ss; }
    __syncthreads();
    if (tid==0){
        float S  = red[0]+red[1]+red[2]+red[3];
        float SS = red[4]+red[5]+red[6]+red[7];
        float mu = S*(1.f/D_MODEL);
        float var = SS*(1.f/D_MODEL) - mu*mu;
        red[0]=mu; red[1]=rsqrtf(var + 1e-5f);
    }
    __syncthreads();
    float mu=red[0], rs=red[1];
    float4 wv = *(const float4*)(w + tid*4);
    float4 bv = *(const float4*)(b + tid*4);
    float4 o;
    o.x = fmaf((v.x-mu)*rs, wv.x, bv.x);
    o.y = fmaf((v.y-mu)*rs, wv.y, bv.y);
    o.z = fmaf((v.z-mu)*rs, wv.z, bv.z);
    o.w = fmaf((v.w-mu)*rs, wv.w, bv.w);
    *(float4*)(out + (size_t)row*D_MODEL + tid*4) = o;
}

extern "C" void kernel_launch(void* const* d_in, const int* in_sizes, int n_in,
                              void* d_out, int out_size, void* d_ws, size_t ws_size,
                              hipStream_t stream) {
    (void)in_sizes; (void)n_in; (void)out_size; (void)ws_size;
    const float* x      = (const float*)d_in[0];
    const float* in_w   = (const float*)d_in[1];
    const float* conv_w = (const float*)d_in[2];
    const float* conv_b = (const float*)d_in[3];
    const float* xp_w   = (const float*)d_in[4];
    const float* dtp_w  = (const float*)d_in[5];
    const float* dtp_b  = (const float*)d_in[6];
    const float* A_log  = (const float*)d_in[7];
    const float* Dd     = (const float*)d_in[8];
    const float* out_w  = (const float*)d_in[9];
    const float* nw     = (const float*)d_in[10];
    const float* nb     = (const float*)d_in[11];
    float* out = (float*)d_out;

    char* p = (char*)d_ws;
    float* xz      = (float*)p;  p += (size_t)BT*4096*4;   // 32 MB
    float* uc      = (float*)p;  p += (size_t)BT*2048*4;   // 16 MB
    float* xdbl    = (float*)p;  p += (size_t)BT*96*4;     // 768 KB
    float* dtb     = (float*)p;  p += (size_t)BT*2048*4;   // 16 MB
    float* xcur    = (float*)p;  p += (size_t)BT*1024*4;   // 8 MB
    ushort_t* xinb = (ushort_t*)p; p += (size_t)BT*1024*2; // 4 MB
    ushort_t* ysb  = (ushort_t*)p; p += (size_t)BT*2048*2; // 8 MB
    ushort_t* winb = (ushort_t*)p; p += (size_t)4096*1024*2; // 8 MB
    ushort_t* woutb= (ushort_t*)p; p += (size_t)1024*2048*2; // 4 MB

    for (int i = 0; i < N_LAYERS; ++i){
        const float* xin = (i==0) ? x : xcur;
        // bf16 conversions for this layer
        f2b_k<<<(BT*1024)/1024,256,0,stream>>>(xin, xinb, BT*1024);
        f2b_k<<<(4096*1024)/1024,256,0,stream>>>(in_w + (size_t)i*4096*D_MODEL, winb, 4096*1024);
        f2b_k<<<(1024*2048)/1024,256,0,stream>>>(out_w + (size_t)i*D_MODEL*D_INNER, woutb, 1024*2048);
        // xz = xin @ in_w^T   (2048 x 4096 x K=1024), bf16 MFMA
        gemm_mfma<0><<<dim3(4096/128, BT/128),256,0,stream>>>(
            xinb, winb, xz, BT, 4096, D_MODEL, nullptr);
        // uc = silu(causal_conv(u) + cb)
        conv_silu_k<<<(BT*D_INNER)/256,256,0,stream>>>(
            xz, conv_w + (size_t)i*D_INNER*D_CONV, conv_b + (size_t)i*D_INNER, uc);
        // x_dbl = uc @ xp_w^T  (2048 x 96 x K=2048), fp32
        gemm_tn<0><<<dim3(2,32),256,0,stream>>>(
            uc, D_INNER, xp_w + (size_t)i*96*D_INNER, D_INNER,
            xdbl, 96, BT, 96, D_INNER, nullptr);
        // dt = softplus(dt_r @ dtp_w^T + dtp_b)  (2048 x 2048 x K=64), fp32
        gemm_tn<1><<<dim3(32,32),256,0,stream>>>(
            xdbl, 96, dtp_w + (size_t)i*D_INNER*DT_RANK, DT_RANK,
            dtb, D_INNER, BT, D_INNER, DT_RANK, dtp_b + (size_t)i*D_INNER);
        // selective scan + fused (y + u*D)*silu(z), bf16 out
        scan2_k<<<dim3(D_INNER/SC_NCH, BB),256,0,stream>>>(
            uc, dtb, xdbl, A_log + (size_t)i*D_INNER*D_STATE, xz,
            Dd + (size_t)i*D_INNER, ysb);
        // xcur = ys @ out_w^T + xin   (2048 x 1024 x K=2048), bf16 MFMA + residual
        gemm_mfma<2><<<dim3(1024/128, BT/128),256,0,stream>>>(
            ysb, woutb, xcur, BT, 1024, D_INNER, xin);
    }
    layernorm_k<<<BT,256,0,stream>>>(xcur, nw, nb, out);
}

// Round 4
// 1199.993 us; speedup vs baseline: 3.3349x; 1.6389x over previous
//
#include <hip/hip_runtime.h>
#include <hip/hip_bf16.h>

#define N_LAYERS 4
#define D_MODEL  1024
#define D_INNER  2048
#define D_STATE  16
#define D_CONV   4
#define DT_RANK  64
#define BB       2
#define TT       1024
#define BT       (BB*TT)   // 2048 rows (b*T)

#define NCHUNK 16
#define SCTC   (TT/NCHUNK)   // 64 timesteps per chunk

typedef unsigned short ushort_t;
typedef __attribute__((ext_vector_type(8))) short short8;
typedef __attribute__((ext_vector_type(4))) float f32x4;

__device__ __forceinline__ float sigmoidf_(float x){ return 1.f/(1.f+__expf(-x)); }
__device__ __forceinline__ float siluf_(float x){ return x*sigmoidf_(x); }
__device__ __forceinline__ float softplusf_(float x){ return fmaxf(x,0.f) + log1pf(__expf(-fabsf(x))); }
__device__ __forceinline__ ushort_t f2b(float f){
    unsigned int x = __builtin_bit_cast(unsigned int, f);
    unsigned int r = (x + 0x7fffu + ((x>>16)&1u)) >> 16;   // RNE
    return (ushort_t)r;
}

#define GLOAD(g, l) __builtin_amdgcn_global_load_lds( \
    (const __attribute__((address_space(1))) void*)(g), \
    (__attribute__((address_space(3))) void*)(l), 16, 0, 0)

// fp32 -> bf16 conversion, 4 elems/thread.
__global__ __launch_bounds__(256) void f2b_k(const float* __restrict__ in,
                                             ushort_t* __restrict__ out, int n){
    int i = blockIdx.x*256 + threadIdx.x;
    float4 v = ((const float4*)in)[i];
    ushort4 o;
    o.x = f2b(v.x); o.y = f2b(v.y); o.z = f2b(v.z); o.w = f2b(v.w);
    ((ushort4*)out)[i] = o;
}

// bf16 MFMA GEMM: C[M][N] = A[M][K] @ W[N][K]^T, fp32 out.
// 128x128 tile, BK=32, 4 waves (2x2), wave = 64x64 via 4x4 16x16x32 frags.
template<int EPI>
__global__ __launch_bounds__(256) void gemm_mfma(
    const ushort_t* __restrict__ A, const ushort_t* __restrict__ W,
    float* __restrict__ C, int M, int N, int K,
    const float* __restrict__ res)
{
    __shared__ ushort_t As[128*32];
    __shared__ ushort_t Ws[128*32];
    const int tid  = threadIdx.x;
    const int lane = tid & 63;
    const int wv   = tid >> 6;
    const int wm0  = (wv>>1)*64, wn0 = (wv&1)*64;
    const int m0 = blockIdx.y*128, n0 = blockIdx.x*128;
    const int r0 = tid>>2, ch = tid&3;

    f32x4 acc[4][4];
    #pragma unroll
    for (int i=0;i<4;++i)
        #pragma unroll
        for (int j=0;j<4;++j) acc[i][j] = (f32x4){0.f,0.f,0.f,0.f};

    const int row_a = lane & 15, kc = (lane>>4)*8;

    for (int k0 = 0; k0 < K; k0 += 32){
        const ushort_t* gA = A + (size_t)(m0+r0)*K + k0 + ch*8;
        const ushort_t* gW = W + (size_t)(n0+r0)*K + k0 + ch*8;
        GLOAD(gA,            (char*)As + tid*16);
        GLOAD(gA + 64*(size_t)K, (char*)As + tid*16 + 4096);
        GLOAD(gW,            (char*)Ws + tid*16);
        GLOAD(gW + 64*(size_t)K, (char*)Ws + tid*16 + 4096);
        __syncthreads();
        short8 af[4], bf[4];
        #pragma unroll
        for (int i=0;i<4;++i){
            af[i] = *(const short8*)&As[(wm0 + i*16 + row_a)*32 + kc];
            bf[i] = *(const short8*)&Ws[(wn0 + i*16 + row_a)*32 + kc];
        }
        #pragma unroll
        for (int i=0;i<4;++i)
            #pragma unroll
            for (int j=0;j<4;++j)
                acc[i][j] = __builtin_amdgcn_mfma_f32_16x16x32_bf16(af[i], bf[j], acc[i][j], 0,0,0);
        __syncthreads();
    }

    const int crow = (lane>>4)*4, ccol = lane & 15;
    #pragma unroll
    for (int i=0;i<4;++i){
        #pragma unroll
        for (int j=0;j<4;++j){
            #pragma unroll
            for (int r=0;r<4;++r){
                int m = m0 + wm0 + i*16 + crow + r;
                int n = n0 + wn0 + j*16 + ccol;
                float v = acc[i][j][r];
                if (EPI==2) v += res[(size_t)m*N + n];
                C[(size_t)m*N + n] = v;
            }
        }
    }
}

// fp32 GEMM (small ops): C[M][N] = A[M][K] @ W[N][K]^T, 64x64 tile, BK=16.
// EPI: 0 plain, 1 = softplus(c + bias[n])
template<int EPI>
__global__ __launch_bounds__(256) void gemm_tn(
    const float* __restrict__ A, int lda,
    const float* __restrict__ W, int ldw,
    float* __restrict__ C, int ldc,
    int M, int N, int K,
    const float* __restrict__ bias)
{
    __shared__ float As[16][68];
    __shared__ float Ws[16][68];
    const int tid = threadIdx.x;
    const int tx = tid & 15, ty = tid >> 4;
    const int m0 = blockIdx.y * 64, n0 = blockIdx.x * 64;
    const int lr = tid >> 2;
    const int lk = (tid & 3) << 2;
    float acc[4][4] = {{0.f}};

    for (int k0 = 0; k0 < K; k0 += 16) {
        float4 av = *(const float4*)(A + (size_t)(m0+lr)*lda + k0 + lk);
        float4 wv = make_float4(0.f,0.f,0.f,0.f);
        if (n0 + lr < N) wv = *(const float4*)(W + (size_t)(n0+lr)*ldw + k0 + lk);
        __syncthreads();
        As[lk+0][lr]=av.x; As[lk+1][lr]=av.y; As[lk+2][lr]=av.z; As[lk+3][lr]=av.w;
        Ws[lk+0][lr]=wv.x; Ws[lk+1][lr]=wv.y; Ws[lk+2][lr]=wv.z; Ws[lk+3][lr]=wv.w;
        __syncthreads();
        #pragma unroll
        for (int k = 0; k < 16; ++k) {
            float4 a = *(const float4*)&As[k][ty<<2];
            float4 b = *(const float4*)&Ws[k][tx<<2];
            float a4[4] = {a.x,a.y,a.z,a.w};
            float b4[4] = {b.x,b.y,b.z,b.w};
            #pragma unroll
            for (int i=0;i<4;++i)
                #pragma unroll
                for (int j=0;j<4;++j)
                    acc[i][j] = fmaf(a4[i], b4[j], acc[i][j]);
        }
    }

    #pragma unroll
    for (int i=0;i<4;++i){
        int m = m0 + (ty<<2) + i;
        #pragma unroll
        for (int j=0;j<4;++j){
            int n = n0 + (tx<<2) + j;
            if (n < N){
                float v = acc[i][j];
                if (EPI==1) v = softplusf_(v + bias[n]);
                C[(size_t)m*ldc + n] = v;
            }
        }
    }
}

// Depthwise causal conv (K=4) + bias + SiLU. u = xz[..., :2048].
__global__ __launch_bounds__(256) void conv_silu_k(
    const float* __restrict__ xz, const float* __restrict__ cw,
    const float* __restrict__ cb, float* __restrict__ uc)
{
    int idx = blockIdx.x*256 + threadIdx.x;
    int d  = idx & (D_INNER-1);
    int bt = idx >> 11;
    int t  = bt & (TT-1);
    float4 w4 = *(const float4*)(cw + d*4);
    float wv[4] = {w4.x, w4.y, w4.z, w4.w};
    float acc = cb[d];
    #pragma unroll
    for (int k=0;k<4;++k){
        int tt = t - 3 + k;
        if (tt >= 0) acc = fmaf(xz[(size_t)(bt-3+k)*4096 + d], wv[k], acc);
    }
    uc[idx] = siluf_(acc);
}

// ---- Chunked selective scan, 3 phases. Lane = channel, 16 states in regs. ----

// Phase 1: per-chunk partial scan from h=0. Emits h_partial[16] and
// decay[16] = exp(A * sum(dt)) per (chunk,b,d). Grid (D_INNER/256, BB, NCHUNK).
__global__ __launch_bounds__(256) void scan_p1(
    const float* __restrict__ dt, const float* __restrict__ uc,
    const float* __restrict__ xdbl, const float* __restrict__ A_log,
    float* __restrict__ hpart, float* __restrict__ hdecay)
{
    const int tid = threadIdx.x;
    const int d = blockIdx.x*256 + tid;
    const int b = blockIdx.y;
    const int k = blockIdx.z;
    const int t0 = k*SCTC;
    float A[16];
    #pragma unroll
    for (int q=0;q<4;++q){
        float4 v = *(const float4*)(A_log + (size_t)d*16 + q*4);
        A[q*4+0]=-__expf(v.x); A[q*4+1]=-__expf(v.y);
        A[q*4+2]=-__expf(v.z); A[q*4+3]=-__expf(v.w);
    }
    float h[16];
    #pragma unroll
    for (int s=0;s<16;++s) h[s]=0.f;
    float sumdt = 0.f;
    const float* dtp = dt + ((size_t)b*TT + t0)*D_INNER + d;
    const float* ucp = uc + ((size_t)b*TT + t0)*D_INNER + d;
    const float* bcp = xdbl + ((size_t)b*TT + t0)*96 + 64;
    #pragma unroll 2
    for (int t=0;t<SCTC;++t){
        float dtv = dtp[(size_t)t*D_INNER];
        float uv  = ucp[(size_t)t*D_INNER];
        const float* bc = bcp + (size_t)t*96;
        float du = dtv*uv;
        sumdt += dtv;
        #pragma unroll
        for (int s=0;s<16;++s)
            h[s] = fmaf(__expf(dtv*A[s]), h[s], du*bc[s]);
    }
    size_t base = ((size_t)(k*BB+b)*D_INNER + d)*16;
    float4* hp = (float4*)(hpart + base);
    float4* hd = (float4*)(hdecay + base);
    #pragma unroll
    for (int q=0;q<4;++q){
        hp[q] = make_float4(h[q*4],h[q*4+1],h[q*4+2],h[q*4+3]);
        hd[q] = make_float4(__expf(sumdt*A[q*4+0]),__expf(sumdt*A[q*4+1]),
                            __expf(sumdt*A[q*4+2]),__expf(sumdt*A[q*4+3]));
    }
}

// Phase 2: stitch chunk states. Thread per (b,d,s); sequential over chunks.
// hstart[k] = h_end[k-1]; h_end[k] = decay[k]*h_start[k] + hpart[k].
__global__ __launch_bounds__(256) void scan_fix(
    const float* __restrict__ hpart, const float* __restrict__ hdecay,
    float* __restrict__ hstart)
{
    int g = blockIdx.x*256 + threadIdx.x;     // b*(D_INNER*16) + d*16 + s
    float h = 0.f;
    #pragma unroll
    for (int k=0;k<NCHUNK;++k){
        size_t idx = (size_t)k*(BB*D_INNER*16) + g;
        hstart[idx] = h;
        h = fmaf(hdecay[idx], h, hpart[idx]);
    }
}

// Phase 3: rescan chunk from true h_start; y = C.h, fused
// out = (y + u*Dd)*silu(z) -> bf16. Grid (D_INNER/256, BB, NCHUNK).
__global__ __launch_bounds__(256) void scan_p3(
    const float* __restrict__ dt, const float* __restrict__ uc,
    const float* __restrict__ xdbl, const float* __restrict__ A_log,
    const float* __restrict__ xz, const float* __restrict__ Dd,
    const float* __restrict__ hstart, ushort_t* __restrict__ ysb)
{
    const int tid = threadIdx.x;
    const int d = blockIdx.x*256 + tid;
    const int b = blockIdx.y;
    const int k = blockIdx.z;
    const int t0 = k*SCTC;
    float A[16];
    #pragma unroll
    for (int q=0;q<4;++q){
        float4 v = *(const float4*)(A_log + (size_t)d*16 + q*4);
        A[q*4+0]=-__expf(v.x); A[q*4+1]=-__expf(v.y);
        A[q*4+2]=-__expf(v.z); A[q*4+3]=-__expf(v.w);
    }
    float h[16];
    {
        const float4* hs = (const float4*)(hstart + ((size_t)(k*BB+b)*D_INNER + d)*16);
        #pragma unroll
        for (int q=0;q<4;++q){
            float4 v = hs[q];
            h[q*4+0]=v.x; h[q*4+1]=v.y; h[q*4+2]=v.z; h[q*4+3]=v.w;
        }
    }
    const float Ddc = Dd[d];
    const float* dtp = dt + ((size_t)b*TT + t0)*D_INNER + d;
    const float* ucp = uc + ((size_t)b*TT + t0)*D_INNER + d;
    const float* zp  = xz + ((size_t)b*TT + t0)*4096 + 2048 + d;
    const float* bcp = xdbl + ((size_t)b*TT + t0)*96 + 64;
    ushort_t* yp = ysb + ((size_t)b*TT + t0)*D_INNER + d;
    #pragma unroll 2
    for (int t=0;t<SCTC;++t){
        float dtv = dtp[(size_t)t*D_INNER];
        float uv  = ucp[(size_t)t*D_INNER];
        float zv  = zp [(size_t)t*4096];
        const float* bc = bcp + (size_t)t*96;
        float du = dtv*uv;
        float y0=0.f,y1=0.f,y2=0.f,y3=0.f;
        #pragma unroll
        for (int q=0;q<4;++q){
            h[q*4+0] = fmaf(__expf(dtv*A[q*4+0]), h[q*4+0], du*bc[q*4+0]);
            h[q*4+1] = fmaf(__expf(dtv*A[q*4+1]), h[q*4+1], du*bc[q*4+1]);
            h[q*4+2] = fmaf(__expf(dtv*A[q*4+2]), h[q*4+2], du*bc[q*4+2]);
            h[q*4+3] = fmaf(__expf(dtv*A[q*4+3]), h[q*4+3], du*bc[q*4+3]);
        }
        #pragma unroll
        for (int q=0;q<4;++q){
            y0 = fmaf(h[q*4+0], bc[16+q*4+0], y0);
            y1 = fmaf(h[q*4+1], bc[16+q*4+1], y1);
            y2 = fmaf(h[q*4+2], bc[16+q*4+2], y2);
            y3 = fmaf(h[q*4+3], bc[16+q*4+3], y3);
        }
        float y = (y0+y1)+(y2+y3);
        float yv = (y + uv*Ddc) * siluf_(zv);
        yp[(size_t)t*D_INNER] = f2b(yv);
    }
}

__global__ __launch_bounds__(256) void layernorm_k(
    const float* __restrict__ X, const float* __restrict__ w,
    const float* __restrict__ b, float* __restrict__ out)
{
    int row = blockIdx.x;
    int tid = threadIdx.x;
    const float* xr = X + (size_t)row*D_MODEL;
    float4 v = *(const float4*)(xr + tid*4);
    float s  = v.x+v.y+v.z+v.w;
    float ss = fmaf(v.x,v.x, fmaf(v.y,v.y, fmaf(v.z,v.z, v.w*v.w)));
    #pragma unroll
    for (int off=32; off>0; off>>=1){
        s  += __shfl_down(s, off, 64);
        ss += __shfl_down(ss, off, 64);
    }
    __shared__ float red[8];
    int wid = tid>>6, lane = tid&63;
    if (lane==0){ red[wid]=s; red[4+wid]=ss; }
    __syncthreads();
    if (tid==0){
        float S  = red[0]+red[1]+red[2]+red[3];
        float SS = red[4]+red[5]+red[6]+red[7];
        float mu = S*(1.f/D_MODEL);
        float var = SS*(1.f/D_MODEL) - mu*mu;
        red[0]=mu; red[1]=rsqrtf(var + 1e-5f);
    }
    __syncthreads();
    float mu=red[0], rs=red[1];
    float4 wv = *(const float4*)(w + tid*4);
    float4 bv = *(const float4*)(b + tid*4);
    float4 o;
    o.x = fmaf((v.x-mu)*rs, wv.x, bv.x);
    o.y = fmaf((v.y-mu)*rs, wv.y, bv.y);
    o.z = fmaf((v.z-mu)*rs, wv.z, bv.z);
    o.w = fmaf((v.w-mu)*rs, wv.w, bv.w);
    *(float4*)(out + (size_t)row*D_MODEL + tid*4) = o;
}

extern "C" void kernel_launch(void* const* d_in, const int* in_sizes, int n_in,
                              void* d_out, int out_size, void* d_ws, size_t ws_size,
                              hipStream_t stream) {
    (void)in_sizes; (void)n_in; (void)out_size; (void)ws_size;
    const float* x      = (const float*)d_in[0];
    const float* in_w   = (const float*)d_in[1];
    const float* conv_w = (const float*)d_in[2];
    const float* conv_b = (const float*)d_in[3];
    const float* xp_w   = (const float*)d_in[4];
    const float* dtp_w  = (const float*)d_in[5];
    const float* dtp_b  = (const float*)d_in[6];
    const float* A_log  = (const float*)d_in[7];
    const float* Dd     = (const float*)d_in[8];
    const float* out_w  = (const float*)d_in[9];
    const float* nw     = (const float*)d_in[10];
    const float* nb     = (const float*)d_in[11];
    float* out = (float*)d_out;

    char* p = (char*)d_ws;
    float* xz      = (float*)p;  p += (size_t)BT*4096*4;   // 32 MB
    float* uc      = (float*)p;  p += (size_t)BT*2048*4;   // 16 MB
    float* xdbl    = (float*)p;  p += (size_t)BT*96*4;     // 768 KB
    float* dtb     = (float*)p;  p += (size_t)BT*2048*4;   // 16 MB
    float* xcur    = (float*)p;  p += (size_t)BT*1024*4;   // 8 MB
    ushort_t* xinb = (ushort_t*)p; p += (size_t)BT*1024*2; // 4 MB
    ushort_t* ysb  = (ushort_t*)p; p += (size_t)BT*2048*2; // 8 MB
    ushort_t* winb = (ushort_t*)p; p += (size_t)4096*1024*2; // 8 MB
    ushort_t* woutb= (ushort_t*)p; p += (size_t)1024*2048*2; // 4 MB

    // Scan chunk-state buffers alias winb (8 MB) + xinb (4 MB): both are dead
    // between the in_proj GEMM (their last read) and the next layer's f2b
    // (their next write); the scan runs entirely inside that window.
    float* hpart  = (float*)winb;                                  // 4 MB
    float* hdecay = hpart + (size_t)NCHUNK*BB*D_INNER*16;          // 4 MB
    float* hstart = (float*)xinb;                                  // 4 MB

    for (int i = 0; i < N_LAYERS; ++i){
        const float* xin = (i==0) ? x : xcur;
        // bf16 conversions for this layer
        f2b_k<<<(BT*1024)/1024,256,0,stream>>>(xin, xinb, BT*1024);
        f2b_k<<<(4096*1024)/1024,256,0,stream>>>(in_w + (size_t)i*4096*D_MODEL, winb, 4096*1024);
        f2b_k<<<(1024*2048)/1024,256,0,stream>>>(out_w + (size_t)i*D_MODEL*D_INNER, woutb, 1024*2048);
        // xz = xin @ in_w^T   (2048 x 4096 x K=1024), bf16 MFMA
        gemm_mfma<0><<<dim3(4096/128, BT/128),256,0,stream>>>(
            xinb, winb, xz, BT, 4096, D_MODEL, nullptr);
        // uc = silu(causal_conv(u) + cb)
        conv_silu_k<<<(BT*D_INNER)/256,256,0,stream>>>(
            xz, conv_w + (size_t)i*D_INNER*D_CONV, conv_b + (size_t)i*D_INNER, uc);
        // x_dbl = uc @ xp_w^T  (2048 x 96 x K=2048), fp32
        gemm_tn<0><<<dim3(2,32),256,0,stream>>>(
            uc, D_INNER, xp_w + (size_t)i*96*D_INNER, D_INNER,
            xdbl, 96, BT, 96, D_INNER, nullptr);
        // dt = softplus(dt_r @ dtp_w^T + dtp_b)  (2048 x 2048 x K=64), fp32
        gemm_tn<1><<<dim3(32,32),256,0,stream>>>(
            xdbl, 96, dtp_w + (size_t)i*D_INNER*DT_RANK, DT_RANK,
            dtb, D_INNER, BT, D_INNER, DT_RANK, dtp_b + (size_t)i*D_INNER);
        // chunked selective scan + fused (y + u*D)*silu(z) -> bf16
        scan_p1<<<dim3(D_INNER/256, BB, NCHUNK),256,0,stream>>>(
            dtb, uc, xdbl, A_log + (size_t)i*D_INNER*D_STATE, hpart, hdecay);
        scan_fix<<<(BB*D_INNER*16)/256,256,0,stream>>>(hpart, hdecay, hstart);
        scan_p3<<<dim3(D_INNER/256, BB, NCHUNK),256,0,stream>>>(
            dtb, uc, xdbl, A_log + (size_t)i*D_INNER*D_STATE, xz,
            Dd + (size_t)i*D_INNER, hstart, ysb);
        // xcur = ys @ out_w^T + xin   (2048 x 1024 x K=2048), bf16 MFMA + residual
        gemm_mfma<2><<<dim3(1024/128, BT/128),256,0,stream>>>(
            ysb, woutb, xcur, BT, 1024, D_INNER, xin);
    }
    layernorm_k<<<BT,256,0,stream>>>(xcur, nw, nb, out);
}

// Round 5
// 917.264 us; speedup vs baseline: 4.3628x; 1.3082x over previous
//
#include <hip/hip_runtime.h>
#include <hip/hip_bf16.h>

#define N_LAYERS 4
#define D_MODEL  1024
#define D_INNER  2048
#define D_STATE  16
#define D_CONV   4
#define DT_RANK  64
#define BB       2
#define TT       1024
#define BT       (BB*TT)   // 2048 rows (b*T)

#define NCHUNK 16
#define SCTC   (TT/NCHUNK)   // 64 timesteps per chunk

#define XP_KS  8             // x_proj K-split factor

typedef unsigned short ushort_t;
typedef __attribute__((ext_vector_type(8))) short short8;
typedef __attribute__((ext_vector_type(4))) float f32x4;

__device__ __forceinline__ float sigmoidf_(float x){ return 1.f/(1.f+__expf(-x)); }
__device__ __forceinline__ float siluf_(float x){ return x*sigmoidf_(x); }
__device__ __forceinline__ float softplusf_(float x){ return fmaxf(x,0.f) + log1pf(__expf(-fabsf(x))); }
__device__ __forceinline__ ushort_t f2b(float f){
    unsigned int x = __builtin_bit_cast(unsigned int, f);
    unsigned int r = (x + 0x7fffu + ((x>>16)&1u)) >> 16;   // RNE
    return (ushort_t)r;
}

#define GLOAD(g, l) __builtin_amdgcn_global_load_lds( \
    (const __attribute__((address_space(1))) void*)(g), \
    (__attribute__((address_space(3))) void*)(l), 16, 0, 0)

// fp32 -> bf16 conversion, 4 elems/thread.
__global__ __launch_bounds__(256) void f2b_k(const float* __restrict__ in,
                                             ushort_t* __restrict__ out, int n){
    int i = blockIdx.x*256 + threadIdx.x;
    float4 v = ((const float4*)in)[i];
    ushort4 o;
    o.x = f2b(v.x); o.y = f2b(v.y); o.z = f2b(v.z); o.w = f2b(v.w);
    ((ushort4*)out)[i] = o;
}

// bf16 MFMA GEMM: C[M][N] = A[M][K] @ W[N][K]^T, fp32 out.
// 128x128 tile, BK=32, 4 waves (2x2), wave = 64x64 via 4x4 16x16x32 frags.
template<int EPI>
__global__ __launch_bounds__(256) void gemm_mfma(
    const ushort_t* __restrict__ A, const ushort_t* __restrict__ W,
    float* __restrict__ C, int M, int N, int K,
    const float* __restrict__ res)
{
    __shared__ ushort_t As[128*32];
    __shared__ ushort_t Ws[128*32];
    const int tid  = threadIdx.x;
    const int lane = tid & 63;
    const int wv   = tid >> 6;
    const int wm0  = (wv>>1)*64, wn0 = (wv&1)*64;
    const int m0 = blockIdx.y*128, n0 = blockIdx.x*128;
    const int r0 = tid>>2, ch = tid&3;

    f32x4 acc[4][4];
    #pragma unroll
    for (int i=0;i<4;++i)
        #pragma unroll
        for (int j=0;j<4;++j) acc[i][j] = (f32x4){0.f,0.f,0.f,0.f};

    const int row_a = lane & 15, kc = (lane>>4)*8;

    for (int k0 = 0; k0 < K; k0 += 32){
        const ushort_t* gA = A + (size_t)(m0+r0)*K + k0 + ch*8;
        const ushort_t* gW = W + (size_t)(n0+r0)*K + k0 + ch*8;
        GLOAD(gA,            (char*)As + tid*16);
        GLOAD(gA + 64*(size_t)K, (char*)As + tid*16 + 4096);
        GLOAD(gW,            (char*)Ws + tid*16);
        GLOAD(gW + 64*(size_t)K, (char*)Ws + tid*16 + 4096);
        __syncthreads();
        short8 af[4], bf[4];
        #pragma unroll
        for (int i=0;i<4;++i){
            af[i] = *(const short8*)&As[(wm0 + i*16 + row_a)*32 + kc];
            bf[i] = *(const short8*)&Ws[(wn0 + i*16 + row_a)*32 + kc];
        }
        #pragma unroll
        for (int i=0;i<4;++i)
            #pragma unroll
            for (int j=0;j<4;++j)
                acc[i][j] = __builtin_amdgcn_mfma_f32_16x16x32_bf16(af[i], bf[j], acc[i][j], 0,0,0);
        __syncthreads();
    }

    const int crow = (lane>>4)*4, ccol = lane & 15;
    #pragma unroll
    for (int i=0;i<4;++i){
        #pragma unroll
        for (int j=0;j<4;++j){
            #pragma unroll
            for (int r=0;r<4;++r){
                int m = m0 + wm0 + i*16 + crow + r;
                int n = n0 + wn0 + j*16 + ccol;
                float v = acc[i][j][r];
                if (EPI==2) v += res[(size_t)m*N + n];
                C[(size_t)m*N + n] = v;
            }
        }
    }
}

// fp32 GEMM: C[M][N] = A[M][K] @ W[N][K]^T, 64x64 tile, BK=16.
// EPI: 0 plain, 1 = softplus(c + bias[n])
template<int EPI>
__global__ __launch_bounds__(256) void gemm_tn(
    const float* __restrict__ A, int lda,
    const float* __restrict__ W, int ldw,
    float* __restrict__ C, int ldc,
    int M, int N, int K,
    const float* __restrict__ bias)
{
    __shared__ float As[16][68];
    __shared__ float Ws[16][68];
    const int tid = threadIdx.x;
    const int tx = tid & 15, ty = tid >> 4;
    const int m0 = blockIdx.y * 64, n0 = blockIdx.x * 64;
    const int lr = tid >> 2;
    const int lk = (tid & 3) << 2;
    float acc[4][4] = {{0.f}};

    for (int k0 = 0; k0 < K; k0 += 16) {
        float4 av = *(const float4*)(A + (size_t)(m0+lr)*lda + k0 + lk);
        float4 wv = make_float4(0.f,0.f,0.f,0.f);
        if (n0 + lr < N) wv = *(const float4*)(W + (size_t)(n0+lr)*ldw + k0 + lk);
        __syncthreads();
        As[lk+0][lr]=av.x; As[lk+1][lr]=av.y; As[lk+2][lr]=av.z; As[lk+3][lr]=av.w;
        Ws[lk+0][lr]=wv.x; Ws[lk+1][lr]=wv.y; Ws[lk+2][lr]=wv.z; Ws[lk+3][lr]=wv.w;
        __syncthreads();
        #pragma unroll
        for (int k = 0; k < 16; ++k) {
            float4 a = *(const float4*)&As[k][ty<<2];
            float4 b = *(const float4*)&Ws[k][tx<<2];
            float a4[4] = {a.x,a.y,a.z,a.w};
            float b4[4] = {b.x,b.y,b.z,b.w};
            #pragma unroll
            for (int i=0;i<4;++i)
                #pragma unroll
                for (int j=0;j<4;++j)
                    acc[i][j] = fmaf(a4[i], b4[j], acc[i][j]);
        }
    }

    #pragma unroll
    for (int i=0;i<4;++i){
        int m = m0 + (ty<<2) + i;
        #pragma unroll
        for (int j=0;j<4;++j){
            int n = n0 + (tx<<2) + j;
            if (n < N){
                float v = acc[i][j];
                if (EPI==1) v = softplusf_(v + bias[n]);
                C[(size_t)m*ldc + n] = v;
            }
        }
    }
}

// Split-K fp32 GEMM for skinny N: grid (N/64, M/64, XP_KS). Each block does a
// 64x64 tile over K-chunk of K/XP_KS; partials to P[kz][M*96-layout].
__global__ __launch_bounds__(256) void gemm_tn_sk(
    const float* __restrict__ A, int lda,
    const float* __restrict__ W, int ldw,
    float* __restrict__ P, int M, int N, int K)
{
    __shared__ float As[16][68];
    __shared__ float Ws[16][68];
    const int tid = threadIdx.x;
    const int tx = tid & 15, ty = tid >> 4;
    const int m0 = blockIdx.y * 64, n0 = blockIdx.x * 64;
    const int kbase = blockIdx.z * (K/XP_KS);
    const int lr = tid >> 2;
    const int lk = (tid & 3) << 2;
    float acc[4][4] = {{0.f}};

    for (int kk = 0; kk < K/XP_KS; kk += 16) {
        int k0 = kbase + kk;
        float4 av = *(const float4*)(A + (size_t)(m0+lr)*lda + k0 + lk);
        float4 wv = make_float4(0.f,0.f,0.f,0.f);
        if (n0 + lr < N) wv = *(const float4*)(W + (size_t)(n0+lr)*ldw + k0 + lk);
        __syncthreads();
        As[lk+0][lr]=av.x; As[lk+1][lr]=av.y; As[lk+2][lr]=av.z; As[lk+3][lr]=av.w;
        Ws[lk+0][lr]=wv.x; Ws[lk+1][lr]=wv.y; Ws[lk+2][lr]=wv.z; Ws[lk+3][lr]=wv.w;
        __syncthreads();
        #pragma unroll
        for (int k = 0; k < 16; ++k) {
            float4 a = *(const float4*)&As[k][ty<<2];
            float4 b = *(const float4*)&Ws[k][tx<<2];
            float a4[4] = {a.x,a.y,a.z,a.w};
            float b4[4] = {b.x,b.y,b.z,b.w};
            #pragma unroll
            for (int i=0;i<4;++i)
                #pragma unroll
                for (int j=0;j<4;++j)
                    acc[i][j] = fmaf(a4[i], b4[j], acc[i][j]);
        }
    }

    float* Pz = P + (size_t)blockIdx.z * M * 96;
    #pragma unroll
    for (int i=0;i<4;++i){
        int m = m0 + (ty<<2) + i;
        #pragma unroll
        for (int j=0;j<4;++j){
            int n = n0 + (tx<<2) + j;
            if (n < N) Pz[(size_t)m*96 + n] = acc[i][j];
        }
    }
}

// xdbl[g] = sum_ks P[ks][g], g over M*96.
__global__ __launch_bounds__(256) void sk_reduce(
    const float* __restrict__ P, float* __restrict__ outp, int MN)
{
    int g = blockIdx.x*256 + threadIdx.x;
    float s = 0.f;
    #pragma unroll
    for (int ks=0; ks<XP_KS; ++ks) s += P[(size_t)ks*MN + g];
    outp[g] = s;
}

// Depthwise causal conv (K=4) + bias + SiLU. u = xz[..., :2048].
__global__ __launch_bounds__(256) void conv_silu_k(
    const float* __restrict__ xz, const float* __restrict__ cw,
    const float* __restrict__ cb, float* __restrict__ uc)
{
    int idx = blockIdx.x*256 + threadIdx.x;
    int d  = idx & (D_INNER-1);
    int bt = idx >> 11;
    int t  = bt & (TT-1);
    float4 w4 = *(const float4*)(cw + d*4);
    float wv[4] = {w4.x, w4.y, w4.z, w4.w};
    float acc = cb[d];
    #pragma unroll
    for (int k=0;k<4;++k){
        int tt = t - 3 + k;
        if (tt >= 0) acc = fmaf(xz[(size_t)(bt-3+k)*4096 + d], wv[k], acc);
    }
    uc[idx] = siluf_(acc);
}

// ---- Chunked selective scan, 3 phases. Lane = channel, 16 states in regs. ----

__global__ __launch_bounds__(256) void scan_p1(
    const float* __restrict__ dt, const float* __restrict__ uc,
    const float* __restrict__ xdbl, const float* __restrict__ A_log,
    float* __restrict__ hpart, float* __restrict__ hdecay)
{
    const int tid = threadIdx.x;
    const int d = blockIdx.x*256 + tid;
    const int b = blockIdx.y;
    const int k = blockIdx.z;
    const int t0 = k*SCTC;
    float A[16];
    #pragma unroll
    for (int q=0;q<4;++q){
        float4 v = *(const float4*)(A_log + (size_t)d*16 + q*4);
        A[q*4+0]=-__expf(v.x); A[q*4+1]=-__expf(v.y);
        A[q*4+2]=-__expf(v.z); A[q*4+3]=-__expf(v.w);
    }
    float h[16];
    #pragma unroll
    for (int s=0;s<16;++s) h[s]=0.f;
    float sumdt = 0.f;
    const float* dtp = dt + ((size_t)b*TT + t0)*D_INNER + d;
    const float* ucp = uc + ((size_t)b*TT + t0)*D_INNER + d;
    const float* bcp = xdbl + ((size_t)b*TT + t0)*96 + 64;
    #pragma unroll 2
    for (int t=0;t<SCTC;++t){
        float dtv = dtp[(size_t)t*D_INNER];
        float uv  = ucp[(size_t)t*D_INNER];
        const float* bc = bcp + (size_t)t*96;
        float du = dtv*uv;
        sumdt += dtv;
        #pragma unroll
        for (int s=0;s<16;++s)
            h[s] = fmaf(__expf(dtv*A[s]), h[s], du*bc[s]);
    }
    size_t base = ((size_t)(k*BB+b)*D_INNER + d)*16;
    float4* hp = (float4*)(hpart + base);
    float4* hd = (float4*)(hdecay + base);
    #pragma unroll
    for (int q=0;q<4;++q){
        hp[q] = make_float4(h[q*4],h[q*4+1],h[q*4+2],h[q*4+3]);
        hd[q] = make_float4(__expf(sumdt*A[q*4+0]),__expf(sumdt*A[q*4+1]),
                            __expf(sumdt*A[q*4+2]),__expf(sumdt*A[q*4+3]));
    }
}

__global__ __launch_bounds__(256) void scan_fix(
    const float* __restrict__ hpart, const float* __restrict__ hdecay,
    float* __restrict__ hstart)
{
    int g = blockIdx.x*256 + threadIdx.x;
    float h = 0.f;
    #pragma unroll
    for (int k=0;k<NCHUNK;++k){
        size_t idx = (size_t)k*(BB*D_INNER*16) + g;
        hstart[idx] = h;
        h = fmaf(hdecay[idx], h, hpart[idx]);
    }
}

__global__ __launch_bounds__(256) void scan_p3(
    const float* __restrict__ dt, const float* __restrict__ uc,
    const float* __restrict__ xdbl, const float* __restrict__ A_log,
    const float* __restrict__ xz, const float* __restrict__ Dd,
    const float* __restrict__ hstart, ushort_t* __restrict__ ysb)
{
    const int tid = threadIdx.x;
    const int d = blockIdx.x*256 + tid;
    const int b = blockIdx.y;
    const int k = blockIdx.z;
    const int t0 = k*SCTC;
    float A[16];
    #pragma unroll
    for (int q=0;q<4;++q){
        float4 v = *(const float4*)(A_log + (size_t)d*16 + q*4);
        A[q*4+0]=-__expf(v.x); A[q*4+1]=-__expf(v.y);
        A[q*4+2]=-__expf(v.z); A[q*4+3]=-__expf(v.w);
    }
    float h[16];
    {
        const float4* hs = (const float4*)(hstart + ((size_t)(k*BB+b)*D_INNER + d)*16);
        #pragma unroll
        for (int q=0;q<4;++q){
            float4 v = hs[q];
            h[q*4+0]=v.x; h[q*4+1]=v.y; h[q*4+2]=v.z; h[q*4+3]=v.w;
        }
    }
    const float Ddc = Dd[d];
    const float* dtp = dt + ((size_t)b*TT + t0)*D_INNER + d;
    const float* ucp = uc + ((size_t)b*TT + t0)*D_INNER + d;
    const float* zp  = xz + ((size_t)b*TT + t0)*4096 + 2048 + d;
    const float* bcp = xdbl + ((size_t)b*TT + t0)*96 + 64;
    ushort_t* yp = ysb + ((size_t)b*TT + t0)*D_INNER + d;
    #pragma unroll 2
    for (int t=0;t<SCTC;++t){
        float dtv = dtp[(size_t)t*D_INNER];
        float uv  = ucp[(size_t)t*D_INNER];
        float zv  = zp [(size_t)t*4096];
        const float* bc = bcp + (size_t)t*96;
        float du = dtv*uv;
        float y0=0.f,y1=0.f,y2=0.f,y3=0.f;
        #pragma unroll
        for (int q=0;q<4;++q){
            h[q*4+0] = fmaf(__expf(dtv*A[q*4+0]), h[q*4+0], du*bc[q*4+0]);
            h[q*4+1] = fmaf(__expf(dtv*A[q*4+1]), h[q*4+1], du*bc[q*4+1]);
            h[q*4+2] = fmaf(__expf(dtv*A[q*4+2]), h[q*4+2], du*bc[q*4+2]);
            h[q*4+3] = fmaf(__expf(dtv*A[q*4+3]), h[q*4+3], du*bc[q*4+3]);
        }
        #pragma unroll
        for (int q=0;q<4;++q){
            y0 = fmaf(h[q*4+0], bc[16+q*4+0], y0);
            y1 = fmaf(h[q*4+1], bc[16+q*4+1], y1);
            y2 = fmaf(h[q*4+2], bc[16+q*4+2], y2);
            y3 = fmaf(h[q*4+3], bc[16+q*4+3], y3);
        }
        float y = (y0+y1)+(y2+y3);
        float yv = (y + uv*Ddc) * siluf_(zv);
        yp[(size_t)t*D_INNER] = f2b(yv);
    }
}

__global__ __launch_bounds__(256) void layernorm_k(
    const float* __restrict__ X, const float* __restrict__ w,
    const float* __restrict__ b, float* __restrict__ out)
{
    int row = blockIdx.x;
    int tid = threadIdx.x;
    const float* xr = X + (size_t)row*D_MODEL;
    float4 v = *(const float4*)(xr + tid*4);
    float s  = v.x+v.y+v.z+v.w;
    float ss = fmaf(v.x,v.x, fmaf(v.y,v.y, fmaf(v.z,v.z, v.w*v.w)));
    #pragma unroll
    for (int off=32; off>0; off>>=1){
        s  += __shfl_down(s, off, 64);
        ss += __shfl_down(ss, off, 64);
    }
    __shared__ float red[8];
    int wid = tid>>6, lane = tid&63;
    if (lane==0){ red[wid]=s; red[4+wid]=ss; }
    __syncthreads();
    if (tid==0){
        float S  = red[0]+red[1]+red[2]+red[3];
        float SS = red[4]+red[5]+red[6]+red[7];
        float mu = S*(1.f/D_MODEL);
        float var = SS*(1.f/D_MODEL) - mu*mu;
        red[0]=mu; red[1]=rsqrtf(var + 1e-5f);
    }
    __syncthreads();
    float mu=red[0], rs=red[1];
    float4 wv = *(const float4*)(w + tid*4);
    float4 bv = *(const float4*)(b + tid*4);
    float4 o;
    o.x = fmaf((v.x-mu)*rs, wv.x, bv.x);
    o.y = fmaf((v.y-mu)*rs, wv.y, bv.y);
    o.z = fmaf((v.z-mu)*rs, wv.z, bv.z);
    o.w = fmaf((v.w-mu)*rs, wv.w, bv.w);
    *(float4*)(out + (size_t)row*D_MODEL + tid*4) = o;
}

extern "C" void kernel_launch(void* const* d_in, const int* in_sizes, int n_in,
                              void* d_out, int out_size, void* d_ws, size_t ws_size,
                              hipStream_t stream) {
    (void)in_sizes; (void)n_in; (void)out_size; (void)ws_size;
    const float* x      = (const float*)d_in[0];
    const float* in_w   = (const float*)d_in[1];
    const float* conv_w = (const float*)d_in[2];
    const float* conv_b = (const float*)d_in[3];
    const float* xp_w   = (const float*)d_in[4];
    const float* dtp_w  = (const float*)d_in[5];
    const float* dtp_b  = (const float*)d_in[6];
    const float* A_log  = (const float*)d_in[7];
    const float* Dd     = (const float*)d_in[8];
    const float* out_w  = (const float*)d_in[9];
    const float* nw     = (const float*)d_in[10];
    const float* nb     = (const float*)d_in[11];
    float* out = (float*)d_out;

    char* p = (char*)d_ws;
    float* xz      = (float*)p;  p += (size_t)BT*4096*4;   // 32 MB
    float* uc      = (float*)p;  p += (size_t)BT*2048*4;   // 16 MB
    float* xdbl    = (float*)p;  p += (size_t)BT*96*4;     // 768 KB
    float* dtb     = (float*)p;  p += (size_t)BT*2048*4;   // 16 MB
    float* xcur    = (float*)p;  p += (size_t)BT*1024*4;   // 8 MB
    ushort_t* xinb = (ushort_t*)p; p += (size_t)BT*1024*2; // 4 MB
    ushort_t* ysb  = (ushort_t*)p; p += (size_t)BT*2048*2; // 8 MB
    ushort_t* winb = (ushort_t*)p; p += (size_t)4096*1024*2; // 8 MB
    ushort_t* woutb= (ushort_t*)p; p += (size_t)1024*2048*2; // 4 MB

    // Aliases into dead windows:
    //  - pbuf (6 MB, x_proj split-K partials) overlays winb: winb dead after
    //    in_proj; pbuf consumed by sk_reduce before scan_p1 writes hpart.
    //  - hpart/hdecay overlay winb after pbuf is dead.
    //  - hstart overlays xinb (dead after in_proj; pbuf not in this region).
    float* pbuf   = (float*)winb;                                  // 6 MB
    float* hpart  = (float*)winb;                                  // 4 MB
    float* hdecay = hpart + (size_t)NCHUNK*BB*D_INNER*16;          // 4 MB
    float* hstart = (float*)xinb;                                  // 4 MB

    for (int i = 0; i < N_LAYERS; ++i){
        const float* xin = (i==0) ? x : xcur;
        // bf16 conversions for this layer
        f2b_k<<<(BT*1024)/1024,256,0,stream>>>(xin, xinb, BT*1024);
        f2b_k<<<(4096*1024)/1024,256,0,stream>>>(in_w + (size_t)i*4096*D_MODEL, winb, 4096*1024);
        f2b_k<<<(1024*2048)/1024,256,0,stream>>>(out_w + (size_t)i*D_MODEL*D_INNER, woutb, 1024*2048);
        // xz = xin @ in_w^T   (2048 x 4096 x K=1024), bf16 MFMA
        gemm_mfma<0><<<dim3(4096/128, BT/128),256,0,stream>>>(
            xinb, winb, xz, BT, 4096, D_MODEL, nullptr);
        // uc = silu(causal_conv(u) + cb)
        conv_silu_k<<<(BT*D_INNER)/256,256,0,stream>>>(
            xz, conv_w + (size_t)i*D_INNER*D_CONV, conv_b + (size_t)i*D_INNER, uc);
        // x_dbl = uc @ xp_w^T  (2048 x 96 x K=2048), fp32 split-K
        gemm_tn_sk<<<dim3(2,32,XP_KS),256,0,stream>>>(
            uc, D_INNER, xp_w + (size_t)i*96*D_INNER, D_INNER,
            pbuf, BT, 96, D_INNER);
        sk_reduce<<<(BT*96)/256,256,0,stream>>>(pbuf, xdbl, BT*96);
        // dt = softplus(dt_r @ dtp_w^T + dtp_b)  (2048 x 2048 x K=64), fp32
        gemm_tn<1><<<dim3(32,32),256,0,stream>>>(
            xdbl, 96, dtp_w + (size_t)i*D_INNER*DT_RANK, DT_RANK,
            dtb, D_INNER, BT, D_INNER, DT_RANK, dtp_b + (size_t)i*D_INNER);
        // chunked selective scan + fused (y + u*D)*silu(z) -> bf16
        scan_p1<<<dim3(D_INNER/256, BB, NCHUNK),256,0,stream>>>(
            dtb, uc, xdbl, A_log + (size_t)i*D_INNER*D_STATE, hpart, hdecay);
        scan_fix<<<(BB*D_INNER*16)/256,256,0,stream>>>(hpart, hdecay, hstart);
        scan_p3<<<dim3(D_INNER/256, BB, NCHUNK),256,0,stream>>>(
            dtb, uc, xdbl, A_log + (size_t)i*D_INNER*D_STATE, xz,
            Dd + (size_t)i*D_INNER, hstart, ysb);
        // xcur = ys @ out_w^T + xin   (2048 x 1024 x K=2048), bf16 MFMA + residual
        gemm_mfma<2><<<dim3(1024/128, BT/128),256,0,stream>>>(
            ysb, woutb, xcur, BT, 1024, D_INNER, xin);
    }
    layernorm_k<<<BT,256,0,stream>>>(xcur, nw, nb, out);
}

// Round 6
// 898.743 us; speedup vs baseline: 4.4527x; 1.0206x over previous
//
#include <hip/hip_runtime.h>
#include <hip/hip_bf16.h>

#define N_LAYERS 4
#define D_MODEL  1024
#define D_INNER  2048
#define D_STATE  16
#define D_CONV   4
#define DT_RANK  64
#define BB       2
#define TT       1024
#define BT       (BB*TT)   // 2048 rows (b*T)

#define NCHUNK 16
#define SCTC   (TT/NCHUNK)   // 64 timesteps per chunk

#define XP_KS  8             // x_proj K-split factor

typedef unsigned short ushort_t;
typedef __attribute__((ext_vector_type(8))) short short8;
typedef __attribute__((ext_vector_type(4))) float f32x4;

__device__ __forceinline__ float sigmoidf_(float x){ return 1.f/(1.f+__expf(-x)); }
__device__ __forceinline__ float siluf_(float x){ return x*sigmoidf_(x); }
__device__ __forceinline__ float softplusf_(float x){ return fmaxf(x,0.f) + log1pf(__expf(-fabsf(x))); }
__device__ __forceinline__ ushort_t f2b(float f){
    unsigned int x = __builtin_bit_cast(unsigned int, f);
    unsigned int r = (x + 0x7fffu + ((x>>16)&1u)) >> 16;   // RNE
    return (ushort_t)r;
}

#define GLOAD(g, l) __builtin_amdgcn_global_load_lds( \
    (const __attribute__((address_space(1))) void*)(g), \
    (__attribute__((address_space(3))) void*)(l), 16, 0, 0)

// fp32 -> bf16 conversion, 4 elems/thread.
__global__ __launch_bounds__(256) void f2b_k(const float* __restrict__ in,
                                             ushort_t* __restrict__ out, int n){
    int i = blockIdx.x*256 + threadIdx.x;
    float4 v = ((const float4*)in)[i];
    ushort4 o;
    o.x = f2b(v.x); o.y = f2b(v.y); o.z = f2b(v.z); o.w = f2b(v.w);
    ((ushort4*)out)[i] = o;
}

// Two-buffer fp32->bf16 in one launch (na4/nb4 = float4 counts).
__global__ __launch_bounds__(256) void f2b2_k(
    const float* __restrict__ a, ushort_t* __restrict__ ao, int na4,
    const float* __restrict__ b, ushort_t* __restrict__ bo){
    int i = blockIdx.x*256 + threadIdx.x;
    const float4* src; ushort4* dst; int j;
    if (i < na4){ src = (const float4*)a; dst = (ushort4*)ao; j = i; }
    else        { src = (const float4*)b; dst = (ushort4*)bo; j = i - na4; }
    float4 v = src[j];
    ushort4 o;
    o.x = f2b(v.x); o.y = f2b(v.y); o.z = f2b(v.z); o.w = f2b(v.w);
    dst[j] = o;
}

// bf16 MFMA GEMM: C[M][N] = A[M][K] @ W[N][K]^T, fp32 out.
// 128x128 tile, BK=32, 4 waves (2x2), wave = 64x64 via 4x4 16x16x32 frags.
// Double-buffered LDS + counted-vmcnt prefetch (T3-minimum): next tile's
// 4 global_load_lds issued before computing current; s_waitcnt vmcnt(4)
// (current tile's loads done, next's still in flight); raw s_barrier.
// EPI: 0 plain, 2 = +res, also writes bf16 copy to outb.
template<int EPI>
__global__ __launch_bounds__(256) void gemm_mfma(
    const ushort_t* __restrict__ A, const ushort_t* __restrict__ W,
    float* __restrict__ C, int M, int N, int K,
    const float* __restrict__ res, ushort_t* __restrict__ outb)
{
    __shared__ ushort_t As[2][128*32];
    __shared__ ushort_t Ws[2][128*32];
    const int tid  = threadIdx.x;
    const int lane = tid & 63;
    const int wv   = tid >> 6;
    const int wm0  = (wv>>1)*64, wn0 = (wv&1)*64;
    const int m0 = blockIdx.y*128, n0 = blockIdx.x*128;
    const int r0 = tid>>2, ch = tid&3;

    f32x4 acc[4][4];
    #pragma unroll
    for (int i=0;i<4;++i)
        #pragma unroll
        for (int j=0;j<4;++j) acc[i][j] = (f32x4){0.f,0.f,0.f,0.f};

    const int row_a = lane & 15, kc = (lane>>4)*8;
    const ushort_t* gA = A + (size_t)(m0+r0)*K + ch*8;
    const ushort_t* gW = W + (size_t)(n0+r0)*K + ch*8;

#define STAGE(KT, BUF) { \
    const ushort_t* pA_ = gA + (KT)*32; \
    const ushort_t* pW_ = gW + (KT)*32; \
    GLOAD(pA_,              (char*)&As[BUF][0] + tid*16); \
    GLOAD(pA_ + 64*(size_t)K, (char*)&As[BUF][0] + tid*16 + 4096); \
    GLOAD(pW_,              (char*)&Ws[BUF][0] + tid*16); \
    GLOAD(pW_ + 64*(size_t)K, (char*)&Ws[BUF][0] + tid*16 + 4096); }

#define COMPUTE(BUF) { \
    short8 af[4], bf[4]; \
    _Pragma("unroll") \
    for (int i=0;i<4;++i){ \
        af[i] = *(const short8*)&As[BUF][(wm0 + i*16 + row_a)*32 + kc]; \
        bf[i] = *(const short8*)&Ws[BUF][(wn0 + i*16 + row_a)*32 + kc]; } \
    _Pragma("unroll") \
    for (int i=0;i<4;++i) \
        _Pragma("unroll") \
        for (int j=0;j<4;++j) \
            acc[i][j] = __builtin_amdgcn_mfma_f32_16x16x32_bf16(af[i], bf[j], acc[i][j], 0,0,0); }

    const int nt = K >> 5;
    STAGE(0, 0);
    for (int t = 0; t < nt-1; ++t){
        const int cur = t & 1;
        STAGE(t+1, cur^1);
        asm volatile("s_waitcnt vmcnt(4)" ::: "memory");
        asm volatile("s_barrier" ::: "memory");
        COMPUTE(cur);
        asm volatile("s_barrier" ::: "memory");
    }
    asm volatile("s_waitcnt vmcnt(0)" ::: "memory");
    asm volatile("s_barrier" ::: "memory");
    COMPUTE((nt-1)&1);
#undef STAGE
#undef COMPUTE

    const int crow = (lane>>4)*4, ccol = lane & 15;
    #pragma unroll
    for (int i=0;i<4;++i){
        #pragma unroll
        for (int j=0;j<4;++j){
            #pragma unroll
            for (int r=0;r<4;++r){
                int m = m0 + wm0 + i*16 + crow + r;
                int n = n0 + wn0 + j*16 + ccol;
                float v = acc[i][j][r];
                if (EPI==2) v += res[(size_t)m*N + n];
                C[(size_t)m*N + n] = v;
                if (EPI==2) outb[(size_t)m*N + n] = f2b(v);
            }
        }
    }
}

// fp32 GEMM: C[M][N] = A[M][K] @ W[N][K]^T, 64x64 tile, BK=16.
// EPI: 0 plain, 1 = softplus(c + bias[n])
template<int EPI>
__global__ __launch_bounds__(256) void gemm_tn(
    const float* __restrict__ A, int lda,
    const float* __restrict__ W, int ldw,
    float* __restrict__ C, int ldc,
    int M, int N, int K,
    const float* __restrict__ bias)
{
    __shared__ float As[16][68];
    __shared__ float Ws[16][68];
    const int tid = threadIdx.x;
    const int tx = tid & 15, ty = tid >> 4;
    const int m0 = blockIdx.y * 64, n0 = blockIdx.x * 64;
    const int lr = tid >> 2;
    const int lk = (tid & 3) << 2;
    float acc[4][4] = {{0.f}};

    for (int k0 = 0; k0 < K; k0 += 16) {
        float4 av = *(const float4*)(A + (size_t)(m0+lr)*lda + k0 + lk);
        float4 wv = make_float4(0.f,0.f,0.f,0.f);
        if (n0 + lr < N) wv = *(const float4*)(W + (size_t)(n0+lr)*ldw + k0 + lk);
        __syncthreads();
        As[lk+0][lr]=av.x; As[lk+1][lr]=av.y; As[lk+2][lr]=av.z; As[lk+3][lr]=av.w;
        Ws[lk+0][lr]=wv.x; Ws[lk+1][lr]=wv.y; Ws[lk+2][lr]=wv.z; Ws[lk+3][lr]=wv.w;
        __syncthreads();
        #pragma unroll
        for (int k = 0; k < 16; ++k) {
            float4 a = *(const float4*)&As[k][ty<<2];
            float4 b = *(const float4*)&Ws[k][tx<<2];
            float a4[4] = {a.x,a.y,a.z,a.w};
            float b4[4] = {b.x,b.y,b.z,b.w};
            #pragma unroll
            for (int i=0;i<4;++i)
                #pragma unroll
                for (int j=0;j<4;++j)
                    acc[i][j] = fmaf(a4[i], b4[j], acc[i][j]);
        }
    }

    #pragma unroll
    for (int i=0;i<4;++i){
        int m = m0 + (ty<<2) + i;
        #pragma unroll
        for (int j=0;j<4;++j){
            int n = n0 + (tx<<2) + j;
            if (n < N){
                float v = acc[i][j];
                if (EPI==1) v = softplusf_(v + bias[n]);
                C[(size_t)m*ldc + n] = v;
            }
        }
    }
}

// Split-K fp32 GEMM for skinny N: grid (N/64, M/64, XP_KS).
__global__ __launch_bounds__(256) void gemm_tn_sk(
    const float* __restrict__ A, int lda,
    const float* __restrict__ W, int ldw,
    float* __restrict__ P, int M, int N, int K)
{
    __shared__ float As[16][68];
    __shared__ float Ws[16][68];
    const int tid = threadIdx.x;
    const int tx = tid & 15, ty = tid >> 4;
    const int m0 = blockIdx.y * 64, n0 = blockIdx.x * 64;
    const int kbase = blockIdx.z * (K/XP_KS);
    const int lr = tid >> 2;
    const int lk = (tid & 3) << 2;
    float acc[4][4] = {{0.f}};

    for (int kk = 0; kk < K/XP_KS; kk += 16) {
        int k0 = kbase + kk;
        float4 av = *(const float4*)(A + (size_t)(m0+lr)*lda + k0 + lk);
        float4 wv = make_float4(0.f,0.f,0.f,0.f);
        if (n0 + lr < N) wv = *(const float4*)(W + (size_t)(n0+lr)*ldw + k0 + lk);
        __syncthreads();
        As[lk+0][lr]=av.x; As[lk+1][lr]=av.y; As[lk+2][lr]=av.z; As[lk+3][lr]=av.w;
        Ws[lk+0][lr]=wv.x; Ws[lk+1][lr]=wv.y; Ws[lk+2][lr]=wv.z; Ws[lk+3][lr]=wv.w;
        __syncthreads();
        #pragma unroll
        for (int k = 0; k < 16; ++k) {
            float4 a = *(const float4*)&As[k][ty<<2];
            float4 b = *(const float4*)&Ws[k][tx<<2];
            float a4[4] = {a.x,a.y,a.z,a.w};
            float b4[4] = {b.x,b.y,b.z,b.w};
            #pragma unroll
            for (int i=0;i<4;++i)
                #pragma unroll
                for (int j=0;j<4;++j)
                    acc[i][j] = fmaf(a4[i], b4[j], acc[i][j]);
        }
    }

    float* Pz = P + (size_t)blockIdx.z * M * 96;
    #pragma unroll
    for (int i=0;i<4;++i){
        int m = m0 + (ty<<2) + i;
        #pragma unroll
        for (int j=0;j<4;++j){
            int n = n0 + (tx<<2) + j;
            if (n < N) Pz[(size_t)m*96 + n] = acc[i][j];
        }
    }
}

// xdbl[g] = sum_ks P[ks][g], g over M*96.
__global__ __launch_bounds__(256) void sk_reduce(
    const float* __restrict__ P, float* __restrict__ outp, int MN)
{
    int g = blockIdx.x*256 + threadIdx.x;
    float s = 0.f;
    #pragma unroll
    for (int ks=0; ks<XP_KS; ++ks) s += P[(size_t)ks*MN + g];
    outp[g] = s;
}

// Depthwise causal conv (K=4) + bias + SiLU. u = xz[..., :2048].
__global__ __launch_bounds__(256) void conv_silu_k(
    const float* __restrict__ xz, const float* __restrict__ cw,
    const float* __restrict__ cb, float* __restrict__ uc)
{
    int idx = blockIdx.x*256 + threadIdx.x;
    int d  = idx & (D_INNER-1);
    int bt = idx >> 11;
    int t  = bt & (TT-1);
    float4 w4 = *(const float4*)(cw + d*4);
    float wv[4] = {w4.x, w4.y, w4.z, w4.w};
    float acc = cb[d];
    #pragma unroll
    for (int k=0;k<4;++k){
        int tt = t - 3 + k;
        if (tt >= 0) acc = fmaf(xz[(size_t)(bt-3+k)*4096 + d], wv[k], acc);
    }
    uc[idx] = siluf_(acc);
}

// ---- Chunked selective scan, 3 phases. Lane = channel, 16 states in regs. ----

__global__ __launch_bounds__(256) void scan_p1(
    const float* __restrict__ dt, const float* __restrict__ uc,
    const float* __restrict__ xdbl, const float* __restrict__ A_log,
    float* __restrict__ hpart, float* __restrict__ hdecay)
{
    const int tid = threadIdx.x;
    const int d = blockIdx.x*256 + tid;
    const int b = blockIdx.y;
    const int k = blockIdx.z;
    const int t0 = k*SCTC;
    float A[16];
    #pragma unroll
    for (int q=0;q<4;++q){
        float4 v = *(const float4*)(A_log + (size_t)d*16 + q*4);
        A[q*4+0]=-__expf(v.x); A[q*4+1]=-__expf(v.y);
        A[q*4+2]=-__expf(v.z); A[q*4+3]=-__expf(v.w);
    }
    float h[16];
    #pragma unroll
    for (int s=0;s<16;++s) h[s]=0.f;
    float sumdt = 0.f;
    const float* dtp = dt + ((size_t)b*TT + t0)*D_INNER + d;
    const float* ucp = uc + ((size_t)b*TT + t0)*D_INNER + d;
    const float* bcp = xdbl + ((size_t)b*TT + t0)*96 + 64;
    #pragma unroll 2
    for (int t=0;t<SCTC;++t){
        float dtv = dtp[(size_t)t*D_INNER];
        float uv  = ucp[(size_t)t*D_INNER];
        const float* bc = bcp + (size_t)t*96;
        float du = dtv*uv;
        sumdt += dtv;
        #pragma unroll
        for (int s=0;s<16;++s)
            h[s] = fmaf(__expf(dtv*A[s]), h[s], du*bc[s]);
    }
    size_t base = ((size_t)(k*BB+b)*D_INNER + d)*16;
    float4* hp = (float4*)(hpart + base);
    float4* hd = (float4*)(hdecay + base);
    #pragma unroll
    for (int q=0;q<4;++q){
        hp[q] = make_float4(h[q*4],h[q*4+1],h[q*4+2],h[q*4+3]);
        hd[q] = make_float4(__expf(sumdt*A[q*4+0]),__expf(sumdt*A[q*4+1]),
                            __expf(sumdt*A[q*4+2]),__expf(sumdt*A[q*4+3]));
    }
}

__global__ __launch_bounds__(256) void scan_fix(
    const float* __restrict__ hpart, const float* __restrict__ hdecay,
    float* __restrict__ hstart)
{
    int g = blockIdx.x*256 + threadIdx.x;
    float h = 0.f;
    #pragma unroll
    for (int k=0;k<NCHUNK;++k){
        size_t idx = (size_t)k*(BB*D_INNER*16) + g;
        hstart[idx] = h;
        h = fmaf(hdecay[idx], h, hpart[idx]);
    }
}

__global__ __launch_bounds__(256) void scan_p3(
    const float* __restrict__ dt, const float* __restrict__ uc,
    const float* __restrict__ xdbl, const float* __restrict__ A_log,
    const float* __restrict__ xz, const float* __restrict__ Dd,
    const float* __restrict__ hstart, ushort_t* __restrict__ ysb)
{
    const int tid = threadIdx.x;
    const int d = blockIdx.x*256 + tid;
    const int b = blockIdx.y;
    const int k = blockIdx.z;
    const int t0 = k*SCTC;
    float A[16];
    #pragma unroll
    for (int q=0;q<4;++q){
        float4 v = *(const float4*)(A_log + (size_t)d*16 + q*4);
        A[q*4+0]=-__expf(v.x); A[q*4+1]=-__expf(v.y);
        A[q*4+2]=-__expf(v.z); A[q*4+3]=-__expf(v.w);
    }
    float h[16];
    {
        const float4* hs = (const float4*)(hstart + ((size_t)(k*BB+b)*D_INNER + d)*16);
        #pragma unroll
        for (int q=0;q<4;++q){
            float4 v = hs[q];
            h[q*4+0]=v.x; h[q*4+1]=v.y; h[q*4+2]=v.z; h[q*4+3]=v.w;
        }
    }
    const float Ddc = Dd[d];
    const float* dtp = dt + ((size_t)b*TT + t0)*D_INNER + d;
    const float* ucp = uc + ((size_t)b*TT + t0)*D_INNER + d;
    const float* zp  = xz + ((size_t)b*TT + t0)*4096 + 2048 + d;
    const float* bcp = xdbl + ((size_t)b*TT + t0)*96 + 64;
    ushort_t* yp = ysb + ((size_t)b*TT + t0)*D_INNER + d;
    #pragma unroll 2
    for (int t=0;t<SCTC;++t){
        float dtv = dtp[(size_t)t*D_INNER];
        float uv  = ucp[(size_t)t*D_INNER];
        float zv  = zp [(size_t)t*4096];
        const float* bc = bcp + (size_t)t*96;
        float du = dtv*uv;
        float y0=0.f,y1=0.f,y2=0.f,y3=0.f;
        #pragma unroll
        for (int q=0;q<4;++q){
            h[q*4+0] = fmaf(__expf(dtv*A[q*4+0]), h[q*4+0], du*bc[q*4+0]);
            h[q*4+1] = fmaf(__expf(dtv*A[q*4+1]), h[q*4+1], du*bc[q*4+1]);
            h[q*4+2] = fmaf(__expf(dtv*A[q*4+2]), h[q*4+2], du*bc[q*4+2]);
            h[q*4+3] = fmaf(__expf(dtv*A[q*4+3]), h[q*4+3], du*bc[q*4+3]);
        }
        #pragma unroll
        for (int q=0;q<4;++q){
            y0 = fmaf(h[q*4+0], bc[16+q*4+0], y0);
            y1 = fmaf(h[q*4+1], bc[16+q*4+1], y1);
            y2 = fmaf(h[q*4+2], bc[16+q*4+2], y2);
            y3 = fmaf(h[q*4+3], bc[16+q*4+3], y3);
        }
        float y = (y0+y1)+(y2+y3);
        float yv = (y + uv*Ddc) * siluf_(zv);
        yp[(size_t)t*D_INNER] = f2b(yv);
    }
}

__global__ __launch_bounds__(256) void layernorm_k(
    const float* __restrict__ X, const float* __restrict__ w,
    const float* __restrict__ b, float* __restrict__ out)
{
    int row = blockIdx.x;
    int tid = threadIdx.x;
    const float* xr = X + (size_t)row*D_MODEL;
    float4 v = *(const float4*)(xr + tid*4);
    float s  = v.x+v.y+v.z+v.w;
    float ss = fmaf(v.x,v.x, fmaf(v.y,v.y, fmaf(v.z,v.z, v.w*v.w)));
    #pragma unroll
    for (int off=32; off>0; off>>=1){
        s  += __shfl_down(s, off, 64);
        ss += __shfl_down(ss, off, 64);
    }
    __shared__ float red[8];
    int wid = tid>>6, lane = tid&63;
    if (lane==0){ red[wid]=s; red[4+wid]=ss; }
    __syncthreads();
    if (tid==0){
        float S  = red[0]+red[1]+red[2]+red[3];
        float SS = red[4]+red[5]+red[6]+red[7];
        float mu = S*(1.f/D_MODEL);
        float var = SS*(1.f/D_MODEL) - mu*mu;
        red[0]=mu; red[1]=rsqrtf(var + 1e-5f);
    }
    __syncthreads();
    float mu=red[0], rs=red[1];
    float4 wv = *(const float4*)(w + tid*4);
    float4 bv = *(const float4*)(b + tid*4);
    float4 o;
    o.x = fmaf((v.x-mu)*rs, wv.x, bv.x);
    o.y = fmaf((v.y-mu)*rs, wv.y, bv.y);
    o.z = fmaf((v.z-mu)*rs, wv.z, bv.z);
    o.w = fmaf((v.w-mu)*rs, wv.w, bv.w);
    *(float4*)(out + (size_t)row*D_MODEL + tid*4) = o;
}

extern "C" void kernel_launch(void* const* d_in, const int* in_sizes, int n_in,
                              void* d_out, int out_size, void* d_ws, size_t ws_size,
                              hipStream_t stream) {
    (void)in_sizes; (void)n_in; (void)out_size; (void)ws_size;
    const float* x      = (const float*)d_in[0];
    const float* in_w   = (const float*)d_in[1];
    const float* conv_w = (const float*)d_in[2];
    const float* conv_b = (const float*)d_in[3];
    const float* xp_w   = (const float*)d_in[4];
    const float* dtp_w  = (const float*)d_in[5];
    const float* dtp_b  = (const float*)d_in[6];
    const float* A_log  = (const float*)d_in[7];
    const float* Dd     = (const float*)d_in[8];
    const float* out_w  = (const float*)d_in[9];
    const float* nw     = (const float*)d_in[10];
    const float* nb     = (const float*)d_in[11];
    float* out = (float*)d_out;

    char* p = (char*)d_ws;
    float* xz      = (float*)p;  p += (size_t)BT*4096*4;   // 32 MB
    float* uc      = (float*)p;  p += (size_t)BT*2048*4;   // 16 MB
    float* xdbl    = (float*)p;  p += (size_t)BT*96*4;     // 768 KB
    float* dtb     = (float*)p;  p += (size_t)BT*2048*4;   // 16 MB
    float* xcur    = (float*)p;  p += (size_t)BT*1024*4;   // 8 MB
    ushort_t* xinb = (ushort_t*)p; p += (size_t)BT*1024*2; // 4 MB
    ushort_t* ysb  = (ushort_t*)p; p += (size_t)BT*2048*2; // 8 MB
    ushort_t* winb = (ushort_t*)p; p += (size_t)4096*1024*2; // 8 MB
    ushort_t* woutb= (ushort_t*)p; p += (size_t)1024*2048*2; // 4 MB

    // Aliases into dead windows (stream-ordered, verified per-layer order):
    //  - pbuf (x_proj split-K partials, 6.3 MB) overlays winb (dead after in_proj).
    //  - hpart/hdecay overlay winb after sk_reduce consumed pbuf.
    //  - hstart overlays xinb (consumed by in_proj before scan_fix writes it;
    //    out_proj rewrites xinb after scan_p3 is done reading hstart).
    float* pbuf   = (float*)winb;
    float* hpart  = (float*)winb;
    float* hdecay = hpart + (size_t)NCHUNK*BB*D_INNER*16;
    float* hstart = (float*)xinb;

    // Layer 0's bf16 input; later layers get xinb from out_proj's epilogue.
    f2b_k<<<(BT*1024)/1024,256,0,stream>>>(x, xinb, BT*1024);

    for (int i = 0; i < N_LAYERS; ++i){
        const float* xin = (i==0) ? x : xcur;
        // weight conversions for this layer (one launch)
        f2b2_k<<<(4096*1024 + 1024*2048)/1024,256,0,stream>>>(
            in_w + (size_t)i*4096*D_MODEL, winb, (4096*1024)/4,
            out_w + (size_t)i*D_MODEL*D_INNER, woutb);
        // xz = xin @ in_w^T   (2048 x 4096 x K=1024), bf16 MFMA
        gemm_mfma<0><<<dim3(4096/128, BT/128),256,0,stream>>>(
            xinb, winb, xz, BT, 4096, D_MODEL, nullptr, nullptr);
        // uc = silu(causal_conv(u) + cb)
        conv_silu_k<<<(BT*D_INNER)/256,256,0,stream>>>(
            xz, conv_w + (size_t)i*D_INNER*D_CONV, conv_b + (size_t)i*D_INNER, uc);
        // x_dbl = uc @ xp_w^T  (2048 x 96 x K=2048), fp32 split-K
        gemm_tn_sk<<<dim3(2,32,XP_KS),256,0,stream>>>(
            uc, D_INNER, xp_w + (size_t)i*96*D_INNER, D_INNER,
            pbuf, BT, 96, D_INNER);
        sk_reduce<<<(BT*96)/256,256,0,stream>>>(pbuf, xdbl, BT*96);
        // dt = softplus(dt_r @ dtp_w^T + dtp_b)  (2048 x 2048 x K=64), fp32
        gemm_tn<1><<<dim3(32,32),256,0,stream>>>(
            xdbl, 96, dtp_w + (size_t)i*D_INNER*DT_RANK, DT_RANK,
            dtb, D_INNER, BT, D_INNER, DT_RANK, dtp_b + (size_t)i*D_INNER);
        // chunked selective scan + fused (y + u*D)*silu(z) -> bf16
        scan_p1<<<dim3(D_INNER/256, BB, NCHUNK),256,0,stream>>>(
            dtb, uc, xdbl, A_log + (size_t)i*D_INNER*D_STATE, hpart, hdecay);
        scan_fix<<<(BB*D_INNER*16)/256,256,0,stream>>>(hpart, hdecay, hstart);
        scan_p3<<<dim3(D_INNER/256, BB, NCHUNK),256,0,stream>>>(
            dtb, uc, xdbl, A_log + (size_t)i*D_INNER*D_STATE, xz,
            Dd + (size_t)i*D_INNER, hstart, ysb);
        // xcur = ys @ out_w^T + xin, bf16 MFMA + residual; also emits bf16 xinb
        gemm_mfma<2><<<dim3(1024/128, BT/128),256,0,stream>>>(
            ysb, woutb, xcur, BT, 1024, D_INNER, xin, xinb);
    }
    layernorm_k<<<BT,256,0,stream>>>(xcur, nw, nb, out);
}

// Round 7
// 845.071 us; speedup vs baseline: 4.7355x; 1.0635x over previous
//
#include <hip/hip_runtime.h>
#include <hip/hip_bf16.h>

#define N_LAYERS 4
#define D_MODEL  1024
#define D_INNER  2048
#define D_STATE  16
#define D_CONV   4
#define DT_RANK  64
#define BB       2
#define TT       1024
#define BT       (BB*TT)   // 2048 rows (b*T)

#define NCHUNK 16
#define SCTC   (TT/NCHUNK)   // 64 timesteps per chunk

#define XP_KS  8             // x_proj K-split factor

typedef unsigned short ushort_t;
typedef __attribute__((ext_vector_type(8))) short short8;
typedef __attribute__((ext_vector_type(4))) float f32x4;

__device__ __forceinline__ float sigmoidf_(float x){ return 1.f/(1.f+__expf(-x)); }
__device__ __forceinline__ float siluf_(float x){ return x*sigmoidf_(x); }
__device__ __forceinline__ float softplusf_(float x){ return fmaxf(x,0.f) + log1pf(__expf(-fabsf(x))); }
__device__ __forceinline__ ushort_t f2b(float f){
    unsigned int x = __builtin_bit_cast(unsigned int, f);
    unsigned int r = (x + 0x7fffu + ((x>>16)&1u)) >> 16;   // RNE
    return (ushort_t)r;
}
__device__ __forceinline__ float b2f(ushort_t u){
    unsigned int x = ((unsigned int)u) << 16;
    return __builtin_bit_cast(float, x);
}

#define GLOAD(g, l) __builtin_amdgcn_global_load_lds( \
    (const __attribute__((address_space(1))) void*)(g), \
    (__attribute__((address_space(3))) void*)(l), 16, 0, 0)

// fp32 -> bf16 conversion, 4 elems/thread.
__global__ __launch_bounds__(256) void f2b_k(const float* __restrict__ in,
                                             ushort_t* __restrict__ out, int n){
    int i = blockIdx.x*256 + threadIdx.x;
    float4 v = ((const float4*)in)[i];
    ushort4 o;
    o.x = f2b(v.x); o.y = f2b(v.y); o.z = f2b(v.z); o.w = f2b(v.w);
    ((ushort4*)out)[i] = o;
}

// Two-buffer fp32->bf16 in one launch (na4 = float4 count of buffer a).
__global__ __launch_bounds__(256) void f2b2_k(
    const float* __restrict__ a, ushort_t* __restrict__ ao, int na4,
    const float* __restrict__ b, ushort_t* __restrict__ bo){
    int i = blockIdx.x*256 + threadIdx.x;
    const float4* src; ushort4* dst; int j;
    if (i < na4){ src = (const float4*)a; dst = (ushort4*)ao; j = i; }
    else        { src = (const float4*)b; dst = (ushort4*)bo; j = i - na4; }
    float4 v = src[j];
    ushort4 o;
    o.x = f2b(v.x); o.y = f2b(v.y); o.z = f2b(v.z); o.w = f2b(v.w);
    dst[j] = o;
}

// bf16 MFMA GEMM: C[M][N] = A[M][K] @ W[N][K]^T.
// 128x128 tile, BK=32, 4 waves (2x2), wave = 64x64 via 4x4 16x16x32 frags.
// Depth-3 software pipeline: 4 LDS buffers, STAGE(t+3) each iter, steady
// vmcnt(8) (3 stages of 4 loads in flight, wait for oldest), ONE raw
// s_barrier per iter (placed so it also protects buffer reuse).
// 1D grid + XCD rect swizzle: bid&7 = XCD, each XCD owns an RMxRN rect.
// EPI: 2 = +res, store fp32 C AND bf16 outb; 3 = store bf16 outb only.
template<int EPI>
__global__ __launch_bounds__(256) void gemm_mfma(
    const ushort_t* __restrict__ A, const ushort_t* __restrict__ W,
    float* __restrict__ C, int M, int N, int K,
    const float* __restrict__ res, ushort_t* __restrict__ outb,
    int RM, int RN, int XN)
{
    __shared__ ushort_t As[4][128*32];
    __shared__ ushort_t Ws[4][128*32];
    const int tid  = threadIdx.x;
    const int lane = tid & 63;
    const int wv   = tid >> 6;
    const int wm0  = (wv>>1)*64, wn0 = (wv&1)*64;

    const int bid = blockIdx.x;
    const int xcd = bid & 7, bi = bid >> 3;
    const int xm = xcd / XN, xn = xcd - xm*XN;
    const int m0 = (xm*RM + bi/RN)*128;
    const int n0 = (xn*RN + bi - (bi/RN)*RN)*128;

    const int r0 = tid>>2, ch = tid&3;

    f32x4 acc[4][4];
    #pragma unroll
    for (int i=0;i<4;++i)
        #pragma unroll
        for (int j=0;j<4;++j) acc[i][j] = (f32x4){0.f,0.f,0.f,0.f};

    const int row_a = lane & 15, kc = (lane>>4)*8;
    const ushort_t* gA = A + (size_t)(m0+r0)*K + ch*8;
    const ushort_t* gW = W + (size_t)(n0+r0)*K + ch*8;

#define STAGE(KT, BUF) { \
    const ushort_t* pA_ = gA + (KT)*32; \
    const ushort_t* pW_ = gW + (KT)*32; \
    GLOAD(pA_,                (char*)&As[BUF][0] + tid*16); \
    GLOAD(pA_ + 64*(size_t)K, (char*)&As[BUF][0] + tid*16 + 4096); \
    GLOAD(pW_,                (char*)&Ws[BUF][0] + tid*16); \
    GLOAD(pW_ + 64*(size_t)K, (char*)&Ws[BUF][0] + tid*16 + 4096); }

#define COMPUTE(BUF) { \
    short8 af[4], bf[4]; \
    _Pragma("unroll") \
    for (int i=0;i<4;++i){ \
        af[i] = *(const short8*)&As[BUF][(wm0 + i*16 + row_a)*32 + kc]; \
        bf[i] = *(const short8*)&Ws[BUF][(wn0 + i*16 + row_a)*32 + kc]; } \
    _Pragma("unroll") \
    for (int i=0;i<4;++i) \
        _Pragma("unroll") \
        for (int j=0;j<4;++j) \
            acc[i][j] = __builtin_amdgcn_mfma_f32_16x16x32_bf16(af[i], bf[j], acc[i][j], 0,0,0); }

    const int nt = K >> 5;          // >= 4 always here (min K = 1024)
    STAGE(0, 0); STAGE(1, 1); STAGE(2, 2);
    for (int t = 0; t < nt-3; ++t){
        asm volatile("s_waitcnt vmcnt(8)" ::: "memory");
        asm volatile("s_barrier" ::: "memory");
        STAGE(t+3, (t+3)&3);
        COMPUTE(t&3);
    }
    asm volatile("s_waitcnt vmcnt(8)" ::: "memory");
    asm volatile("s_barrier" ::: "memory");
    COMPUTE((nt-3)&3);
    asm volatile("s_waitcnt vmcnt(4)" ::: "memory");
    asm volatile("s_barrier" ::: "memory");
    COMPUTE((nt-2)&3);
    asm volatile("s_waitcnt vmcnt(0)" ::: "memory");
    asm volatile("s_barrier" ::: "memory");
    COMPUTE((nt-1)&3);
#undef STAGE
#undef COMPUTE

    const int crow = (lane>>4)*4, ccol = lane & 15;
    #pragma unroll
    for (int i=0;i<4;++i){
        #pragma unroll
        for (int j=0;j<4;++j){
            #pragma unroll
            for (int r=0;r<4;++r){
                int m = m0 + wm0 + i*16 + crow + r;
                int n = n0 + wn0 + j*16 + ccol;
                float v = acc[i][j][r];
                if (EPI==2) v += res[(size_t)m*N + n];
                if (EPI!=3) C[(size_t)m*N + n] = v;
                outb[(size_t)m*N + n] = f2b(v);
            }
        }
    }
}

// fp32 GEMM: C[M][N] = A[M][K] @ W[N][K]^T, 64x64 tile, BK=16.
// EPI: 0 plain, 1 = softplus(c + bias[n])
template<int EPI>
__global__ __launch_bounds__(256) void gemm_tn(
    const float* __restrict__ A, int lda,
    const float* __restrict__ W, int ldw,
    float* __restrict__ C, int ldc,
    int M, int N, int K,
    const float* __restrict__ bias)
{
    __shared__ float As[16][68];
    __shared__ float Ws[16][68];
    const int tid = threadIdx.x;
    const int tx = tid & 15, ty = tid >> 4;
    const int m0 = blockIdx.y * 64, n0 = blockIdx.x * 64;
    const int lr = tid >> 2;
    const int lk = (tid & 3) << 2;
    float acc[4][4] = {{0.f}};

    for (int k0 = 0; k0 < K; k0 += 16) {
        float4 av = *(const float4*)(A + (size_t)(m0+lr)*lda + k0 + lk);
        float4 wv = make_float4(0.f,0.f,0.f,0.f);
        if (n0 + lr < N) wv = *(const float4*)(W + (size_t)(n0+lr)*ldw + k0 + lk);
        __syncthreads();
        As[lk+0][lr]=av.x; As[lk+1][lr]=av.y; As[lk+2][lr]=av.z; As[lk+3][lr]=av.w;
        Ws[lk+0][lr]=wv.x; Ws[lk+1][lr]=wv.y; Ws[lk+2][lr]=wv.z; Ws[lk+3][lr]=wv.w;
        __syncthreads();
        #pragma unroll
        for (int k = 0; k < 16; ++k) {
            float4 a = *(const float4*)&As[k][ty<<2];
            float4 b = *(const float4*)&Ws[k][tx<<2];
            float a4[4] = {a.x,a.y,a.z,a.w};
            float b4[4] = {b.x,b.y,b.z,b.w};
            #pragma unroll
            for (int i=0;i<4;++i)
                #pragma unroll
                for (int j=0;j<4;++j)
                    acc[i][j] = fmaf(a4[i], b4[j], acc[i][j]);
        }
    }

    #pragma unroll
    for (int i=0;i<4;++i){
        int m = m0 + (ty<<2) + i;
        #pragma unroll
        for (int j=0;j<4;++j){
            int n = n0 + (tx<<2) + j;
            if (n < N){
                float v = acc[i][j];
                if (EPI==1) v = softplusf_(v + bias[n]);
                C[(size_t)m*ldc + n] = v;
            }
        }
    }
}

// Split-K fp32 GEMM for skinny N: grid (N/64, M/64, XP_KS).
__global__ __launch_bounds__(256) void gemm_tn_sk(
    const float* __restrict__ A, int lda,
    const float* __restrict__ W, int ldw,
    float* __restrict__ P, int M, int N, int K)
{
    __shared__ float As[16][68];
    __shared__ float Ws[16][68];
    const int tid = threadIdx.x;
    const int tx = tid & 15, ty = tid >> 4;
    const int m0 = blockIdx.y * 64, n0 = blockIdx.x * 64;
    const int kbase = blockIdx.z * (K/XP_KS);
    const int lr = tid >> 2;
    const int lk = (tid & 3) << 2;
    float acc[4][4] = {{0.f}};

    for (int kk = 0; kk < K/XP_KS; kk += 16) {
        int k0 = kbase + kk;
        float4 av = *(const float4*)(A + (size_t)(m0+lr)*lda + k0 + lk);
        float4 wv = make_float4(0.f,0.f,0.f,0.f);
        if (n0 + lr < N) wv = *(const float4*)(W + (size_t)(n0+lr)*ldw + k0 + lk);
        __syncthreads();
        As[lk+0][lr]=av.x; As[lk+1][lr]=av.y; As[lk+2][lr]=av.z; As[lk+3][lr]=av.w;
        Ws[lk+0][lr]=wv.x; Ws[lk+1][lr]=wv.y; Ws[lk+2][lr]=wv.z; Ws[lk+3][lr]=wv.w;
        __syncthreads();
        #pragma unroll
        for (int k = 0; k < 16; ++k) {
            float4 a = *(const float4*)&As[k][ty<<2];
            float4 b = *(const float4*)&Ws[k][tx<<2];
            float a4[4] = {a.x,a.y,a.z,a.w};
            float b4[4] = {b.x,b.y,b.z,b.w};
            #pragma unroll
            for (int i=0;i<4;++i)
                #pragma unroll
                for (int j=0;j<4;++j)
                    acc[i][j] = fmaf(a4[i], b4[j], acc[i][j]);
        }
    }

    float* Pz = P + (size_t)blockIdx.z * M * 96;
    #pragma unroll
    for (int i=0;i<4;++i){
        int m = m0 + (ty<<2) + i;
        #pragma unroll
        for (int j=0;j<4;++j){
            int n = n0 + (tx<<2) + j;
            if (n < N) Pz[(size_t)m*96 + n] = acc[i][j];
        }
    }
}

// xdbl[g] = sum_ks P[ks][g], g over M*96.
__global__ __launch_bounds__(256) void sk_reduce(
    const float* __restrict__ P, float* __restrict__ outp, int MN)
{
    int g = blockIdx.x*256 + threadIdx.x;
    float s = 0.f;
    #pragma unroll
    for (int ks=0; ks<XP_KS; ++ks) s += P[(size_t)ks*MN + g];
    outp[g] = s;
}

// Depthwise causal conv (K=4) + bias + SiLU, bf16 input xzb. u = xzb[..., :2048].
__global__ __launch_bounds__(256) void conv_silu_k(
    const ushort_t* __restrict__ xzb, const float* __restrict__ cw,
    const float* __restrict__ cb, float* __restrict__ uc)
{
    int idx = blockIdx.x*256 + threadIdx.x;
    int d  = idx & (D_INNER-1);
    int bt = idx >> 11;
    int t  = bt & (TT-1);
    float4 w4 = *(const float4*)(cw + d*4);
    float wv[4] = {w4.x, w4.y, w4.z, w4.w};
    float acc = cb[d];
    #pragma unroll
    for (int k=0;k<4;++k){
        int tt = t - 3 + k;
        if (tt >= 0) acc = fmaf(b2f(xzb[(size_t)(bt-3+k)*4096 + d]), wv[k], acc);
    }
    uc[idx] = siluf_(acc);
}

// ---- Chunked selective scan, 3 phases. Lane = channel, 16 states in regs. ----

__global__ __launch_bounds__(256) void scan_p1(
    const float* __restrict__ dt, const float* __restrict__ uc,
    const float* __restrict__ xdbl, const float* __restrict__ A_log,
    float* __restrict__ hpart, float* __restrict__ hdecay)
{
    const int tid = threadIdx.x;
    const int d = blockIdx.x*256 + tid;
    const int b = blockIdx.y;
    const int k = blockIdx.z;
    const int t0 = k*SCTC;
    float A[16];
    #pragma unroll
    for (int q=0;q<4;++q){
        float4 v = *(const float4*)(A_log + (size_t)d*16 + q*4);
        A[q*4+0]=-__expf(v.x); A[q*4+1]=-__expf(v.y);
        A[q*4+2]=-__expf(v.z); A[q*4+3]=-__expf(v.w);
    }
    float h[16];
    #pragma unroll
    for (int s=0;s<16;++s) h[s]=0.f;
    float sumdt = 0.f;
    const float* dtp = dt + ((size_t)b*TT + t0)*D_INNER + d;
    const float* ucp = uc + ((size_t)b*TT + t0)*D_INNER + d;
    const float* bcp = xdbl + ((size_t)b*TT + t0)*96 + 64;
    #pragma unroll 2
    for (int t=0;t<SCTC;++t){
        float dtv = dtp[(size_t)t*D_INNER];
        float uv  = ucp[(size_t)t*D_INNER];
        const float* bc = bcp + (size_t)t*96;
        float du = dtv*uv;
        sumdt += dtv;
        #pragma unroll
        for (int s=0;s<16;++s)
            h[s] = fmaf(__expf(dtv*A[s]), h[s], du*bc[s]);
    }
    size_t base = ((size_t)(k*BB+b)*D_INNER + d)*16;
    float4* hp = (float4*)(hpart + base);
    float4* hd = (float4*)(hdecay + base);
    #pragma unroll
    for (int q=0;q<4;++q){
        hp[q] = make_float4(h[q*4],h[q*4+1],h[q*4+2],h[q*4+3]);
        hd[q] = make_float4(__expf(sumdt*A[q*4+0]),__expf(sumdt*A[q*4+1]),
                            __expf(sumdt*A[q*4+2]),__expf(sumdt*A[q*4+3]));
    }
}

__global__ __launch_bounds__(256) void scan_fix(
    const float* __restrict__ hpart, const float* __restrict__ hdecay,
    float* __restrict__ hstart)
{
    int g = blockIdx.x*256 + threadIdx.x;
    float h = 0.f;
    #pragma unroll
    for (int k=0;k<NCHUNK;++k){
        size_t idx = (size_t)k*(BB*D_INNER*16) + g;
        hstart[idx] = h;
        h = fmaf(hdecay[idx], h, hpart[idx]);
    }
}

__global__ __launch_bounds__(256) void scan_p3(
    const float* __restrict__ dt, const float* __restrict__ uc,
    const float* __restrict__ xdbl, const float* __restrict__ A_log,
    const ushort_t* __restrict__ xzb, const float* __restrict__ Dd,
    const float* __restrict__ hstart, ushort_t* __restrict__ ysb)
{
    const int tid = threadIdx.x;
    const int d = blockIdx.x*256 + tid;
    const int b = blockIdx.y;
    const int k = blockIdx.z;
    const int t0 = k*SCTC;
    float A[16];
    #pragma unroll
    for (int q=0;q<4;++q){
        float4 v = *(const float4*)(A_log + (size_t)d*16 + q*4);
        A[q*4+0]=-__expf(v.x); A[q*4+1]=-__expf(v.y);
        A[q*4+2]=-__expf(v.z); A[q*4+3]=-__expf(v.w);
    }
    float h[16];
    {
        const float4* hs = (const float4*)(hstart + ((size_t)(k*BB+b)*D_INNER + d)*16);
        #pragma unroll
        for (int q=0;q<4;++q){
            float4 v = hs[q];
            h[q*4+0]=v.x; h[q*4+1]=v.y; h[q*4+2]=v.z; h[q*4+3]=v.w;
        }
    }
    const float Ddc = Dd[d];
    const float* dtp = dt + ((size_t)b*TT + t0)*D_INNER + d;
    const float* ucp = uc + ((size_t)b*TT + t0)*D_INNER + d;
    const ushort_t* zp = xzb + ((size_t)b*TT + t0)*4096 + 2048 + d;
    const float* bcp = xdbl + ((size_t)b*TT + t0)*96 + 64;
    ushort_t* yp = ysb + ((size_t)b*TT + t0)*D_INNER + d;
    #pragma unroll 2
    for (int t=0;t<SCTC;++t){
        float dtv = dtp[(size_t)t*D_INNER];
        float uv  = ucp[(size_t)t*D_INNER];
        float zv  = b2f(zp[(size_t)t*4096]);
        const float* bc = bcp + (size_t)t*96;
        float du = dtv*uv;
        float y0=0.f,y1=0.f,y2=0.f,y3=0.f;
        #pragma unroll
        for (int q=0;q<4;++q){
            h[q*4+0] = fmaf(__expf(dtv*A[q*4+0]), h[q*4+0], du*bc[q*4+0]);
            h[q*4+1] = fmaf(__expf(dtv*A[q*4+1]), h[q*4+1], du*bc[q*4+1]);
            h[q*4+2] = fmaf(__expf(dtv*A[q*4+2]), h[q*4+2], du*bc[q*4+2]);
            h[q*4+3] = fmaf(__expf(dtv*A[q*4+3]), h[q*4+3], du*bc[q*4+3]);
        }
        #pragma unroll
        for (int q=0;q<4;++q){
            y0 = fmaf(h[q*4+0], bc[16+q*4+0], y0);
            y1 = fmaf(h[q*4+1], bc[16+q*4+1], y1);
            y2 = fmaf(h[q*4+2], bc[16+q*4+2], y2);
            y3 = fmaf(h[q*4+3], bc[16+q*4+3], y3);
        }
        float y = (y0+y1)+(y2+y3);
        float yv = (y + uv*Ddc) * siluf_(zv);
        yp[(size_t)t*D_INNER] = f2b(yv);
    }
}

__global__ __launch_bounds__(256) void layernorm_k(
    const float* __restrict__ X, const float* __restrict__ w,
    const float* __restrict__ b, float* __restrict__ out)
{
    int row = blockIdx.x;
    int tid = threadIdx.x;
    const float* xr = X + (size_t)row*D_MODEL;
    float4 v = *(const float4*)(xr + tid*4);
    float s  = v.x+v.y+v.z+v.w;
    float ss = fmaf(v.x,v.x, fmaf(v.y,v.y, fmaf(v.z,v.z, v.w*v.w)));
    #pragma unroll
    for (int off=32; off>0; off>>=1){
        s  += __shfl_down(s, off, 64);
        ss += __shfl_down(ss, off, 64);
    }
    __shared__ float red[8];
    int wid = tid>>6, lane = tid&63;
    if (lane==0){ red[wid]=s; red[4+wid]=ss; }
    __syncthreads();
    if (tid==0){
        float S  = red[0]+red[1]+red[2]+red[3];
        float SS = red[4]+red[5]+red[6]+red[7];
        float mu = S*(1.f/D_MODEL);
        float var = SS*(1.f/D_MODEL) - mu*mu;
        red[0]=mu; red[1]=rsqrtf(var + 1e-5f);
    }
    __syncthreads();
    float mu=red[0], rs=red[1];
    float4 wv = *(const float4*)(w + tid*4);
    float4 bv = *(const float4*)(b + tid*4);
    float4 o;
    o.x = fmaf((v.x-mu)*rs, wv.x, bv.x);
    o.y = fmaf((v.y-mu)*rs, wv.y, bv.y);
    o.z = fmaf((v.z-mu)*rs, wv.z, bv.z);
    o.w = fmaf((v.w-mu)*rs, wv.w, bv.w);
    *(float4*)(out + (size_t)row*D_MODEL + tid*4) = o;
}

extern "C" void kernel_launch(void* const* d_in, const int* in_sizes, int n_in,
                              void* d_out, int out_size, void* d_ws, size_t ws_size,
                              hipStream_t stream) {
    (void)in_sizes; (void)n_in; (void)out_size; (void)ws_size;
    const float* x      = (const float*)d_in[0];
    const float* in_w   = (const float*)d_in[1];
    const float* conv_w = (const float*)d_in[2];
    const float* conv_b = (const float*)d_in[3];
    const float* xp_w   = (const float*)d_in[4];
    const float* dtp_w  = (const float*)d_in[5];
    const float* dtp_b  = (const float*)d_in[6];
    const float* A_log  = (const float*)d_in[7];
    const float* Dd     = (const float*)d_in[8];
    const float* out_w  = (const float*)d_in[9];
    const float* nw     = (const float*)d_in[10];
    const float* nb     = (const float*)d_in[11];
    float* out = (float*)d_out;

    char* p = (char*)d_ws;
    ushort_t* xzb  = (ushort_t*)p; p += (size_t)BT*4096*2;   // 16 MB (bf16 xz)
    float* uc      = (float*)p;  p += (size_t)BT*2048*4;     // 16 MB
    float* xdbl    = (float*)p;  p += (size_t)BT*96*4;       // 768 KB
    float* dtb     = (float*)p;  p += (size_t)BT*2048*4;     // 16 MB
    float* xcur    = (float*)p;  p += (size_t)BT*1024*4;     // 8 MB
    ushort_t* xinb = (ushort_t*)p; p += (size_t)BT*1024*2;   // 4 MB
    ushort_t* ysb  = (ushort_t*)p; p += (size_t)BT*2048*2;   // 8 MB
    ushort_t* winb = (ushort_t*)p; p += (size_t)4096*1024*2; // 8 MB
    ushort_t* woutb= (ushort_t*)p; p += (size_t)1024*2048*2; // 4 MB

    // Aliases into dead windows (stream-ordered, per-layer order verified):
    //  - pbuf (x_proj split-K partials, 6.3 MB) overlays winb (dead after in_proj).
    //  - hpart/hdecay overlay winb after sk_reduce consumed pbuf.
    //  - hstart overlays xinb (consumed by in_proj before scan_fix writes it;
    //    out_proj rewrites xinb after scan_p3 is done reading hstart).
    float* pbuf   = (float*)winb;
    float* hpart  = (float*)winb;
    float* hdecay = hpart + (size_t)NCHUNK*BB*D_INNER*16;
    float* hstart = (float*)xinb;

    // Layer 0's bf16 input; later layers get xinb from out_proj's epilogue.
    f2b_k<<<(BT*1024)/1024,256,0,stream>>>(x, xinb, BT*1024);

    for (int i = 0; i < N_LAYERS; ++i){
        const float* xin = (i==0) ? x : xcur;
        // weight conversions for this layer (one launch)
        f2b2_k<<<(4096*1024 + 1024*2048)/1024,256,0,stream>>>(
            in_w + (size_t)i*4096*D_MODEL, winb, (4096*1024)/4,
            out_w + (size_t)i*D_MODEL*D_INNER, woutb);
        // xz = xin @ in_w^T (2048x4096 K=1024), bf16 MFMA -> bf16 xzb.
        // grid 512: XCD rect 8x8 (XM=2, XN=4).
        gemm_mfma<3><<<512,256,0,stream>>>(
            xinb, winb, nullptr, BT, 4096, D_MODEL, nullptr, xzb, 8, 8, 4);
        // uc = silu(causal_conv(u) + cb)
        conv_silu_k<<<(BT*D_INNER)/256,256,0,stream>>>(
            xzb, conv_w + (size_t)i*D_INNER*D_CONV, conv_b + (size_t)i*D_INNER, uc);
        // x_dbl = uc @ xp_w^T  (2048 x 96 x K=2048), fp32 split-K
        gemm_tn_sk<<<dim3(2,32,XP_KS),256,0,stream>>>(
            uc, D_INNER, xp_w + (size_t)i*96*D_INNER, D_INNER,
            pbuf, BT, 96, D_INNER);
        sk_reduce<<<(BT*96)/256,256,0,stream>>>(pbuf, xdbl, BT*96);
        // dt = softplus(dt_r @ dtp_w^T + dtp_b)  (2048 x 2048 x K=64), fp32
        gemm_tn<1><<<dim3(32,32),256,0,stream>>>(
            xdbl, 96, dtp_w + (size_t)i*D_INNER*DT_RANK, DT_RANK,
            dtb, D_INNER, BT, D_INNER, DT_RANK, dtp_b + (size_t)i*D_INNER);
        // chunked selective scan + fused (y + u*D)*silu(z) -> bf16
        scan_p1<<<dim3(D_INNER/256, BB, NCHUNK),256,0,stream>>>(
            dtb, uc, xdbl, A_log + (size_t)i*D_INNER*D_STATE, hpart, hdecay);
        scan_fix<<<(BB*D_INNER*16)/256,256,0,stream>>>(hpart, hdecay, hstart);
        scan_p3<<<dim3(D_INNER/256, BB, NCHUNK),256,0,stream>>>(
            dtb, uc, xdbl, A_log + (size_t)i*D_INNER*D_STATE, xzb,
            Dd + (size_t)i*D_INNER, hstart, ysb);
        // xcur = ys @ out_w^T + xin, bf16 MFMA + residual; bf16 copy -> xinb.
        // grid 128: XCD rect 4x4 (XM=4, XN=2).
        gemm_mfma<2><<<128,256,0,stream>>>(
            ysb, woutb, xcur, BT, 1024, D_INNER, xin, xinb, 4, 4, 2);
    }
    layernorm_k<<<BT,256,0,stream>>>(xcur, nw, nb, out);
}

// Round 8
// 753.129 us; speedup vs baseline: 5.3136x; 1.1221x over previous
//
#include <hip/hip_runtime.h>
#include <hip/hip_bf16.h>

#define N_LAYERS 4
#define D_MODEL  1024
#define D_INNER  2048
#define D_STATE  16
#define D_CONV   4
#define DT_RANK  64
#define BB       2
#define TT       1024
#define BT       (BB*TT)   // 2048 rows (b*T)

#define NCHUNK 16
#define SCTC   (TT/NCHUNK)   // 64 timesteps per chunk

#define XP_KS  8             // x_proj K-split factor

typedef unsigned short ushort_t;
typedef __attribute__((ext_vector_type(8))) short short8;
typedef __attribute__((ext_vector_type(4))) float f32x4;

__device__ __forceinline__ float sigmoidf_(float x){ return 1.f/(1.f+__expf(-x)); }
__device__ __forceinline__ float siluf_(float x){ return x*sigmoidf_(x); }
__device__ __forceinline__ float softplusf_(float x){ return fmaxf(x,0.f) + log1pf(__expf(-fabsf(x))); }
__device__ __forceinline__ ushort_t f2b(float f){
    unsigned int x = __builtin_bit_cast(unsigned int, f);
    unsigned int r = (x + 0x7fffu + ((x>>16)&1u)) >> 16;   // RNE
    return (ushort_t)r;
}
__device__ __forceinline__ float b2f(ushort_t u){
    unsigned int x = ((unsigned int)u) << 16;
    return __builtin_bit_cast(float, x);
}

#define GLOAD(g, l) __builtin_amdgcn_global_load_lds( \
    (const __attribute__((address_space(1))) void*)(g), \
    (__attribute__((address_space(3))) void*)(l), 16, 0, 0)

// fp32 -> bf16 conversion, 4 elems/thread.
__global__ __launch_bounds__(256) void f2b_k(const float* __restrict__ in,
                                             ushort_t* __restrict__ out, int n){
    int i = blockIdx.x*256 + threadIdx.x;
    float4 v = ((const float4*)in)[i];
    ushort4 o;
    o.x = f2b(v.x); o.y = f2b(v.y); o.z = f2b(v.z); o.w = f2b(v.w);
    ((ushort4*)out)[i] = o;
}

// Two-buffer fp32->bf16 in one launch (na4 = float4 count of buffer a).
__global__ __launch_bounds__(256) void f2b2_k(
    const float* __restrict__ a, ushort_t* __restrict__ ao, int na4,
    const float* __restrict__ b, ushort_t* __restrict__ bo){
    int i = blockIdx.x*256 + threadIdx.x;
    const float4* src; ushort4* dst; int j;
    if (i < na4){ src = (const float4*)a; dst = (ushort4*)ao; j = i; }
    else        { src = (const float4*)b; dst = (ushort4*)bo; j = i - na4; }
    float4 v = src[j];
    ushort4 o;
    o.x = f2b(v.x); o.y = f2b(v.y); o.z = f2b(v.z); o.w = f2b(v.w);
    dst[j] = o;
}

// in_proj GEMM: outb[M][N](bf16) = A[M][K] @ W[N][K]^T. 128x128 tile, BK=32,
// 512 thr = 8 waves (2x4), wave = 64x32 via 4x2 16x16x32 frags (8 MFMA/step).
// Depth-3 pipeline, 4 LDS buffers, 2 global_load_lds per stage, steady
// vmcnt(4). 16 waves/CU at 2 blocks/CU. XCD rect swizzle (bid&7 = XCD).
__global__ __launch_bounds__(512) void gemm_ip(
    const ushort_t* __restrict__ A, const ushort_t* __restrict__ W,
    int M, int N, int K, ushort_t* __restrict__ outb,
    int RM, int RN, int XN)
{
    __shared__ ushort_t As[4][128*32];
    __shared__ ushort_t Ws[4][128*32];
    const int tid  = threadIdx.x;
    const int lane = tid & 63;
    const int wv   = tid >> 6;                 // 0..7
    const int wm0  = (wv>>2)*64, wn0 = (wv&3)*32;

    const int bid = blockIdx.x;
    const int xcd = bid & 7, bi = bid >> 3;
    const int xm = xcd / XN, xn = xcd - xm*XN;
    const int m0 = (xm*RM + bi/RN)*128;
    const int n0 = (xn*RN + bi - (bi/RN)*RN)*128;

    const int r0 = tid>>2, ch = tid&3;         // staging row / 16B chunk

    f32x4 acc[4][2];
    #pragma unroll
    for (int i=0;i<4;++i)
        #pragma unroll
        for (int j=0;j<2;++j) acc[i][j] = (f32x4){0.f,0.f,0.f,0.f};

    const int row_a = lane & 15, kc = (lane>>4)*8;
    const ushort_t* gA = A + (size_t)(m0+r0)*K + ch*8;
    const ushort_t* gW = W + (size_t)(n0+r0)*K + ch*8;

#define STAGE(KT, BUF) { \
    GLOAD(gA + (KT)*32, (char*)&As[BUF][0] + tid*16); \
    GLOAD(gW + (KT)*32, (char*)&Ws[BUF][0] + tid*16); }

#define COMPUTE(BUF) { \
    short8 af[4], bf[2]; \
    _Pragma("unroll") \
    for (int i=0;i<4;++i) af[i] = *(const short8*)&As[BUF][(wm0 + i*16 + row_a)*32 + kc]; \
    _Pragma("unroll") \
    for (int j=0;j<2;++j) bf[j] = *(const short8*)&Ws[BUF][(wn0 + j*16 + row_a)*32 + kc]; \
    _Pragma("unroll") \
    for (int i=0;i<4;++i) \
        _Pragma("unroll") \
        for (int j=0;j<2;++j) \
            acc[i][j] = __builtin_amdgcn_mfma_f32_16x16x32_bf16(af[i], bf[j], acc[i][j], 0,0,0); }

    const int nt = K >> 5;                     // >= 32 here
    STAGE(0, 0); STAGE(1, 1); STAGE(2, 2);
    for (int t = 0; t < nt-3; ++t){
        asm volatile("s_waitcnt vmcnt(4)" ::: "memory");
        asm volatile("s_barrier" ::: "memory");
        STAGE(t+3, (t+3)&3);
        COMPUTE(t&3);
    }
    asm volatile("s_waitcnt vmcnt(4)" ::: "memory");
    asm volatile("s_barrier" ::: "memory");
    COMPUTE((nt-3)&3);
    asm volatile("s_waitcnt vmcnt(2)" ::: "memory");
    asm volatile("s_barrier" ::: "memory");
    COMPUTE((nt-2)&3);
    asm volatile("s_waitcnt vmcnt(0)" ::: "memory");
    asm volatile("s_barrier" ::: "memory");
    COMPUTE((nt-1)&3);
#undef STAGE
#undef COMPUTE

    const int crow = (lane>>4)*4, ccol = lane & 15;
    #pragma unroll
    for (int i=0;i<4;++i){
        #pragma unroll
        for (int j=0;j<2;++j){
            #pragma unroll
            for (int r=0;r<4;++r){
                int m = m0 + wm0 + i*16 + crow + r;
                int n = n0 + wn0 + j*16 + ccol;
                outb[(size_t)m*N + n] = f2b(acc[i][j][r]);
            }
        }
    }
}

// out_proj GEMM: C = ys @ W^T + res (fp32), bf16 copy to outb. 64x64 tile,
// BK=32, 256 thr = 4 waves (2x2), wave = 32x32 via 2x2 frags (4 MFMA/step).
// Depth-3 pipeline, 4 LDS buffers, 2 loads/stage, vmcnt(4). Grid 512 blocks
// -> 2 blocks/CU everywhere. XCD rect swizzle.
__global__ __launch_bounds__(256) void gemm_op(
    const ushort_t* __restrict__ A, const ushort_t* __restrict__ W,
    float* __restrict__ C, int M, int N, int K,
    const float* __restrict__ res, ushort_t* __restrict__ outb,
    int RM, int RN, int XN)
{
    __shared__ ushort_t As[4][64*32];
    __shared__ ushort_t Ws[4][64*32];
    const int tid  = threadIdx.x;
    const int lane = tid & 63;
    const int wv   = tid >> 6;                 // 0..3
    const int wm0  = (wv>>1)*32, wn0 = (wv&1)*32;

    const int bid = blockIdx.x;
    const int xcd = bid & 7, bi = bid >> 3;
    const int xm = xcd / XN, xn = xcd - xm*XN;
    const int m0 = (xm*RM + bi/RN)*64;
    const int n0 = (xn*RN + bi - (bi/RN)*RN)*64;

    const int r0 = tid>>2, ch = tid&3;         // 64 rows x 4 chunks

    f32x4 acc[2][2];
    #pragma unroll
    for (int i=0;i<2;++i)
        #pragma unroll
        for (int j=0;j<2;++j) acc[i][j] = (f32x4){0.f,0.f,0.f,0.f};

    const int row_a = lane & 15, kc = (lane>>4)*8;
    const ushort_t* gA = A + (size_t)(m0+r0)*K + ch*8;
    const ushort_t* gW = W + (size_t)(n0+r0)*K + ch*8;

#define STAGE(KT, BUF) { \
    GLOAD(gA + (KT)*32, (char*)&As[BUF][0] + tid*16); \
    GLOAD(gW + (KT)*32, (char*)&Ws[BUF][0] + tid*16); }

#define COMPUTE(BUF) { \
    short8 af[2], bf[2]; \
    _Pragma("unroll") \
    for (int i=0;i<2;++i) af[i] = *(const short8*)&As[BUF][(wm0 + i*16 + row_a)*32 + kc]; \
    _Pragma("unroll") \
    for (int j=0;j<2;++j) bf[j] = *(const short8*)&Ws[BUF][(wn0 + j*16 + row_a)*32 + kc]; \
    _Pragma("unroll") \
    for (int i=0;i<2;++i) \
        _Pragma("unroll") \
        for (int j=0;j<2;++j) \
            acc[i][j] = __builtin_amdgcn_mfma_f32_16x16x32_bf16(af[i], bf[j], acc[i][j], 0,0,0); }

    const int nt = K >> 5;                     // 64 here
    STAGE(0, 0); STAGE(1, 1); STAGE(2, 2);
    for (int t = 0; t < nt-3; ++t){
        asm volatile("s_waitcnt vmcnt(4)" ::: "memory");
        asm volatile("s_barrier" ::: "memory");
        STAGE(t+3, (t+3)&3);
        COMPUTE(t&3);
    }
    asm volatile("s_waitcnt vmcnt(4)" ::: "memory");
    asm volatile("s_barrier" ::: "memory");
    COMPUTE((nt-3)&3);
    asm volatile("s_waitcnt vmcnt(2)" ::: "memory");
    asm volatile("s_barrier" ::: "memory");
    COMPUTE((nt-2)&3);
    asm volatile("s_waitcnt vmcnt(0)" ::: "memory");
    asm volatile("s_barrier" ::: "memory");
    COMPUTE((nt-1)&3);
#undef STAGE
#undef COMPUTE

    const int crow = (lane>>4)*4, ccol = lane & 15;
    #pragma unroll
    for (int i=0;i<2;++i){
        #pragma unroll
        for (int j=0;j<2;++j){
            #pragma unroll
            for (int r=0;r<4;++r){
                int m = m0 + wm0 + i*16 + crow + r;
                int n = n0 + wn0 + j*16 + ccol;
                float v = acc[i][j][r] + res[(size_t)m*N + n];
                C[(size_t)m*N + n] = v;
                outb[(size_t)m*N + n] = f2b(v);
            }
        }
    }
}

// fp32 GEMM: C[M][N] = A[M][K] @ W[N][K]^T, 64x64 tile, BK=16.
// EPI: 0 plain, 1 = softplus(c + bias[n])
template<int EPI>
__global__ __launch_bounds__(256) void gemm_tn(
    const float* __restrict__ A, int lda,
    const float* __restrict__ W, int ldw,
    float* __restrict__ C, int ldc,
    int M, int N, int K,
    const float* __restrict__ bias)
{
    __shared__ float As[16][68];
    __shared__ float Ws[16][68];
    const int tid = threadIdx.x;
    const int tx = tid & 15, ty = tid >> 4;
    const int m0 = blockIdx.y * 64, n0 = blockIdx.x * 64;
    const int lr = tid >> 2;
    const int lk = (tid & 3) << 2;
    float acc[4][4] = {{0.f}};

    for (int k0 = 0; k0 < K; k0 += 16) {
        float4 av = *(const float4*)(A + (size_t)(m0+lr)*lda + k0 + lk);
        float4 wv = make_float4(0.f,0.f,0.f,0.f);
        if (n0 + lr < N) wv = *(const float4*)(W + (size_t)(n0+lr)*ldw + k0 + lk);
        __syncthreads();
        As[lk+0][lr]=av.x; As[lk+1][lr]=av.y; As[lk+2][lr]=av.z; As[lk+3][lr]=av.w;
        Ws[lk+0][lr]=wv.x; Ws[lk+1][lr]=wv.y; Ws[lk+2][lr]=wv.z; Ws[lk+3][lr]=wv.w;
        __syncthreads();
        #pragma unroll
        for (int k = 0; k < 16; ++k) {
            float4 a = *(const float4*)&As[k][ty<<2];
            float4 b = *(const float4*)&Ws[k][tx<<2];
            float a4[4] = {a.x,a.y,a.z,a.w};
            float b4[4] = {b.x,b.y,b.z,b.w};
            #pragma unroll
            for (int i=0;i<4;++i)
                #pragma unroll
                for (int j=0;j<4;++j)
                    acc[i][j] = fmaf(a4[i], b4[j], acc[i][j]);
        }
    }

    #pragma unroll
    for (int i=0;i<4;++i){
        int m = m0 + (ty<<2) + i;
        #pragma unroll
        for (int j=0;j<4;++j){
            int n = n0 + (tx<<2) + j;
            if (n < N){
                float v = acc[i][j];
                if (EPI==1) v = softplusf_(v + bias[n]);
                C[(size_t)m*ldc + n] = v;
            }
        }
    }
}

// Split-K fp32 GEMM for skinny N: grid (N/64, M/64, XP_KS).
__global__ __launch_bounds__(256) void gemm_tn_sk(
    const float* __restrict__ A, int lda,
    const float* __restrict__ W, int ldw,
    float* __restrict__ P, int M, int N, int K)
{
    __shared__ float As[16][68];
    __shared__ float Ws[16][68];
    const int tid = threadIdx.x;
    const int tx = tid & 15, ty = tid >> 4;
    const int m0 = blockIdx.y * 64, n0 = blockIdx.x * 64;
    const int kbase = blockIdx.z * (K/XP_KS);
    const int lr = tid >> 2;
    const int lk = (tid & 3) << 2;
    float acc[4][4] = {{0.f}};

    for (int kk = 0; kk < K/XP_KS; kk += 16) {
        int k0 = kbase + kk;
        float4 av = *(const float4*)(A + (size_t)(m0+lr)*lda + k0 + lk);
        float4 wv = make_float4(0.f,0.f,0.f,0.f);
        if (n0 + lr < N) wv = *(const float4*)(W + (size_t)(n0+lr)*ldw + k0 + lk);
        __syncthreads();
        As[lk+0][lr]=av.x; As[lk+1][lr]=av.y; As[lk+2][lr]=av.z; As[lk+3][lr]=av.w;
        Ws[lk+0][lr]=wv.x; Ws[lk+1][lr]=wv.y; Ws[lk+2][lr]=wv.z; Ws[lk+3][lr]=wv.w;
        __syncthreads();
        #pragma unroll
        for (int k = 0; k < 16; ++k) {
            float4 a = *(const float4*)&As[k][ty<<2];
            float4 b = *(const float4*)&Ws[k][tx<<2];
            float a4[4] = {a.x,a.y,a.z,a.w};
            float b4[4] = {b.x,b.y,b.z,b.w};
            #pragma unroll
            for (int i=0;i<4;++i)
                #pragma unroll
                for (int j=0;j<4;++j)
                    acc[i][j] = fmaf(a4[i], b4[j], acc[i][j]);
        }
    }

    float* Pz = P + (size_t)blockIdx.z * M * 96;
    #pragma unroll
    for (int i=0;i<4;++i){
        int m = m0 + (ty<<2) + i;
        #pragma unroll
        for (int j=0;j<4;++j){
            int n = n0 + (tx<<2) + j;
            if (n < N) Pz[(size_t)m*96 + n] = acc[i][j];
        }
    }
}

// xdbl[g] = sum_ks P[ks][g], g over M*96.
__global__ __launch_bounds__(256) void sk_reduce(
    const float* __restrict__ P, float* __restrict__ outp, int MN)
{
    int g = blockIdx.x*256 + threadIdx.x;
    float s = 0.f;
    #pragma unroll
    for (int ks=0; ks<XP_KS; ++ks) s += P[(size_t)ks*MN + g];
    outp[g] = s;
}

// Depthwise causal conv (K=4) + bias + SiLU, bf16 input xzb. u = xzb[..., :2048].
__global__ __launch_bounds__(256) void conv_silu_k(
    const ushort_t* __restrict__ xzb, const float* __restrict__ cw,
    const float* __restrict__ cb, float* __restrict__ uc)
{
    int idx = blockIdx.x*256 + threadIdx.x;
    int d  = idx & (D_INNER-1);
    int bt = idx >> 11;
    int t  = bt & (TT-1);
    float4 w4 = *(const float4*)(cw + d*4);
    float wv[4] = {w4.x, w4.y, w4.z, w4.w};
    float acc = cb[d];
    #pragma unroll
    for (int k=0;k<4;++k){
        int tt = t - 3 + k;
        if (tt >= 0) acc = fmaf(b2f(xzb[(size_t)(bt-3+k)*4096 + d]), wv[k], acc);
    }
    uc[idx] = siluf_(acc);
}

// ---- Chunked selective scan, 3 phases. Lane = channel, 16 states in regs. ----

__global__ __launch_bounds__(256) void scan_p1(
    const float* __restrict__ dt, const float* __restrict__ uc,
    const float* __restrict__ xdbl, const float* __restrict__ A_log,
    float* __restrict__ hpart, float* __restrict__ hdecay)
{
    const int tid = threadIdx.x;
    const int d = blockIdx.x*256 + tid;
    const int b = blockIdx.y;
    const int k = blockIdx.z;
    const int t0 = k*SCTC;
    float A[16];
    #pragma unroll
    for (int q=0;q<4;++q){
        float4 v = *(const float4*)(A_log + (size_t)d*16 + q*4);
        A[q*4+0]=-__expf(v.x); A[q*4+1]=-__expf(v.y);
        A[q*4+2]=-__expf(v.z); A[q*4+3]=-__expf(v.w);
    }
    float h[16];
    #pragma unroll
    for (int s=0;s<16;++s) h[s]=0.f;
    float sumdt = 0.f;
    const float* dtp = dt + ((size_t)b*TT + t0)*D_INNER + d;
    const float* ucp = uc + ((size_t)b*TT + t0)*D_INNER + d;
    const float* bcp = xdbl + ((size_t)b*TT + t0)*96 + 64;
    #pragma unroll 2
    for (int t=0;t<SCTC;++t){
        float dtv = dtp[(size_t)t*D_INNER];
        float uv  = ucp[(size_t)t*D_INNER];
        const float* bc = bcp + (size_t)t*96;
        float du = dtv*uv;
        sumdt += dtv;
        #pragma unroll
        for (int s=0;s<16;++s)
            h[s] = fmaf(__expf(dtv*A[s]), h[s], du*bc[s]);
    }
    size_t base = ((size_t)(k*BB+b)*D_INNER + d)*16;
    float4* hp = (float4*)(hpart + base);
    float4* hd = (float4*)(hdecay + base);
    #pragma unroll
    for (int q=0;q<4;++q){
        hp[q] = make_float4(h[q*4],h[q*4+1],h[q*4+2],h[q*4+3]);
        hd[q] = make_float4(__expf(sumdt*A[q*4+0]),__expf(sumdt*A[q*4+1]),
                            __expf(sumdt*A[q*4+2]),__expf(sumdt*A[q*4+3]));
    }
}

__global__ __launch_bounds__(256) void scan_fix(
    const float* __restrict__ hpart, const float* __restrict__ hdecay,
    float* __restrict__ hstart)
{
    int g = blockIdx.x*256 + threadIdx.x;
    float h = 0.f;
    #pragma unroll
    for (int k=0;k<NCHUNK;++k){
        size_t idx = (size_t)k*(BB*D_INNER*16) + g;
        hstart[idx] = h;
        h = fmaf(hdecay[idx], h, hpart[idx]);
    }
}

__global__ __launch_bounds__(256) void scan_p3(
    const float* __restrict__ dt, const float* __restrict__ uc,
    const float* __restrict__ xdbl, const float* __restrict__ A_log,
    const ushort_t* __restrict__ xzb, const float* __restrict__ Dd,
    const float* __restrict__ hstart, ushort_t* __restrict__ ysb)
{
    const int tid = threadIdx.x;
    const int d = blockIdx.x*256 + tid;
    const int b = blockIdx.y;
    const int k = blockIdx.z;
    const int t0 = k*SCTC;
    float A[16];
    #pragma unroll
    for (int q=0;q<4;++q){
        float4 v = *(const float4*)(A_log + (size_t)d*16 + q*4);
        A[q*4+0]=-__expf(v.x); A[q*4+1]=-__expf(v.y);
        A[q*4+2]=-__expf(v.z); A[q*4+3]=-__expf(v.w);
    }
    float h[16];
    {
        const float4* hs = (const float4*)(hstart + ((size_t)(k*BB+b)*D_INNER + d)*16);
        #pragma unroll
        for (int q=0;q<4;++q){
            float4 v = hs[q];
            h[q*4+0]=v.x; h[q*4+1]=v.y; h[q*4+2]=v.z; h[q*4+3]=v.w;
        }
    }
    const float Ddc = Dd[d];
    const float* dtp = dt + ((size_t)b*TT + t0)*D_INNER + d;
    const float* ucp = uc + ((size_t)b*TT + t0)*D_INNER + d;
    const ushort_t* zp = xzb + ((size_t)b*TT + t0)*4096 + 2048 + d;
    const float* bcp = xdbl + ((size_t)b*TT + t0)*96 + 64;
    ushort_t* yp = ysb + ((size_t)b*TT + t0)*D_INNER + d;
    #pragma unroll 2
    for (int t=0;t<SCTC;++t){
        float dtv = dtp[(size_t)t*D_INNER];
        float uv  = ucp[(size_t)t*D_INNER];
        float zv  = b2f(zp[(size_t)t*4096]);
        const float* bc = bcp + (size_t)t*96;
        float du = dtv*uv;
        float y0=0.f,y1=0.f,y2=0.f,y3=0.f;
        #pragma unroll
        for (int q=0;q<4;++q){
            h[q*4+0] = fmaf(__expf(dtv*A[q*4+0]), h[q*4+0], du*bc[q*4+0]);
            h[q*4+1] = fmaf(__expf(dtv*A[q*4+1]), h[q*4+1], du*bc[q*4+1]);
            h[q*4+2] = fmaf(__expf(dtv*A[q*4+2]), h[q*4+2], du*bc[q*4+2]);
            h[q*4+3] = fmaf(__expf(dtv*A[q*4+3]), h[q*4+3], du*bc[q*4+3]);
        }
        #pragma unroll
        for (int q=0;q<4;++q){
            y0 = fmaf(h[q*4+0], bc[16+q*4+0], y0);
            y1 = fmaf(h[q*4+1], bc[16+q*4+1], y1);
            y2 = fmaf(h[q*4+2], bc[16+q*4+2], y2);
            y3 = fmaf(h[q*4+3], bc[16+q*4+3], y3);
        }
        float y = (y0+y1)+(y2+y3);
        float yv = (y + uv*Ddc) * siluf_(zv);
        yp[(size_t)t*D_INNER] = f2b(yv);
    }
}

__global__ __launch_bounds__(256) void layernorm_k(
    const float* __restrict__ X, const float* __restrict__ w,
    const float* __restrict__ b, float* __restrict__ out)
{
    int row = blockIdx.x;
    int tid = threadIdx.x;
    const float* xr = X + (size_t)row*D_MODEL;
    float4 v = *(const float4*)(xr + tid*4);
    float s  = v.x+v.y+v.z+v.w;
    float ss = fmaf(v.x,v.x, fmaf(v.y,v.y, fmaf(v.z,v.z, v.w*v.w)));
    #pragma unroll
    for (int off=32; off>0; off>>=1){
        s  += __shfl_down(s, off, 64);
        ss += __shfl_down(ss, off, 64);
    }
    __shared__ float red[8];
    int wid = tid>>6, lane = tid&63;
    if (lane==0){ red[wid]=s; red[4+wid]=ss; }
    __syncthreads();
    if (tid==0){
        float S  = red[0]+red[1]+red[2]+red[3];
        float SS = red[4]+red[5]+red[6]+red[7];
        float mu = S*(1.f/D_MODEL);
        float var = SS*(1.f/D_MODEL) - mu*mu;
        red[0]=mu; red[1]=rsqrtf(var + 1e-5f);
    }
    __syncthreads();
    float mu=red[0], rs=red[1];
    float4 wv = *(const float4*)(w + tid*4);
    float4 bv = *(const float4*)(b + tid*4);
    float4 o;
    o.x = fmaf((v.x-mu)*rs, wv.x, bv.x);
    o.y = fmaf((v.y-mu)*rs, wv.y, bv.y);
    o.z = fmaf((v.z-mu)*rs, wv.z, bv.z);
    o.w = fmaf((v.w-mu)*rs, wv.w, bv.w);
    *(float4*)(out + (size_t)row*D_MODEL + tid*4) = o;
}

extern "C" void kernel_launch(void* const* d_in, const int* in_sizes, int n_in,
                              void* d_out, int out_size, void* d_ws, size_t ws_size,
                              hipStream_t stream) {
    (void)in_sizes; (void)n_in; (void)out_size; (void)ws_size;
    const float* x      = (const float*)d_in[0];
    const float* in_w   = (const float*)d_in[1];
    const float* conv_w = (const float*)d_in[2];
    const float* conv_b = (const float*)d_in[3];
    const float* xp_w   = (const float*)d_in[4];
    const float* dtp_w  = (const float*)d_in[5];
    const float* dtp_b  = (const float*)d_in[6];
    const float* A_log  = (const float*)d_in[7];
    const float* Dd     = (const float*)d_in[8];
    const float* out_w  = (const float*)d_in[9];
    const float* nw     = (const float*)d_in[10];
    const float* nb     = (const float*)d_in[11];
    float* out = (float*)d_out;

    char* p = (char*)d_ws;
    ushort_t* xzb  = (ushort_t*)p; p += (size_t)BT*4096*2;   // 16 MB (bf16 xz)
    float* uc      = (float*)p;  p += (size_t)BT*2048*4;     // 16 MB
    float* xdbl    = (float*)p;  p += (size_t)BT*96*4;       // 768 KB
    float* dtb     = (float*)p;  p += (size_t)BT*2048*4;     // 16 MB
    float* xcur    = (float*)p;  p += (size_t)BT*1024*4;     // 8 MB
    ushort_t* xinb = (ushort_t*)p; p += (size_t)BT*1024*2;   // 4 MB
    ushort_t* ysb  = (ushort_t*)p; p += (size_t)BT*2048*2;   // 8 MB
    ushort_t* winb = (ushort_t*)p; p += (size_t)4096*1024*2; // 8 MB
    ushort_t* woutb= (ushort_t*)p; p += (size_t)1024*2048*2; // 4 MB

    // Aliases into dead windows (stream-ordered, per-layer order verified):
    //  - pbuf (x_proj split-K partials, 6.3 MB) overlays winb (dead after in_proj).
    //  - hpart/hdecay overlay winb after sk_reduce consumed pbuf.
    //  - hstart overlays xinb (consumed by in_proj before scan_fix writes it;
    //    out_proj rewrites xinb after scan_p3 is done reading hstart).
    float* pbuf   = (float*)winb;
    float* hpart  = (float*)winb;
    float* hdecay = hpart + (size_t)NCHUNK*BB*D_INNER*16;
    float* hstart = (float*)xinb;

    // Layer 0's bf16 input; later layers get xinb from out_proj's epilogue.
    f2b_k<<<(BT*1024)/1024,256,0,stream>>>(x, xinb, BT*1024);

    for (int i = 0; i < N_LAYERS; ++i){
        const float* xin = (i==0) ? x : xcur;
        // weight conversions for this layer (one launch)
        f2b2_k<<<(4096*1024 + 1024*2048)/1024,256,0,stream>>>(
            in_w + (size_t)i*4096*D_MODEL, winb, (4096*1024)/4,
            out_w + (size_t)i*D_MODEL*D_INNER, woutb);
        // xz = xin @ in_w^T (2048x4096 K=1024) -> bf16 xzb.
        // grid 512 (16x32 tiles of 128), XCD rect 8x8 (XM=2, XN=4), 512 thr.
        gemm_ip<<<512,512,0,stream>>>(
            xinb, winb, BT, 4096, D_MODEL, xzb, 8, 8, 4);
        // uc = silu(causal_conv(u) + cb)
        conv_silu_k<<<(BT*D_INNER)/256,256,0,stream>>>(
            xzb, conv_w + (size_t)i*D_INNER*D_CONV, conv_b + (size_t)i*D_INNER, uc);
        // x_dbl = uc @ xp_w^T  (2048 x 96 x K=2048), fp32 split-K
        gemm_tn_sk<<<dim3(2,32,XP_KS),256,0,stream>>>(
            uc, D_INNER, xp_w + (size_t)i*96*D_INNER, D_INNER,
            pbuf, BT, 96, D_INNER);
        sk_reduce<<<(BT*96)/256,256,0,stream>>>(pbuf, xdbl, BT*96);
        // dt = softplus(dt_r @ dtp_w^T + dtp_b)  (2048 x 2048 x K=64), fp32
        gemm_tn<1><<<dim3(32,32),256,0,stream>>>(
            xdbl, 96, dtp_w + (size_t)i*D_INNER*DT_RANK, DT_RANK,
            dtb, D_INNER, BT, D_INNER, DT_RANK, dtp_b + (size_t)i*D_INNER);
        // chunked selective scan + fused (y + u*D)*silu(z) -> bf16
        scan_p1<<<dim3(D_INNER/256, BB, NCHUNK),256,0,stream>>>(
            dtb, uc, xdbl, A_log + (size_t)i*D_INNER*D_STATE, hpart, hdecay);
        scan_fix<<<(BB*D_INNER*16)/256,256,0,stream>>>(hpart, hdecay, hstart);
        scan_p3<<<dim3(D_INNER/256, BB, NCHUNK),256,0,stream>>>(
            dtb, uc, xdbl, A_log + (size_t)i*D_INNER*D_STATE, xzb,
            Dd + (size_t)i*D_INNER, hstart, ysb);
        // xcur = ys @ out_w^T + xin (2048x1024 K=2048), fp32 + bf16 copy.
        // grid 512 (32x16 tiles of 64), XCD rect 8x8 (XM=4, XN=2), 256 thr.
        gemm_op<<<512,256,0,stream>>>(
            ysb, woutb, xcur, BT, 1024, D_INNER, xin, xinb, 8, 8, 2);
    }
    layernorm_k<<<BT,256,0,stream>>>(xcur, nw, nb, out);
}

// Round 9
// 681.640 us; speedup vs baseline: 5.8709x; 1.1049x over previous
//
#include <hip/hip_runtime.h>
#include <hip/hip_bf16.h>

#define N_LAYERS 4
#define D_MODEL  1024
#define D_INNER  2048
#define D_STATE  16
#define D_CONV   4
#define DT_RANK  64
#define BB       2
#define TT       1024
#define BT       (BB*TT)   // 2048 rows (b*T)

#define NCHUNK 32
#define SCTC   (TT/NCHUNK)   // 32 timesteps per chunk

#define XP_KS  8             // x_proj K-split factor

typedef unsigned short ushort_t;
typedef __attribute__((ext_vector_type(8))) short short8;
typedef __attribute__((ext_vector_type(4))) float f32x4;

__device__ __forceinline__ float sigmoidf_(float x){ return 1.f/(1.f+__expf(-x)); }
__device__ __forceinline__ float siluf_(float x){ return x*sigmoidf_(x); }
__device__ __forceinline__ float softplusf_(float x){ return fmaxf(x,0.f) + log1pf(__expf(-fabsf(x))); }
__device__ __forceinline__ ushort_t f2b(float f){
    unsigned int x = __builtin_bit_cast(unsigned int, f);
    unsigned int r = (x + 0x7fffu + ((x>>16)&1u)) >> 16;   // RNE
    return (ushort_t)r;
}
__device__ __forceinline__ float b2f(ushort_t u){
    unsigned int x = ((unsigned int)u) << 16;
    return __builtin_bit_cast(float, x);
}

#define GLOAD(g, l) __builtin_amdgcn_global_load_lds( \
    (const __attribute__((address_space(1))) void*)(g), \
    (__attribute__((address_space(3))) void*)(l), 16, 0, 0)

// fp32 -> bf16 conversion, 4 elems/thread.
__global__ __launch_bounds__(256) void f2b_k(const float* __restrict__ in,
                                             ushort_t* __restrict__ out, int n){
    int i = blockIdx.x*256 + threadIdx.x;
    float4 v = ((const float4*)in)[i];
    ushort4 o;
    o.x = f2b(v.x); o.y = f2b(v.y); o.z = f2b(v.z); o.w = f2b(v.w);
    ((ushort4*)out)[i] = o;
}

// Pre-convert ALL layers' weights (in_w, out_w, dtp_w) to bf16 in one launch.
__global__ __launch_bounds__(256) void f2bw_k(
    const float* __restrict__ in_w, const float* __restrict__ out_w,
    const float* __restrict__ dtp_w,
    ushort_t* __restrict__ winb, ushort_t* __restrict__ woutb,
    ushort_t* __restrict__ dtpb){
    const int n1 = (N_LAYERS*4096*1024)/4;
    const int n2 = (N_LAYERS*1024*2048)/4;
    int i = blockIdx.x*256 + threadIdx.x;
    const float4* src; ushort4* dst; int j;
    if (i < n1){ src=(const float4*)in_w;  dst=(ushort4*)winb;  j=i; }
    else if (i < n1+n2){ src=(const float4*)out_w; dst=(ushort4*)woutb; j=i-n1; }
    else { src=(const float4*)dtp_w; dst=(ushort4*)dtpb; j=i-n1-n2; }
    float4 v = src[j];
    ushort4 o;
    o.x = f2b(v.x); o.y = f2b(v.y); o.z = f2b(v.z); o.w = f2b(v.w);
    dst[j] = o;
}

// in_proj GEMM: outb[M][N](bf16) = A[M][K] @ W[N][K]^T. 128x128 tile, BK=32,
// 512 thr = 8 waves (2x4), wave = 64x32 via 4x2 frags. Depth-3 pipeline,
// 4 LDS buffers, vmcnt(4). XCD rect swizzle (bid&7 = XCD).
__global__ __launch_bounds__(512) void gemm_ip(
    const ushort_t* __restrict__ A, const ushort_t* __restrict__ W,
    int M, int N, int K, ushort_t* __restrict__ outb,
    int RM, int RN, int XN)
{
    __shared__ ushort_t As[4][128*32];
    __shared__ ushort_t Ws[4][128*32];
    const int tid  = threadIdx.x;
    const int lane = tid & 63;
    const int wv   = tid >> 6;
    const int wm0  = (wv>>2)*64, wn0 = (wv&3)*32;

    const int bid = blockIdx.x;
    const int xcd = bid & 7, bi = bid >> 3;
    const int xm = xcd / XN, xn = xcd - xm*XN;
    const int m0 = (xm*RM + bi/RN)*128;
    const int n0 = (xn*RN + bi - (bi/RN)*RN)*128;

    const int r0 = tid>>2, ch = tid&3;

    f32x4 acc[4][2];
    #pragma unroll
    for (int i=0;i<4;++i)
        #pragma unroll
        for (int j=0;j<2;++j) acc[i][j] = (f32x4){0.f,0.f,0.f,0.f};

    const int row_a = lane & 15, kc = (lane>>4)*8;
    const ushort_t* gA = A + (size_t)(m0+r0)*K + ch*8;
    const ushort_t* gW = W + (size_t)(n0+r0)*K + ch*8;

#define STAGE(KT, BUF) { \
    GLOAD(gA + (KT)*32, (char*)&As[BUF][0] + tid*16); \
    GLOAD(gW + (KT)*32, (char*)&Ws[BUF][0] + tid*16); }

#define COMPUTE(BUF) { \
    short8 af[4], bf[2]; \
    _Pragma("unroll") \
    for (int i=0;i<4;++i) af[i] = *(const short8*)&As[BUF][(wm0 + i*16 + row_a)*32 + kc]; \
    _Pragma("unroll") \
    for (int j=0;j<2;++j) bf[j] = *(const short8*)&Ws[BUF][(wn0 + j*16 + row_a)*32 + kc]; \
    _Pragma("unroll") \
    for (int i=0;i<4;++i) \
        _Pragma("unroll") \
        for (int j=0;j<2;++j) \
            acc[i][j] = __builtin_amdgcn_mfma_f32_16x16x32_bf16(af[i], bf[j], acc[i][j], 0,0,0); }

    const int nt = K >> 5;
    STAGE(0, 0); STAGE(1, 1); STAGE(2, 2);
    for (int t = 0; t < nt-3; ++t){
        asm volatile("s_waitcnt vmcnt(4)" ::: "memory");
        asm volatile("s_barrier" ::: "memory");
        STAGE(t+3, (t+3)&3);
        COMPUTE(t&3);
    }
    asm volatile("s_waitcnt vmcnt(4)" ::: "memory");
    asm volatile("s_barrier" ::: "memory");
    COMPUTE((nt-3)&3);
    asm volatile("s_waitcnt vmcnt(2)" ::: "memory");
    asm volatile("s_barrier" ::: "memory");
    COMPUTE((nt-2)&3);
    asm volatile("s_waitcnt vmcnt(0)" ::: "memory");
    asm volatile("s_barrier" ::: "memory");
    COMPUTE((nt-1)&3);
#undef STAGE
#undef COMPUTE

    const int crow = (lane>>4)*4, ccol = lane & 15;
    #pragma unroll
    for (int i=0;i<4;++i){
        #pragma unroll
        for (int j=0;j<2;++j){
            #pragma unroll
            for (int r=0;r<4;++r){
                int m = m0 + wm0 + i*16 + crow + r;
                int n = n0 + wn0 + j*16 + ccol;
                outb[(size_t)m*N + n] = f2b(acc[i][j][r]);
            }
        }
    }
}

// out_proj GEMM: C = ys @ W^T + res (fp32), bf16 copy to outb. 64x64 tile,
// BK=32, 4 waves of 32x32. Depth-3 pipeline, vmcnt(4). XCD rect swizzle.
__global__ __launch_bounds__(256) void gemm_op(
    const ushort_t* __restrict__ A, const ushort_t* __restrict__ W,
    float* __restrict__ C, int M, int N, int K,
    const float* __restrict__ res, ushort_t* __restrict__ outb,
    int RM, int RN, int XN)
{
    __shared__ ushort_t As[4][64*32];
    __shared__ ushort_t Ws[4][64*32];
    const int tid  = threadIdx.x;
    const int lane = tid & 63;
    const int wv   = tid >> 6;
    const int wm0  = (wv>>1)*32, wn0 = (wv&1)*32;

    const int bid = blockIdx.x;
    const int xcd = bid & 7, bi = bid >> 3;
    const int xm = xcd / XN, xn = xcd - xm*XN;
    const int m0 = (xm*RM + bi/RN)*64;
    const int n0 = (xn*RN + bi - (bi/RN)*RN)*64;

    const int r0 = tid>>2, ch = tid&3;

    f32x4 acc[2][2];
    #pragma unroll
    for (int i=0;i<2;++i)
        #pragma unroll
        for (int j=0;j<2;++j) acc[i][j] = (f32x4){0.f,0.f,0.f,0.f};

    const int row_a = lane & 15, kc = (lane>>4)*8;
    const ushort_t* gA = A + (size_t)(m0+r0)*K + ch*8;
    const ushort_t* gW = W + (size_t)(n0+r0)*K + ch*8;

#define STAGE(KT, BUF) { \
    GLOAD(gA + (KT)*32, (char*)&As[BUF][0] + tid*16); \
    GLOAD(gW + (KT)*32, (char*)&Ws[BUF][0] + tid*16); }

#define COMPUTE(BUF) { \
    short8 af[2], bf[2]; \
    _Pragma("unroll") \
    for (int i=0;i<2;++i) af[i] = *(const short8*)&As[BUF][(wm0 + i*16 + row_a)*32 + kc]; \
    _Pragma("unroll") \
    for (int j=0;j<2;++j) bf[j] = *(const short8*)&Ws[BUF][(wn0 + j*16 + row_a)*32 + kc]; \
    _Pragma("unroll") \
    for (int i=0;i<2;++i) \
        _Pragma("unroll") \
        for (int j=0;j<2;++j) \
            acc[i][j] = __builtin_amdgcn_mfma_f32_16x16x32_bf16(af[i], bf[j], acc[i][j], 0,0,0); }

    const int nt = K >> 5;
    STAGE(0, 0); STAGE(1, 1); STAGE(2, 2);
    for (int t = 0; t < nt-3; ++t){
        asm volatile("s_waitcnt vmcnt(4)" ::: "memory");
        asm volatile("s_barrier" ::: "memory");
        STAGE(t+3, (t+3)&3);
        COMPUTE(t&3);
    }
    asm volatile("s_waitcnt vmcnt(4)" ::: "memory");
    asm volatile("s_barrier" ::: "memory");
    COMPUTE((nt-3)&3);
    asm volatile("s_waitcnt vmcnt(2)" ::: "memory");
    asm volatile("s_barrier" ::: "memory");
    COMPUTE((nt-2)&3);
    asm volatile("s_waitcnt vmcnt(0)" ::: "memory");
    asm volatile("s_barrier" ::: "memory");
    COMPUTE((nt-1)&3);
#undef STAGE
#undef COMPUTE

    const int crow = (lane>>4)*4, ccol = lane & 15;
    #pragma unroll
    for (int i=0;i<2;++i){
        #pragma unroll
        for (int j=0;j<2;++j){
            #pragma unroll
            for (int r=0;r<4;++r){
                int m = m0 + wm0 + i*16 + crow + r;
                int n = n0 + wn0 + j*16 + ccol;
                float v = acc[i][j][r] + res[(size_t)m*N + n];
                C[(size_t)m*N + n] = v;
                outb[(size_t)m*N + n] = f2b(v);
            }
        }
    }
}

// dt_proj bf16 MFMA: dtb[M][N](bf16) = softplus(A[M][64] @ W[N][64]^T + bias).
// 64x64 tile, 4 waves of 32x32, K=64 = 2 BK32 steps (no pipeline needed).
__global__ __launch_bounds__(256) void dt_mfma(
    const ushort_t* __restrict__ A, const ushort_t* __restrict__ W,
    const float* __restrict__ bias, ushort_t* __restrict__ dtb, int N)
{
    __shared__ ushort_t As[2][64*32];
    __shared__ ushort_t Ws[2][64*32];
    const int tid = threadIdx.x, lane = tid&63, wv = tid>>6;
    const int wm0 = (wv>>1)*32, wn0 = (wv&1)*32;
    const int m0 = blockIdx.y*64, n0 = blockIdx.x*64;
    const int r0 = tid>>2, ch = tid&3;
    const ushort_t* gA = A + (size_t)(m0+r0)*64 + ch*8;
    const ushort_t* gW = W + (size_t)(n0+r0)*64 + ch*8;
    GLOAD(gA,      (char*)&As[0][0] + tid*16);
    GLOAD(gW,      (char*)&Ws[0][0] + tid*16);
    GLOAD(gA + 32, (char*)&As[1][0] + tid*16);
    GLOAD(gW + 32, (char*)&Ws[1][0] + tid*16);

    f32x4 acc[2][2];
    #pragma unroll
    for (int i=0;i<2;++i)
        #pragma unroll
        for (int j=0;j<2;++j) acc[i][j] = (f32x4){0.f,0.f,0.f,0.f};

    asm volatile("s_waitcnt vmcnt(0)" ::: "memory");
    asm volatile("s_barrier" ::: "memory");
    const int row_a = lane&15, kc = (lane>>4)*8;
    #pragma unroll
    for (int buf=0; buf<2; ++buf){
        short8 af[2], bf[2];
        #pragma unroll
        for (int i=0;i<2;++i) af[i] = *(const short8*)&As[buf][(wm0 + i*16 + row_a)*32 + kc];
        #pragma unroll
        for (int j=0;j<2;++j) bf[j] = *(const short8*)&Ws[buf][(wn0 + j*16 + row_a)*32 + kc];
        #pragma unroll
        for (int i=0;i<2;++i)
            #pragma unroll
            for (int j=0;j<2;++j)
                acc[i][j] = __builtin_amdgcn_mfma_f32_16x16x32_bf16(af[i], bf[j], acc[i][j], 0,0,0);
    }

    const int crow = (lane>>4)*4, ccol = lane & 15;
    #pragma unroll
    for (int i=0;i<2;++i){
        #pragma unroll
        for (int j=0;j<2;++j){
            #pragma unroll
            for (int r=0;r<4;++r){
                int m = m0 + wm0 + i*16 + crow + r;
                int n = n0 + wn0 + j*16 + ccol;
                float v = softplusf_(acc[i][j][r] + bias[n]);
                dtb[(size_t)m*N + n] = f2b(v);
            }
        }
    }
}

// Split-K fp32 GEMM for x_proj (A in bf16): grid (N/64, M/64, XP_KS).
__global__ __launch_bounds__(256) void gemm_tn_sk(
    const ushort_t* __restrict__ A, int lda,
    const float* __restrict__ W, int ldw,
    float* __restrict__ P, int M, int N, int K)
{
    __shared__ float As[16][68];
    __shared__ float Ws[16][68];
    const int tid = threadIdx.x;
    const int tx = tid & 15, ty = tid >> 4;
    const int m0 = blockIdx.y * 64, n0 = blockIdx.x * 64;
    const int kbase = blockIdx.z * (K/XP_KS);
    const int lr = tid >> 2;
    const int lk = (tid & 3) << 2;
    float acc[4][4] = {{0.f}};

    for (int kk = 0; kk < K/XP_KS; kk += 16) {
        int k0 = kbase + kk;
        ushort4 av4 = *(const ushort4*)(A + (size_t)(m0+lr)*lda + k0 + lk);
        float4 wv = make_float4(0.f,0.f,0.f,0.f);
        if (n0 + lr < N) wv = *(const float4*)(W + (size_t)(n0+lr)*ldw + k0 + lk);
        __syncthreads();
        As[lk+0][lr]=b2f(av4.x); As[lk+1][lr]=b2f(av4.y);
        As[lk+2][lr]=b2f(av4.z); As[lk+3][lr]=b2f(av4.w);
        Ws[lk+0][lr]=wv.x; Ws[lk+1][lr]=wv.y; Ws[lk+2][lr]=wv.z; Ws[lk+3][lr]=wv.w;
        __syncthreads();
        #pragma unroll
        for (int k = 0; k < 16; ++k) {
            float4 a = *(const float4*)&As[k][ty<<2];
            float4 b = *(const float4*)&Ws[k][tx<<2];
            float a4[4] = {a.x,a.y,a.z,a.w};
            float b4[4] = {b.x,b.y,b.z,b.w};
            #pragma unroll
            for (int i=0;i<4;++i)
                #pragma unroll
                for (int j=0;j<4;++j)
                    acc[i][j] = fmaf(a4[i], b4[j], acc[i][j]);
        }
    }

    float* Pz = P + (size_t)blockIdx.z * M * 96;
    #pragma unroll
    for (int i=0;i<4;++i){
        int m = m0 + (ty<<2) + i;
        #pragma unroll
        for (int j=0;j<4;++j){
            int n = n0 + (tx<<2) + j;
            if (n < N) Pz[(size_t)m*96 + n] = acc[i][j];
        }
    }
}

// xdbl[g] = sum_ks P[ks][g]; also emit bf16 dt_r (cols<64) to dtrb[M][64].
__global__ __launch_bounds__(256) void sk_reduce(
    const float* __restrict__ P, float* __restrict__ outp,
    ushort_t* __restrict__ dtrb, int MN)
{
    int g = blockIdx.x*256 + threadIdx.x;
    float s = 0.f;
    #pragma unroll
    for (int ks=0; ks<XP_KS; ++ks) s += P[(size_t)ks*MN + g];
    outp[g] = s;
    int m = g / 96, c = g - m*96;
    if (c < 64) dtrb[(size_t)m*64 + c] = f2b(s);
}

// Depthwise causal conv (K=4) + bias + SiLU: bf16 in (xzb), bf16 out (ucb).
__global__ __launch_bounds__(256) void conv_silu_k(
    const ushort_t* __restrict__ xzb, const float* __restrict__ cw,
    const float* __restrict__ cb, ushort_t* __restrict__ ucb)
{
    int idx = blockIdx.x*256 + threadIdx.x;
    int d  = idx & (D_INNER-1);
    int bt = idx >> 11;
    int t  = bt & (TT-1);
    float4 w4 = *(const float4*)(cw + d*4);
    float wv[4] = {w4.x, w4.y, w4.z, w4.w};
    float acc = cb[d];
    #pragma unroll
    for (int k=0;k<4;++k){
        int tt = t - 3 + k;
        if (tt >= 0) acc = fmaf(b2f(xzb[(size_t)(bt-3+k)*4096 + d]), wv[k], acc);
    }
    ucb[idx] = f2b(siluf_(acc));
}

// ---- Chunked selective scan (3 phases), bf16 dt/u inputs. ----

__global__ __launch_bounds__(256) void scan_p1(
    const ushort_t* __restrict__ dt, const ushort_t* __restrict__ uc,
    const float* __restrict__ xdbl, const float* __restrict__ A_log,
    float* __restrict__ hpart, float* __restrict__ hdecay)
{
    const int tid = threadIdx.x;
    const int d = blockIdx.x*256 + tid;
    const int b = blockIdx.y;
    const int k = blockIdx.z;
    const int t0 = k*SCTC;
    float A[16];
    #pragma unroll
    for (int q=0;q<4;++q){
        float4 v = *(const float4*)(A_log + (size_t)d*16 + q*4);
        A[q*4+0]=-__expf(v.x); A[q*4+1]=-__expf(v.y);
        A[q*4+2]=-__expf(v.z); A[q*4+3]=-__expf(v.w);
    }
    float h[16];
    #pragma unroll
    for (int s=0;s<16;++s) h[s]=0.f;
    float sumdt = 0.f;
    const ushort_t* dtp = dt + ((size_t)b*TT + t0)*D_INNER + d;
    const ushort_t* ucp = uc + ((size_t)b*TT + t0)*D_INNER + d;
    const float* bcp = xdbl + ((size_t)b*TT + t0)*96 + 64;
    #pragma unroll 2
    for (int t=0;t<SCTC;++t){
        float dtv = b2f(dtp[(size_t)t*D_INNER]);
        float uv  = b2f(ucp[(size_t)t*D_INNER]);
        const float* bc = bcp + (size_t)t*96;
        float du = dtv*uv;
        sumdt += dtv;
        #pragma unroll
        for (int s=0;s<16;++s)
            h[s] = fmaf(__expf(dtv*A[s]), h[s], du*bc[s]);
    }
    size_t base = ((size_t)(k*BB+b)*D_INNER + d)*16;
    float4* hp = (float4*)(hpart + base);
    float4* hd = (float4*)(hdecay + base);
    #pragma unroll
    for (int q=0;q<4;++q){
        hp[q] = make_float4(h[q*4],h[q*4+1],h[q*4+2],h[q*4+3]);
        hd[q] = make_float4(__expf(sumdt*A[q*4+0]),__expf(sumdt*A[q*4+1]),
                            __expf(sumdt*A[q*4+2]),__expf(sumdt*A[q*4+3]));
    }
}

__global__ __launch_bounds__(256) void scan_fix(
    const float* __restrict__ hpart, const float* __restrict__ hdecay,
    float* __restrict__ hstart)
{
    int g = blockIdx.x*256 + threadIdx.x;
    float h = 0.f;
    #pragma unroll
    for (int k=0;k<NCHUNK;++k){
        size_t idx = (size_t)k*(BB*D_INNER*16) + g;
        hstart[idx] = h;
        h = fmaf(hdecay[idx], h, hpart[idx]);
    }
}

__global__ __launch_bounds__(256) void scan_p3(
    const ushort_t* __restrict__ dt, const ushort_t* __restrict__ uc,
    const float* __restrict__ xdbl, const float* __restrict__ A_log,
    const ushort_t* __restrict__ xzb, const float* __restrict__ Dd,
    const float* __restrict__ hstart, ushort_t* __restrict__ ysb)
{
    const int tid = threadIdx.x;
    const int d = blockIdx.x*256 + tid;
    const int b = blockIdx.y;
    const int k = blockIdx.z;
    const int t0 = k*SCTC;
    float A[16];
    #pragma unroll
    for (int q=0;q<4;++q){
        float4 v = *(const float4*)(A_log + (size_t)d*16 + q*4);
        A[q*4+0]=-__expf(v.x); A[q*4+1]=-__expf(v.y);
        A[q*4+2]=-__expf(v.z); A[q*4+3]=-__expf(v.w);
    }
    float h[16];
    {
        const float4* hs = (const float4*)(hstart + ((size_t)(k*BB+b)*D_INNER + d)*16);
        #pragma unroll
        for (int q=0;q<4;++q){
            float4 v = hs[q];
            h[q*4+0]=v.x; h[q*4+1]=v.y; h[q*4+2]=v.z; h[q*4+3]=v.w;
        }
    }
    const float Ddc = Dd[d];
    const ushort_t* dtp = dt + ((size_t)b*TT + t0)*D_INNER + d;
    const ushort_t* ucp = uc + ((size_t)b*TT + t0)*D_INNER + d;
    const ushort_t* zp = xzb + ((size_t)b*TT + t0)*4096 + 2048 + d;
    const float* bcp = xdbl + ((size_t)b*TT + t0)*96 + 64;
    ushort_t* yp = ysb + ((size_t)b*TT + t0)*D_INNER + d;
    #pragma unroll 2
    for (int t=0;t<SCTC;++t){
        float dtv = b2f(dtp[(size_t)t*D_INNER]);
        float uv  = b2f(ucp[(size_t)t*D_INNER]);
        float zv  = b2f(zp[(size_t)t*4096]);
        const float* bc = bcp + (size_t)t*96;
        float du = dtv*uv;
        float y0=0.f,y1=0.f,y2=0.f,y3=0.f;
        #pragma unroll
        for (int q=0;q<4;++q){
            h[q*4+0] = fmaf(__expf(dtv*A[q*4+0]), h[q*4+0], du*bc[q*4+0]);
            h[q*4+1] = fmaf(__expf(dtv*A[q*4+1]), h[q*4+1], du*bc[q*4+1]);
            h[q*4+2] = fmaf(__expf(dtv*A[q*4+2]), h[q*4+2], du*bc[q*4+2]);
            h[q*4+3] = fmaf(__expf(dtv*A[q*4+3]), h[q*4+3], du*bc[q*4+3]);
        }
        #pragma unroll
        for (int q=0;q<4;++q){
            y0 = fmaf(h[q*4+0], bc[16+q*4+0], y0);
            y1 = fmaf(h[q*4+1], bc[16+q*4+1], y1);
            y2 = fmaf(h[q*4+2], bc[16+q*4+2], y2);
            y3 = fmaf(h[q*4+3], bc[16+q*4+3], y3);
        }
        float y = (y0+y1)+(y2+y3);
        float yv = (y + uv*Ddc) * siluf_(zv);
        yp[(size_t)t*D_INNER] = f2b(yv);
    }
}

__global__ __launch_bounds__(256) void layernorm_k(
    const float* __restrict__ X, const float* __restrict__ w,
    const float* __restrict__ b, float* __restrict__ out)
{
    int row = blockIdx.x;
    int tid = threadIdx.x;
    const float* xr = X + (size_t)row*D_MODEL;
    float4 v = *(const float4*)(xr + tid*4);
    float s  = v.x+v.y+v.z+v.w;
    float ss = fmaf(v.x,v.x, fmaf(v.y,v.y, fmaf(v.z,v.z, v.w*v.w)));
    #pragma unroll
    for (int off=32; off>0; off>>=1){
        s  += __shfl_down(s, off, 64);
        ss += __shfl_down(ss, off, 64);
    }
    __shared__ float red[8];
    int wid = tid>>6, lane = tid&63;
    if (lane==0){ red[wid]=s; red[4+wid]=ss; }
    __syncthreads();
    if (tid==0){
        float S  = red[0]+red[1]+red[2]+red[3];
        float SS = red[4]+red[5]+red[6]+red[7];
        float mu = S*(1.f/D_MODEL);
        float var = SS*(1.f/D_MODEL) - mu*mu;
        red[0]=mu; red[1]=rsqrtf(var + 1e-5f);
    }
    __syncthreads();
    float mu=red[0], rs=red[1];
    float4 wv = *(const float4*)(w + tid*4);
    float4 bv = *(const float4*)(b + tid*4);
    float4 o;
    o.x = fmaf((v.x-mu)*rs, wv.x, bv.x);
    o.y = fmaf((v.y-mu)*rs, wv.y, bv.y);
    o.z = fmaf((v.z-mu)*rs, wv.z, bv.z);
    o.w = fmaf((v.w-mu)*rs, wv.w, bv.w);
    *(float4*)(out + (size_t)row*D_MODEL + tid*4) = o;
}

extern "C" void kernel_launch(void* const* d_in, const int* in_sizes, int n_in,
                              void* d_out, int out_size, void* d_ws, size_t ws_size,
                              hipStream_t stream) {
    (void)in_sizes; (void)n_in; (void)out_size; (void)ws_size;
    const float* x      = (const float*)d_in[0];
    const float* in_w   = (const float*)d_in[1];
    const float* conv_w = (const float*)d_in[2];
    const float* conv_b = (const float*)d_in[3];
    const float* xp_w   = (const float*)d_in[4];
    const float* dtp_w  = (const float*)d_in[5];
    const float* dtp_b  = (const float*)d_in[6];
    const float* A_log  = (const float*)d_in[7];
    const float* Dd     = (const float*)d_in[8];
    const float* out_w  = (const float*)d_in[9];
    const float* nw     = (const float*)d_in[10];
    const float* nb     = (const float*)d_in[11];
    float* out = (float*)d_out;

    char* p = (char*)d_ws;
    ushort_t* xzb  = (ushort_t*)p; p += (size_t)BT*4096*2;     // 16 MB
    ushort_t* ucb  = (ushort_t*)p; p += (size_t)BT*2048*2;     // 8 MB
    float* xdbl    = (float*)p;  p += (size_t)BT*96*4;         // 768 KB
    ushort_t* dtrb = (ushort_t*)p; p += (size_t)BT*64*2;       // 256 KB
    ushort_t* dtbb = (ushort_t*)p; p += (size_t)BT*2048*2;     // 8 MB
    float* xcur    = (float*)p;  p += (size_t)BT*1024*4;       // 8 MB
    ushort_t* xinb = (ushort_t*)p; p += (size_t)BT*1024*2;     // 4 MB
    ushort_t* ysb  = (ushort_t*)p; p += (size_t)BT*2048*2;     // 8 MB
    ushort_t* winb = (ushort_t*)p; p += (size_t)N_LAYERS*4096*1024*2;  // 32 MB
    ushort_t* woutb= (ushort_t*)p; p += (size_t)N_LAYERS*1024*2048*2;  // 16 MB
    ushort_t* dtpb = (ushort_t*)p; p += (size_t)N_LAYERS*2048*64*2;    // 1 MB
    float* hpart   = (float*)p;  p += (size_t)NCHUNK*BB*D_INNER*16*4;  // 8 MB
    float* hdecay  = (float*)p;  p += (size_t)NCHUNK*BB*D_INNER*16*4;  // 8 MB
    float* hstart  = (float*)p;  p += (size_t)NCHUNK*BB*D_INNER*16*4;  // 8 MB
    // pbuf (x_proj split-K partials, 6.3 MB) aliases hpart: pbuf is consumed
    // by sk_reduce before scan_p1 writes hpart. (8 MB >= 6.3 MB.)
    float* pbuf    = hpart;

    // One-time conversions: input x and ALL layers' weights.
    f2b_k<<<(BT*1024)/1024,256,0,stream>>>(x, xinb, BT*1024);
    f2bw_k<<<(N_LAYERS*(4096*1024 + 1024*2048 + 2048*64))/1024,256,0,stream>>>(
        in_w, out_w, dtp_w, winb, woutb, dtpb);

    for (int i = 0; i < N_LAYERS; ++i){
        const float* xin = (i==0) ? x : xcur;
        // xz = xin @ in_w^T (2048x4096 K=1024) -> bf16 xzb. 512 blocks, 8x8 rect.
        gemm_ip<<<512,512,0,stream>>>(
            xinb, winb + (size_t)i*4096*1024, BT, 4096, D_MODEL, xzb, 8, 8, 4);
        // uc = silu(causal_conv(u) + cb) -> bf16
        conv_silu_k<<<(BT*D_INNER)/256,256,0,stream>>>(
            xzb, conv_w + (size_t)i*D_INNER*D_CONV, conv_b + (size_t)i*D_INNER, ucb);
        // x_dbl = uc @ xp_w^T  (2048 x 96 x K=2048), fp32 split-K, bf16 A
        gemm_tn_sk<<<dim3(2,32,XP_KS),256,0,stream>>>(
            ucb, D_INNER, xp_w + (size_t)i*96*D_INNER, D_INNER,
            pbuf, BT, 96, D_INNER);
        sk_reduce<<<(BT*96)/256,256,0,stream>>>(pbuf, xdbl, dtrb, BT*96);
        // dt = softplus(dt_r @ dtp_w^T + dtp_b) -> bf16, MFMA (K=64)
        dt_mfma<<<dim3(D_INNER/64, BT/64),256,0,stream>>>(
            dtrb, dtpb + (size_t)i*2048*64, dtp_b + (size_t)i*D_INNER, dtbb, D_INNER);
        // chunked selective scan + fused (y + u*D)*silu(z) -> bf16
        scan_p1<<<dim3(D_INNER/256, BB, NCHUNK),256,0,stream>>>(
            dtbb, ucb, xdbl, A_log + (size_t)i*D_INNER*D_STATE, hpart, hdecay);
        scan_fix<<<(BB*D_INNER*16)/256,256,0,stream>>>(hpart, hdecay, hstart);
        scan_p3<<<dim3(D_INNER/256, BB, NCHUNK),256,0,stream>>>(
            dtbb, ucb, xdbl, A_log + (size_t)i*D_INNER*D_STATE, xzb,
            Dd + (size_t)i*D_INNER, hstart, ysb);
        // xcur = ys @ out_w^T + xin (2048x1024 K=2048), fp32 + bf16 copy.
        gemm_op<<<512,256,0,stream>>>(
            ysb, woutb + (size_t)i*1024*2048, xcur, BT, 1024, D_INNER,
            xin, xinb, 8, 8, 2);
    }
    layernorm_k<<<BT,256,0,stream>>>(xcur, nw, nb, out);
}